// Round 2
// baseline (10806.773 us; speedup 1.0000x reference)
//
#include <hip/hip_runtime.h>
#include <hip/hip_bf16.h>
#include <math.h>

#define NPTS 16384
#define NE 4
#define NM 2048
#define DD 128    // D3
#define DP 64     // D1
#define NHE 256
#define NHM 256
#define NRES 64
#define NTK 16
#define NEG_INF -3.402823466e38f

// ---------- helpers ----------
__device__ __forceinline__ bool rank_gt(float av, int ai, float bv, int bi) {
  // "ranks higher in top-k": larger value, ties broken by lower index (jax top_k)
  return (av > bv) || (av == bv && ai < bi);
}

// ---------- kernel 1: per-point preproc ----------
__global__ __launch_bounds__(256) void k_preproc(
    const float* __restrict__ x, const float* __restrict__ lines,
    const float* __restrict__ Wm1, const float* __restrict__ bm1,
    const float* __restrict__ Wm2, const float* __restrict__ bm2,
    float* __restrict__ pf, float* __restrict__ pe,
    float* __restrict__ slotW, int* __restrict__ plist,
    int* __restrict__ pairE, int* __restrict__ pairS, int* __restrict__ cnt)
{
  int n = blockIdx.x * 256 + threadIdx.x;
  if (n >= NPTS) return;
  float c0 = x[n*5+0], c1 = x[n*5+1], c2 = x[n*5+2];

  // ---- gating MLP ----
  float l0 = bm2[0], l1 = bm2[1], l2 = bm2[2], l3 = bm2[3];
#pragma unroll 4
  for (int j = 0; j < 64; ++j) {
    float h = fmaf(c0, Wm1[j], fmaf(c1, Wm1[64+j], fmaf(c2, Wm1[128+j], bm1[j])));
    h = fmaxf(h, 0.f);
    l0 = fmaf(h, Wm2[j*4+0], l0);
    l1 = fmaf(h, Wm2[j*4+1], l1);
    l2 = fmaf(h, Wm2[j*4+2], l2);
    l3 = fmaf(h, Wm2[j*4+3], l3);
  }
  float lg[4] = {l0, l1, l2, l3};
  float mx = fmaxf(fmaxf(l0, l1), fmaxf(l2, l3));
  float pr[4]; float ssum = 0.f;
#pragma unroll
  for (int k = 0; k < 4; ++k) { pr[k] = expf(lg[k] - mx); ssum += pr[k]; }
#pragma unroll
  for (int k = 0; k < 4; ++k) pr[k] /= ssum;
  int i0 = 0;
#pragma unroll
  for (int k = 1; k < 4; ++k) if (pr[k] > pr[i0]) i0 = k;
  int i1 = (i0 == 0) ? 1 : 0;
#pragma unroll
  for (int k = 0; k < 4; ++k) if (k != i0 && pr[k] > pr[i1]) i1 = k;
  float g0 = pr[i0], g1 = pr[i1], gs = g0 + g1;
  g0 /= gs; g1 /= gs;
  int s0 = atomicAdd(&cnt[i0], 1);
  int s1 = atomicAdd(&cnt[i1], 1);
  plist[i0*NPTS + s0] = n; slotW[i0*NPTS + s0] = g0;
  plist[i1*NPTS + s1] = n; slotW[i1*NPTS + s1] = g1;
  pairE[n*2+0] = i0; pairE[n*2+1] = i1;
  pairS[n*2+0] = s0; pairS[n*2+1] = s1;

  // ---- positional encoding (accurate sinf/cosf: args up to 512*pi) ----
  pe[(size_t)n*64 + 0] = c0;
  pe[(size_t)n*64 + 1] = c1;
  pe[(size_t)n*64 + 2] = c2;
  float cc[3] = {c0, c1, c2};
#pragma unroll
  for (int i = 0; i < 10; ++i) {
    float sc = 3.14159274101257324f * (float)(1 << i);
#pragma unroll
    for (int j = 0; j < 3; ++j) {
      float a = sc * cc[j];
      pe[(size_t)n*64 + 3 + (i*3+j)*2 + 0] = sinf(a);
      pe[(size_t)n*64 + 3 + (i*3+j)*2 + 1] = cosf(a);
    }
  }
  pe[(size_t)n*64 + 63] = 0.f;

  // ---- param feats: product of 2 line interpolations ----
  float pfv[64];
#pragma unroll
  for (int d = 0; d < 64; ++d) pfv[d] = 1.f;
  for (int i = 0; i < 2; ++i) {
    float p = x[n*5 + 3 + i] * 63.0f;
    float f = floorf(p);
    float wfr = p - f;
    int j0 = (int)f;
    int j1 = (int)fminf(f + 1.0f, 63.0f);
    const float* L = lines + (size_t)i * 64 * 64;
#pragma unroll
    for (int d = 0; d < 64; ++d) {
      float a = L[d*64 + j0];
      float b = L[d*64 + j1];
      pfv[d] *= a + wfr * (b - a);
    }
  }
#pragma unroll
  for (int d = 0; d < 64; ++d) pf[(size_t)n*64 + d] = pfv[d];
}

// ---------- kernel 2: K/V projection ----------
__global__ __launch_bounds__(256) void k_kv(
    const float* __restrict__ mem_k, const float* __restrict__ mem_v,
    const float* __restrict__ Wk, const float* __restrict__ Wv,
    float* __restrict__ Khat, float* __restrict__ Vhat)
{
  int e = blockIdx.y;
  int which = blockIdx.z;
  const float* src = which ? mem_v : mem_k;
  const float* W   = which ? Wv : Wk;
  float* dst       = which ? Vhat : Khat;
  int r0 = blockIdx.x * 32;
  __shared__ float sm[32][130];
  int tid = threadIdx.x;
  for (int idx = tid; idx < 32*32; idx += 256) {
    int r = idx >> 5, c4 = (idx & 31) * 4;
    float4 v = *(const float4*)(src + ((size_t)e*NM + r0 + r)*DD + c4);
    sm[r][c4+0] = v.x; sm[r][c4+1] = v.y; sm[r][c4+2] = v.z; sm[r][c4+3] = v.w;
  }
  __syncthreads();
  int r = tid >> 3, cb = (tid & 7) * 16;
  float acc[16];
#pragma unroll
  for (int i = 0; i < 16; ++i) acc[i] = 0.f;
  const float* We = W + (size_t)e*DD*DD;
#pragma unroll 4
  for (int k = 0; k < 128; ++k) {
    float s = sm[r][k];
    const float4* w4 = (const float4*)(We + (size_t)k*DD + cb);
#pragma unroll
    for (int q = 0; q < 4; ++q) {
      float4 wv = w4[q];
      acc[q*4+0] = fmaf(s, wv.x, acc[q*4+0]);
      acc[q*4+1] = fmaf(s, wv.y, acc[q*4+1]);
      acc[q*4+2] = fmaf(s, wv.z, acc[q*4+2]);
      acc[q*4+3] = fmaf(s, wv.w, acc[q*4+3]);
    }
  }
  float* drow = dst + ((size_t)e*NM + r0 + r)*DD + cb;
#pragma unroll
  for (int i = 0; i < 16; ++i) drow[i] = acc[i];
}

// ---------- kernel 3: routed expert SIREN MLP + LN + Q-proj ----------
__global__ __launch_bounds__(256) void k_expert(
    const float* __restrict__ pe,
    const float* __restrict__ We1, const float* __restrict__ be1,
    const float* __restrict__ We2, const float* __restrict__ be2,
    const float* __restrict__ We3, const float* __restrict__ be3,
    const float* __restrict__ ln_g, const float* __restrict__ ln_b,
    const float* __restrict__ Wq,
    const int* __restrict__ plist, const int* __restrict__ cnt,
    float* __restrict__ featsC, float* __restrict__ QC)
{
  int e = blockIdx.y;
  int count = cnt[e];
  int base = blockIdx.x * 16;
  if (base >= count) return;
  __shared__ float peT[16][68];
  __shared__ float hA[16][260];
  __shared__ float hB[16][260];
  __shared__ float fT[16][132];
  __shared__ int pts[16];
  int tid = threadIdx.x;
  if (tid < 16) {
    int slot = base + tid;
    pts[tid] = (slot < count) ? plist[e*NPTS + slot] : 0;
  }
  __syncthreads();
  for (int idx = tid; idx < 16*16; idx += 256) {
    int r = idx >> 4, c4 = (idx & 15) * 4;
    float4 v = *(const float4*)(pe + (size_t)pts[r]*64 + c4);
    peT[r][c4+0] = v.x; peT[r][c4+1] = v.y; peT[r][c4+2] = v.z; peT[r][c4+3] = v.w;
  }
  __syncthreads();

  int row = tid >> 4;
  int c16 = (tid & 15) * 16;
  int c8  = (tid & 15) * 8;

  // layer1: 63 -> 256, sin(30*)
  {
    float acc[16];
#pragma unroll
    for (int i = 0; i < 16; ++i) acc[i] = be1[e*NHE + c16 + i];
    const float* W = We1 + (size_t)e*63*NHE;
    for (int k = 0; k < 63; ++k) {
      float s = peT[row][k];
      const float4* w4 = (const float4*)(W + (size_t)k*NHE + c16);
#pragma unroll
      for (int q = 0; q < 4; ++q) {
        float4 wv = w4[q];
        acc[q*4+0] = fmaf(s, wv.x, acc[q*4+0]);
        acc[q*4+1] = fmaf(s, wv.y, acc[q*4+1]);
        acc[q*4+2] = fmaf(s, wv.z, acc[q*4+2]);
        acc[q*4+3] = fmaf(s, wv.w, acc[q*4+3]);
      }
    }
#pragma unroll
    for (int i = 0; i < 16; ++i) hA[row][c16+i] = sinf(30.0f * acc[i]);
  }
  __syncthreads();

  // layer2: 256 -> 256, sin(30*)
  {
    float acc[16];
#pragma unroll
    for (int i = 0; i < 16; ++i) acc[i] = be2[e*NHE + c16 + i];
    const float* W = We2 + (size_t)e*NHE*NHE;
#pragma unroll 2
    for (int k = 0; k < NHE; ++k) {
      float s = hA[row][k];
      const float4* w4 = (const float4*)(W + (size_t)k*NHE + c16);
#pragma unroll
      for (int q = 0; q < 4; ++q) {
        float4 wv = w4[q];
        acc[q*4+0] = fmaf(s, wv.x, acc[q*4+0]);
        acc[q*4+1] = fmaf(s, wv.y, acc[q*4+1]);
        acc[q*4+2] = fmaf(s, wv.z, acc[q*4+2]);
        acc[q*4+3] = fmaf(s, wv.w, acc[q*4+3]);
      }
    }
#pragma unroll
    for (int i = 0; i < 16; ++i) hB[row][c16+i] = sinf(30.0f * acc[i]);
  }
  __syncthreads();

  // layer3: 256 -> 128 (no activation)
  {
    float acc[8];
#pragma unroll
    for (int i = 0; i < 8; ++i) acc[i] = be3[e*DD + c8 + i];
    const float* W = We3 + (size_t)e*NHE*DD;
#pragma unroll 2
    for (int k = 0; k < NHE; ++k) {
      float s = hB[row][k];
      const float4* w4 = (const float4*)(W + (size_t)k*DD + c8);
#pragma unroll
      for (int q = 0; q < 2; ++q) {
        float4 wv = w4[q];
        acc[q*4+0] = fmaf(s, wv.x, acc[q*4+0]);
        acc[q*4+1] = fmaf(s, wv.y, acc[q*4+1]);
        acc[q*4+2] = fmaf(s, wv.z, acc[q*4+2]);
        acc[q*4+3] = fmaf(s, wv.w, acc[q*4+3]);
      }
    }
#pragma unroll
    for (int i = 0; i < 8; ++i) fT[row][c8+i] = acc[i];
  }
  __syncthreads();

  // layernorm over 128, write q into hA[row][0..127]
  {
    float sm = 0.f, sq = 0.f;
#pragma unroll
    for (int i = 0; i < 8; ++i) {
      float v = fT[row][c8 + i];
      sm += v; sq += v * v;
    }
#pragma unroll
    for (int m = 1; m < 16; m <<= 1) { sm += __shfl_xor(sm, m); sq += __shfl_xor(sq, m); }
    float mu = sm * (1.f/128.f);
    float var = sq * (1.f/128.f) - mu*mu;
    float rs = rsqrtf(var + 1e-5f);
#pragma unroll
    for (int i = 0; i < 8; ++i) {
      int ccc = c8 + i;
      hA[row][ccc] = (fT[row][ccc] - mu) * rs * ln_g[ccc] + ln_b[ccc];
    }
  }
  __syncthreads();

  // Q = q @ Wq[e]
  {
    float acc[8];
#pragma unroll
    for (int i = 0; i < 8; ++i) acc[i] = 0.f;
    const float* W = Wq + (size_t)e*DD*DD;
#pragma unroll 4
    for (int k = 0; k < DD; ++k) {
      float s = hA[row][k];
      const float4* w4 = (const float4*)(W + (size_t)k*DD + c8);
#pragma unroll
      for (int q = 0; q < 2; ++q) {
        float4 wv = w4[q];
        acc[q*4+0] = fmaf(s, wv.x, acc[q*4+0]);
        acc[q*4+1] = fmaf(s, wv.y, acc[q*4+1]);
        acc[q*4+2] = fmaf(s, wv.z, acc[q*4+2]);
        acc[q*4+3] = fmaf(s, wv.w, acc[q*4+3]);
      }
    }
    int slot = base + row;
    if (slot < count) {
      size_t o = ((size_t)e*NPTS + slot) * DD;
#pragma unroll
      for (int i = 0; i < 8; ++i) {
        featsC[o + c8 + i] = fT[row][c8 + i];
        QC[o + c8 + i] = acc[i];
      }
    }
  }
}

// ---------- kernel 4: fused scores + wave-distributed top-16 + softmax ----------
// block: 256 threads = 4 waves; block covers 16 slots (4 per wave).
// Wave's 64 lanes: lanes 16j..16j+15 hold slot j's sorted top-16 list (desc).
// Dot phase: lane = key (2 keys per lane per 128-key chunk), 4 slot-accumulators.
__global__ __launch_bounds__(256) void k_scores(
    const float* __restrict__ QC, const float* __restrict__ Khat,
    const int* __restrict__ cnt,
    float* __restrict__ attnW, int* __restrict__ attnI)
{
  int e = blockIdx.y;
  int count = cnt[e];
  int sbase = blockIdx.x * 16;
  if (sbase >= count) return;
  __shared__ float Ks[128][132];  // 128-key chunk, padded (8-way quad floor on b128)
  __shared__ float Qs[16][128];   // 16 slots' Q rows (broadcast reads)
  int tid = threadIdx.x;
  int w = tid >> 6, lane = tid & 63;

  for (int idx = tid; idx < 16*32; idx += 256) {
    int s = idx >> 5, c4 = (idx & 31) * 4;
    int slot = sbase + s;
    float4 v = make_float4(0.f, 0.f, 0.f, 0.f);
    if (slot < count) v = *(const float4*)(QC + ((size_t)e*NPTS + slot)*DD + c4);
    Qs[s][c4+0] = v.x; Qs[s][c4+1] = v.y; Qs[s][c4+2] = v.z; Qs[s][c4+3] = v.w;
  }

  // distributed top-16 state: this lane holds element (lane&15) of slot (lane>>4)'s list
  float lv = NEG_INF;
  int   li = 0x7fffffff;
  const float* Kbase = Khat + (size_t)e*NM*DD;

  for (int ch = 0; ch < NM/128; ++ch) {
    __syncthreads();
    for (int idx = tid; idx < 128*32; idx += 256) {
      int r = idx >> 5, c4 = (idx & 31) * 4;
      float4 v = *(const float4*)(Kbase + ((size_t)(ch*128 + r))*DD + c4);
      Ks[r][c4+0] = v.x; Ks[r][c4+1] = v.y; Ks[r][c4+2] = v.z; Ks[r][c4+3] = v.w;
    }
    __syncthreads();

    float acc0[4], acc1[4];
#pragma unroll
    for (int j = 0; j < 4; ++j) { acc0[j] = 0.f; acc1[j] = 0.f; }
    const float* krA = &Ks[lane][0];
    const float* krB = &Ks[64 + lane][0];
#pragma unroll
    for (int q = 0; q < 32; ++q) {
      float4 ka = *(const float4*)(krA + q*4);
      float4 kb = *(const float4*)(krB + q*4);
#pragma unroll
      for (int j = 0; j < 4; ++j) {
        float4 qv = *(const float4*)&Qs[w*4 + j][q*4];
        acc0[j] = fmaf(ka.x, qv.x, acc0[j]); acc0[j] = fmaf(ka.y, qv.y, acc0[j]);
        acc0[j] = fmaf(ka.z, qv.z, acc0[j]); acc0[j] = fmaf(ka.w, qv.w, acc0[j]);
        acc1[j] = fmaf(kb.x, qv.x, acc1[j]); acc1[j] = fmaf(kb.y, qv.y, acc1[j]);
        acc1[j] = fmaf(kb.z, qv.z, acc1[j]); acc1[j] = fmaf(kb.w, qv.w, acc1[j]);
      }
    }

    // threshold-gated distributed inserts
#pragma unroll
    for (int j = 0; j < 4; ++j) {
      int slot = sbase + w*4 + j;
      if (slot >= count) continue;   // wave-uniform
#pragma unroll
      for (int h = 0; h < 2; ++h) {
        float v = h ? acc1[j] : acc0[j];
        int key = ch*128 + h*64 + lane;
        float Tv = __shfl(lv, j*16 + 15);
        int   Ti = __shfl(li, j*16 + 15);
        unsigned long long mb = __ballot(rank_gt(v, key, Tv, Ti));
        while (mb) {
          int b = __ffsll((unsigned long long)mb) - 1;
          mb &= mb - 1;
          float cv = __shfl(v, b);
          int   ck = ch*128 + h*64 + b;
          Tv = __shfl(lv, j*16 + 15);
          Ti = __shfl(li, j*16 + 15);
          if (!rank_gt(cv, ck, Tv, Ti)) continue;  // stale candidate (uniform branch)
          float pv = __shfl_up(lv, 1);
          int   pi = __shfl_up(li, 1);
          int p = lane & 15;
          bool abv_me   = rank_gt(lv, li, cv, ck);
          bool abv_prev = (p == 0) || rank_gt(pv, pi, cv, ck);
          float nv = abv_me ? lv : (abv_prev ? cv : pv);
          int   ni = abv_me ? li : (abv_prev ? ck : pi);
          if ((lane >> 4) == j) { lv = nv; li = ni; }
        }
      }
    }
  }

  // softmax over each slot's sorted 16 and write out
  const float inv_scale = 0.08838834764831845f;  // 1/sqrt(128)
#pragma unroll
  for (int j = 0; j < 4; ++j) {
    int slot = sbase + w*4 + j;
    if (slot >= count) continue;
    float m = __shfl(lv, j*16 + 0);
    float ev = expf((lv - m) * inv_scale);
    float s = ev;
    s += __shfl_xor(s, 1); s += __shfl_xor(s, 2);
    s += __shfl_xor(s, 4); s += __shfl_xor(s, 8);
    if ((lane >> 4) == j) {
      size_t off = ((size_t)e*NPTS + slot)*NTK + (lane & 15);
      attnW[off] = ev / s;
      attnI[off] = li;
    }
  }
}

// ---------- kernel 5: adapter MLP + LN + attention combine ----------
__global__ __launch_bounds__(256) void k_adapter(
    const float* __restrict__ Vhat, const float* __restrict__ pf,
    const float* __restrict__ A1, const float* __restrict__ a1,
    const float* __restrict__ A2, const float* __restrict__ a2,
    const float* __restrict__ alng, const float* __restrict__ alnb,
    const float* __restrict__ attnW, const int* __restrict__ attnI,
    const float* __restrict__ featsC, const float* __restrict__ slotW,
    const int* __restrict__ plist, const int* __restrict__ cnt,
    float* __restrict__ outC)
{
  int e = blockIdx.y;
  int count = cnt[e];
  int s0 = blockIdx.x * 2;
  if (s0 >= count) return;
  __shared__ float ain[32][200];
  __shared__ float hid[32][72];
  __shared__ float accv[2][128];
  __shared__ float attw[2][16];
  __shared__ int rti[32];
  __shared__ float wsl[2];
  __shared__ int ptl[2];
  int tid = threadIdx.x;
  if (tid < 32) {
    int sl = tid >> 4, key = tid & 15;
    int slot = s0 + sl;
    if (slot < count) {
      size_t o = ((size_t)e*NPTS + slot)*NTK + key;
      rti[tid] = attnI[o];
      attw[sl][key] = attnW[o];
    } else { rti[tid] = 0; attw[sl][key] = 0.f; }
  }
  if (tid >= 32 && tid < 34) {
    int sl = tid - 32;
    int slot = s0 + sl;
    wsl[sl] = (slot < count) ? slotW[e*NPTS + slot] : 0.f;
    ptl[sl] = (slot < count) ? plist[e*NPTS + slot] : 0;
  }
  if (tid < 256) { accv[tid >> 7][tid & 127] = 0.f; }
  __syncthreads();
  // gather ain = [Vhat[ti] (128) | pf[pt] (64)]
  for (int idx = tid; idx < 32*48; idx += 256) {
    int r = idx / 48, f4 = idx - r*48;
    float4 v;
    if (f4 < 32) v = *(const float4*)(Vhat + ((size_t)e*NM + rti[r])*DD + f4*4);
    else         v = *(const float4*)(pf + (size_t)ptl[r >> 4]*64 + (f4-32)*4);
    *((float4*)&ain[r][f4*4]) = v;
  }
  __syncthreads();

  int r = tid >> 3;
  int hb = (tid & 7) * 8;
  int cb = (tid & 7) * 16;

  // hidden = relu(ain @ A1 + a1), 192 -> 64
  {
    float acc[8];
#pragma unroll
    for (int i = 0; i < 8; ++i) acc[i] = a1[e*64 + hb + i];
    const float* W = A1 + (size_t)e*192*64;
#pragma unroll 4
    for (int k = 0; k < 192; ++k) {
      float s = ain[r][k];
      const float4* w4 = (const float4*)(W + (size_t)k*64 + hb);
#pragma unroll
      for (int q = 0; q < 2; ++q) {
        float4 wv = w4[q];
        acc[q*4+0] = fmaf(s, wv.x, acc[q*4+0]);
        acc[q*4+1] = fmaf(s, wv.y, acc[q*4+1]);
        acc[q*4+2] = fmaf(s, wv.z, acc[q*4+2]);
        acc[q*4+3] = fmaf(s, wv.w, acc[q*4+3]);
      }
    }
#pragma unroll
    for (int i = 0; i < 8; ++i) hid[r][hb+i] = fmaxf(acc[i], 0.f);
  }
  __syncthreads();

  // ad = hidden @ A2 + a2, 64 -> 128; then LN; Va; weighted accumulate
  {
    float ad[16];
#pragma unroll
    for (int i = 0; i < 16; ++i) ad[i] = a2[e*DD + cb + i];
    const float* W = A2 + (size_t)e*64*DD;
#pragma unroll 4
    for (int k = 0; k < 64; ++k) {
      float s = hid[r][k];
      const float4* w4 = (const float4*)(W + (size_t)k*DD + cb);
#pragma unroll
      for (int q = 0; q < 4; ++q) {
        float4 wv = w4[q];
        ad[q*4+0] = fmaf(s, wv.x, ad[q*4+0]);
        ad[q*4+1] = fmaf(s, wv.y, ad[q*4+1]);
        ad[q*4+2] = fmaf(s, wv.z, ad[q*4+2]);
        ad[q*4+3] = fmaf(s, wv.w, ad[q*4+3]);
      }
    }
    float sm = 0.f, sq = 0.f;
#pragma unroll
    for (int i = 0; i < 16; ++i) { sm += ad[i]; sq += ad[i]*ad[i]; }
#pragma unroll
    for (int m = 1; m < 8; m <<= 1) { sm += __shfl_xor(sm, m); sq += __shfl_xor(sq, m); }
    float mu = sm * (1.f/128.f);
    float var = sq * (1.f/128.f) - mu*mu;
    float rs = rsqrtf(var + 1e-5f);
    int sl = r >> 4, key = r & 15;
    float w = attw[sl][key];
#pragma unroll
    for (int i = 0; i < 16; ++i) {
      int ccc = cb + i;
      float va = ain[r][ccc] + ((ad[i] - mu) * rs * alng[e*DD + ccc] + alnb[e*DD + ccc]);
      atomicAdd(&accv[sl][ccc], w * va);
    }
  }
  __syncthreads();
  for (int idx = tid; idx < 2*128; idx += 256) {
    int sl = idx >> 7, ccc = idx & 127;
    int slot = s0 + sl;
    if (slot < count) {
      size_t o = ((size_t)e*NPTS + slot)*DD;
      outC[o + ccc] = wsl[sl] * (accv[sl][ccc] + featsC[o + ccc]);
    }
  }
}

// ---------- kernel 6: gather pairs + final MLP + sigmoid ----------
// 32 rows/block, weights staged through LDS in 8-row chunks (2 blocks/CU).
#define FR 32
__device__ __forceinline__ void mlp_layer_f(
    const float (*X)[260], float (*Y)[260], float (*Wt)[260],
    const float* __restrict__ W, const float* __restrict__ bias,
    int K, int tid)
{
  int rg = tid >> 4;          // 16 row-groups of 2 rows
  int cg = tid & 15;          // 16 col-groups of 16 cols
  int r0 = rg * 2;
  int c16 = cg * 16;
  float acc0[16], acc1[16];
#pragma unroll
  for (int i = 0; i < 16; ++i) { acc0[i] = 0.f; acc1[i] = 0.f; }
  int nkc = K >> 3;
  for (int kc = 0; kc < nkc; ++kc) {
    __syncthreads();
    for (int idx = tid; idx < 512; idx += 256) {
      int rr = idx >> 6, c4 = (idx & 63) * 4;
      *(float4*)&Wt[rr][c4] = *(const float4*)(W + (size_t)(kc*8 + rr)*NHM + c4);
    }
    __syncthreads();
#pragma unroll
    for (int kk = 0; kk < 8; ++kk) {
      float a0 = X[r0][kc*8 + kk];
      float a1 = X[r0+1][kc*8 + kk];
#pragma unroll
      for (int q = 0; q < 4; ++q) {
        float4 wv = *(const float4*)&Wt[kk][c16 + q*4];
        acc0[q*4+0] = fmaf(a0, wv.x, acc0[q*4+0]);
        acc0[q*4+1] = fmaf(a0, wv.y, acc0[q*4+1]);
        acc0[q*4+2] = fmaf(a0, wv.z, acc0[q*4+2]);
        acc0[q*4+3] = fmaf(a0, wv.w, acc0[q*4+3]);
        acc1[q*4+0] = fmaf(a1, wv.x, acc1[q*4+0]);
        acc1[q*4+1] = fmaf(a1, wv.y, acc1[q*4+1]);
        acc1[q*4+2] = fmaf(a1, wv.z, acc1[q*4+2]);
        acc1[q*4+3] = fmaf(a1, wv.w, acc1[q*4+3]);
      }
    }
  }
  float4 b0 = *(const float4*)(bias + c16);
  float4 b1 = *(const float4*)(bias + c16 + 4);
  float4 b2 = *(const float4*)(bias + c16 + 8);
  float4 b3 = *(const float4*)(bias + c16 + 12);
  float bb[16] = {b0.x,b0.y,b0.z,b0.w, b1.x,b1.y,b1.z,b1.w,
                  b2.x,b2.y,b2.z,b2.w, b3.x,b3.y,b3.z,b3.w};
  __syncthreads();
#pragma unroll
  for (int i = 0; i < 16; ++i) {
    Y[r0][c16+i]   = fmaxf(acc0[i] + bb[i], 0.f);
    Y[r0+1][c16+i] = fmaxf(acc1[i] + bb[i], 0.f);
  }
}

__global__ __launch_bounds__(256) void k_final(
    const float* __restrict__ outC, const int* __restrict__ pairE, const int* __restrict__ pairS,
    const float* __restrict__ M1, const float* __restrict__ c1,
    const float* __restrict__ M2, const float* __restrict__ c2,
    const float* __restrict__ M3, const float* __restrict__ c3,
    const float* __restrict__ M4, const float* __restrict__ c4,
    float* __restrict__ out)
{
  int base = blockIdx.x * FR;
  __shared__ float A[FR][260];
  __shared__ float B[FR][260];
  __shared__ float Wt[8][260];
  __shared__ int prE[FR*2];
  __shared__ int prS[FR*2];
  int tid = threadIdx.x;
  if (tid < FR*2) {
    prE[tid] = pairE[(size_t)base*2 + tid];
    prS[tid] = pairS[(size_t)base*2 + tid];
  }
  __syncthreads();
  for (int idx = tid; idx < FR*32; idx += 256) {
    int rr = idx >> 5, c4 = (idx & 31) * 4;
    float4 a = *(const float4*)(outC + ((size_t)prE[rr*2+0]*NPTS + prS[rr*2+0])*DD + c4);
    float4 b = *(const float4*)(outC + ((size_t)prE[rr*2+1]*NPTS + prS[rr*2+1])*DD + c4);
    A[rr][c4+0] = a.x + b.x; A[rr][c4+1] = a.y + b.y;
    A[rr][c4+2] = a.z + b.z; A[rr][c4+3] = a.w + b.w;
  }
  // (mlp_layer_f starts with __syncthreads before staging Wt)

  mlp_layer_f(A, B, Wt, M1, c1, 128, tid);  // 128 -> 256 relu
  mlp_layer_f(B, A, Wt, M2, c2, 256, tid);  // 256 -> 256 relu
  mlp_layer_f(A, B, Wt, M3, c3, 256, tid);  // 256 -> 256 relu

  // final: dot(B_row, M4) + c4 -> sigmoid
  __syncthreads();
  {
    int rg = tid >> 4, cg = tid & 15;
    int r0 = rg * 2, c16 = cg * 16;
    float p0 = 0.f, p1 = 0.f;
#pragma unroll
    for (int q = 0; q < 4; ++q) {
      float4 mv = *(const float4*)(M4 + c16 + q*4);
      p0 = fmaf(B[r0][c16+q*4+0], mv.x, p0); p0 = fmaf(B[r0][c16+q*4+1], mv.y, p0);
      p0 = fmaf(B[r0][c16+q*4+2], mv.z, p0); p0 = fmaf(B[r0][c16+q*4+3], mv.w, p0);
      p1 = fmaf(B[r0+1][c16+q*4+0], mv.x, p1); p1 = fmaf(B[r0+1][c16+q*4+1], mv.y, p1);
      p1 = fmaf(B[r0+1][c16+q*4+2], mv.z, p1); p1 = fmaf(B[r0+1][c16+q*4+3], mv.w, p1);
    }
#pragma unroll
    for (int m = 1; m < 16; m <<= 1) {
      p0 += __shfl_xor(p0, m);
      p1 += __shfl_xor(p1, m);
    }
    if (cg == 0) {
      float z0 = p0 + c4[0];
      float z1 = p1 + c4[0];
      out[base + r0]     = 1.f / (1.f + expf(-z0));
      out[base + r0 + 1] = 1.f / (1.f + expf(-z1));
    }
  }
}

// ---------- launcher ----------
extern "C" void kernel_launch(void* const* d_in, const int* in_sizes, int n_in,
                              void* d_out, int out_size, void* d_ws, size_t ws_size,
                              hipStream_t stream)
{
  const float* x    = (const float*)d_in[0];
  const float* lines= (const float*)d_in[1];
  const float* Wm1  = (const float*)d_in[2];
  const float* bm1  = (const float*)d_in[3];
  const float* Wm2  = (const float*)d_in[4];
  const float* bm2  = (const float*)d_in[5];
  const float* We1  = (const float*)d_in[6];
  const float* be1  = (const float*)d_in[7];
  const float* We2  = (const float*)d_in[8];
  const float* be2  = (const float*)d_in[9];
  const float* We3  = (const float*)d_in[10];
  const float* be3  = (const float*)d_in[11];
  const float* ln_g = (const float*)d_in[12];
  const float* ln_b = (const float*)d_in[13];
  const float* Wq   = (const float*)d_in[14];
  const float* Wk   = (const float*)d_in[15];
  const float* Wv   = (const float*)d_in[16];
  const float* A1   = (const float*)d_in[17];
  const float* a1   = (const float*)d_in[18];
  const float* A2   = (const float*)d_in[19];
  const float* a2   = (const float*)d_in[20];
  const float* alng = (const float*)d_in[21];
  const float* alnb = (const float*)d_in[22];
  const float* mem_k= (const float*)d_in[23];
  const float* mem_v= (const float*)d_in[24];
  const float* M1   = (const float*)d_in[25];
  const float* c1   = (const float*)d_in[26];
  const float* M2   = (const float*)d_in[27];
  const float* c2   = (const float*)d_in[28];
  const float* M3   = (const float*)d_in[29];
  const float* c3   = (const float*)d_in[30];
  const float* M4   = (const float*)d_in[31];
  const float* c4   = (const float*)d_in[32];
  float* out = (float*)d_out;

  char* wp = (char*)d_ws;
  auto alloc = [&](size_t bytes) -> void* {
    void* p = (void*)wp;
    wp += (bytes + 255) & ~(size_t)255;
    return p;
  };
  float* pf     = (float*)alloc((size_t)NPTS*64*4);
  float* pe     = (float*)alloc((size_t)NPTS*64*4);
  float* Khat   = (float*)alloc((size_t)NE*NM*DD*4);
  float* Vhat   = (float*)alloc((size_t)NE*NM*DD*4);
  float* featsC = (float*)alloc((size_t)NE*NPTS*DD*4);
  float* QoutC  = (float*)alloc((size_t)NE*NPTS*DD*4);  // QC then reused as outC
  float* attnWb = (float*)alloc((size_t)NE*NPTS*NTK*4);
  float* slotW  = (float*)alloc((size_t)NE*NPTS*4);
  int*   attnIb = (int*)alloc((size_t)NE*NPTS*NTK*4);
  int*   plist  = (int*)alloc((size_t)NE*NPTS*4);
  int*   pairE  = (int*)alloc((size_t)NPTS*2*4);
  int*   pairS  = (int*)alloc((size_t)NPTS*2*4);
  int*   cnt    = (int*)alloc(64);

  hipMemsetAsync(cnt, 0, 64, stream);
  k_preproc<<<NPTS/256, 256, 0, stream>>>(x, lines, Wm1, bm1, Wm2, bm2,
                                          pf, pe, slotW, plist, pairE, pairS, cnt);
  k_kv<<<dim3(NM/32, NE, 2), 256, 0, stream>>>(mem_k, mem_v, Wk, Wv, Khat, Vhat);
  k_expert<<<dim3(NPTS/16, NE), 256, 0, stream>>>(pe, We1, be1, We2, be2, We3, be3,
                                                  ln_g, ln_b, Wq, plist, cnt, featsC, QoutC);
  k_scores<<<dim3(NPTS/16, NE), 256, 0, stream>>>(QoutC, Khat, cnt, attnWb, attnIb);
  k_adapter<<<dim3(NPTS/2, NE), 256, 0, stream>>>(Vhat, pf, A1, a1, A2, a2, alng, alnb,
                                                  attnWb, attnIb, featsC, slotW, plist, cnt,
                                                  QoutC);
  k_final<<<NPTS/FR, 256, 0, stream>>>(QoutC, pairE, pairS, M1, c1, M2, c2, M3, c3, M4, c4, out);
}

// Round 3
// 4126.723 us; speedup vs baseline: 2.6187x; 2.6187x over previous
//
#include <hip/hip_runtime.h>
#include <hip/hip_bf16.h>
#include <math.h>

#define NPTS 16384
#define NE 4
#define NM 2048
#define DD 128    // D3
#define DP 64     // D1
#define NHE 256
#define NHM 256
#define NRES 64
#define NTK 16
#define NEG_INF -3.402823466e38f

// ---------- helpers ----------
__device__ __forceinline__ bool rank_gt(float av, int ai, float bv, int bi) {
  // "ranks higher in top-k": larger value, ties broken by lower index (jax top_k)
  return (av > bv) || (av == bv && ai < bi);
}

// ---------- kernel 1: per-point preproc ----------
__global__ __launch_bounds__(256) void k_preproc(
    const float* __restrict__ x, const float* __restrict__ lines,
    const float* __restrict__ Wm1, const float* __restrict__ bm1,
    const float* __restrict__ Wm2, const float* __restrict__ bm2,
    float* __restrict__ pf, float* __restrict__ pe,
    float* __restrict__ slotW, int* __restrict__ plist,
    int* __restrict__ pairE, int* __restrict__ pairS, int* __restrict__ cnt)
{
  int n = blockIdx.x * 256 + threadIdx.x;
  if (n >= NPTS) return;
  float c0 = x[n*5+0], c1 = x[n*5+1], c2 = x[n*5+2];

  // ---- gating MLP ----
  float l0 = bm2[0], l1 = bm2[1], l2 = bm2[2], l3 = bm2[3];
#pragma unroll 4
  for (int j = 0; j < 64; ++j) {
    float h = fmaf(c0, Wm1[j], fmaf(c1, Wm1[64+j], fmaf(c2, Wm1[128+j], bm1[j])));
    h = fmaxf(h, 0.f);
    l0 = fmaf(h, Wm2[j*4+0], l0);
    l1 = fmaf(h, Wm2[j*4+1], l1);
    l2 = fmaf(h, Wm2[j*4+2], l2);
    l3 = fmaf(h, Wm2[j*4+3], l3);
  }
  float lg[4] = {l0, l1, l2, l3};
  float mx = fmaxf(fmaxf(l0, l1), fmaxf(l2, l3));
  float pr[4]; float ssum = 0.f;
#pragma unroll
  for (int k = 0; k < 4; ++k) { pr[k] = expf(lg[k] - mx); ssum += pr[k]; }
#pragma unroll
  for (int k = 0; k < 4; ++k) pr[k] /= ssum;
  int i0 = 0;
#pragma unroll
  for (int k = 1; k < 4; ++k) if (pr[k] > pr[i0]) i0 = k;
  int i1 = (i0 == 0) ? 1 : 0;
#pragma unroll
  for (int k = 0; k < 4; ++k) if (k != i0 && pr[k] > pr[i1]) i1 = k;
  float g0 = pr[i0], g1 = pr[i1], gs = g0 + g1;
  g0 /= gs; g1 /= gs;
  int s0 = atomicAdd(&cnt[i0], 1);
  int s1 = atomicAdd(&cnt[i1], 1);
  plist[i0*NPTS + s0] = n; slotW[i0*NPTS + s0] = g0;
  plist[i1*NPTS + s1] = n; slotW[i1*NPTS + s1] = g1;
  pairE[n*2+0] = i0; pairE[n*2+1] = i1;
  pairS[n*2+0] = s0; pairS[n*2+1] = s1;

  // ---- positional encoding (accurate sinf/cosf: args up to 512*pi) ----
  pe[(size_t)n*64 + 0] = c0;
  pe[(size_t)n*64 + 1] = c1;
  pe[(size_t)n*64 + 2] = c2;
  float cc[3] = {c0, c1, c2};
#pragma unroll
  for (int i = 0; i < 10; ++i) {
    float sc = 3.14159274101257324f * (float)(1 << i);
#pragma unroll
    for (int j = 0; j < 3; ++j) {
      float a = sc * cc[j];
      pe[(size_t)n*64 + 3 + (i*3+j)*2 + 0] = sinf(a);
      pe[(size_t)n*64 + 3 + (i*3+j)*2 + 1] = cosf(a);
    }
  }
  pe[(size_t)n*64 + 63] = 0.f;

  // ---- param feats: product of 2 line interpolations ----
  float pfv[64];
#pragma unroll
  for (int d = 0; d < 64; ++d) pfv[d] = 1.f;
  for (int i = 0; i < 2; ++i) {
    float p = x[n*5 + 3 + i] * 63.0f;
    float f = floorf(p);
    float wfr = p - f;
    int j0 = (int)f;
    int j1 = (int)fminf(f + 1.0f, 63.0f);
    const float* L = lines + (size_t)i * 64 * 64;
#pragma unroll
    for (int d = 0; d < 64; ++d) {
      float a = L[d*64 + j0];
      float b = L[d*64 + j1];
      pfv[d] *= a + wfr * (b - a);
    }
  }
#pragma unroll
  for (int d = 0; d < 64; ++d) pf[(size_t)n*64 + d] = pfv[d];
}

// ---------- kernel 2: K/V projection ----------
__global__ __launch_bounds__(256) void k_kv(
    const float* __restrict__ mem_k, const float* __restrict__ mem_v,
    const float* __restrict__ Wk, const float* __restrict__ Wv,
    float* __restrict__ Khat, float* __restrict__ Vhat)
{
  int e = blockIdx.y;
  int which = blockIdx.z;
  const float* src = which ? mem_v : mem_k;
  const float* W   = which ? Wv : Wk;
  float* dst       = which ? Vhat : Khat;
  int r0 = blockIdx.x * 32;
  __shared__ float sm[32][130];
  int tid = threadIdx.x;
  for (int idx = tid; idx < 32*32; idx += 256) {
    int r = idx >> 5, c4 = (idx & 31) * 4;
    float4 v = *(const float4*)(src + ((size_t)e*NM + r0 + r)*DD + c4);
    sm[r][c4+0] = v.x; sm[r][c4+1] = v.y; sm[r][c4+2] = v.z; sm[r][c4+3] = v.w;
  }
  __syncthreads();
  int r = tid >> 3, cb = (tid & 7) * 16;
  float acc[16];
#pragma unroll
  for (int i = 0; i < 16; ++i) acc[i] = 0.f;
  const float* We = W + (size_t)e*DD*DD;
#pragma unroll 4
  for (int k = 0; k < 128; ++k) {
    float s = sm[r][k];
    const float4* w4 = (const float4*)(We + (size_t)k*DD + cb);
#pragma unroll
    for (int q = 0; q < 4; ++q) {
      float4 wv = w4[q];
      acc[q*4+0] = fmaf(s, wv.x, acc[q*4+0]);
      acc[q*4+1] = fmaf(s, wv.y, acc[q*4+1]);
      acc[q*4+2] = fmaf(s, wv.z, acc[q*4+2]);
      acc[q*4+3] = fmaf(s, wv.w, acc[q*4+3]);
    }
  }
  float* drow = dst + ((size_t)e*NM + r0 + r)*DD + cb;
#pragma unroll
  for (int i = 0; i < 16; ++i) drow[i] = acc[i];
}

// ---------- kernel 3: routed expert SIREN MLP + LN + Q-proj ----------
__global__ __launch_bounds__(256) void k_expert(
    const float* __restrict__ pe,
    const float* __restrict__ We1, const float* __restrict__ be1,
    const float* __restrict__ We2, const float* __restrict__ be2,
    const float* __restrict__ We3, const float* __restrict__ be3,
    const float* __restrict__ ln_g, const float* __restrict__ ln_b,
    const float* __restrict__ Wq,
    const int* __restrict__ plist, const int* __restrict__ cnt,
    float* __restrict__ featsC, float* __restrict__ QC)
{
  int e = blockIdx.y;
  int count = cnt[e];
  int base = blockIdx.x * 16;
  if (base >= count) return;
  __shared__ float peT[16][68];
  __shared__ float hA[16][260];
  __shared__ float hB[16][260];
  __shared__ float fT[16][132];
  __shared__ int pts[16];
  int tid = threadIdx.x;
  if (tid < 16) {
    int slot = base + tid;
    pts[tid] = (slot < count) ? plist[e*NPTS + slot] : 0;
  }
  __syncthreads();
  for (int idx = tid; idx < 16*16; idx += 256) {
    int r = idx >> 4, c4 = (idx & 15) * 4;
    float4 v = *(const float4*)(pe + (size_t)pts[r]*64 + c4);
    peT[r][c4+0] = v.x; peT[r][c4+1] = v.y; peT[r][c4+2] = v.z; peT[r][c4+3] = v.w;
  }
  __syncthreads();

  int row = tid >> 4;
  int c16 = (tid & 15) * 16;
  int c8  = (tid & 15) * 8;

  // layer1: 63 -> 256, sin(30*)
  {
    float acc[16];
#pragma unroll
    for (int i = 0; i < 16; ++i) acc[i] = be1[e*NHE + c16 + i];
    const float* W = We1 + (size_t)e*63*NHE;
    for (int k = 0; k < 63; ++k) {
      float s = peT[row][k];
      const float4* w4 = (const float4*)(W + (size_t)k*NHE + c16);
#pragma unroll
      for (int q = 0; q < 4; ++q) {
        float4 wv = w4[q];
        acc[q*4+0] = fmaf(s, wv.x, acc[q*4+0]);
        acc[q*4+1] = fmaf(s, wv.y, acc[q*4+1]);
        acc[q*4+2] = fmaf(s, wv.z, acc[q*4+2]);
        acc[q*4+3] = fmaf(s, wv.w, acc[q*4+3]);
      }
    }
#pragma unroll
    for (int i = 0; i < 16; ++i) hA[row][c16+i] = sinf(30.0f * acc[i]);
  }
  __syncthreads();

  // layer2: 256 -> 256, sin(30*)
  {
    float acc[16];
#pragma unroll
    for (int i = 0; i < 16; ++i) acc[i] = be2[e*NHE + c16 + i];
    const float* W = We2 + (size_t)e*NHE*NHE;
#pragma unroll 2
    for (int k = 0; k < NHE; ++k) {
      float s = hA[row][k];
      const float4* w4 = (const float4*)(W + (size_t)k*NHE + c16);
#pragma unroll
      for (int q = 0; q < 4; ++q) {
        float4 wv = w4[q];
        acc[q*4+0] = fmaf(s, wv.x, acc[q*4+0]);
        acc[q*4+1] = fmaf(s, wv.y, acc[q*4+1]);
        acc[q*4+2] = fmaf(s, wv.z, acc[q*4+2]);
        acc[q*4+3] = fmaf(s, wv.w, acc[q*4+3]);
      }
    }
#pragma unroll
    for (int i = 0; i < 16; ++i) hB[row][c16+i] = sinf(30.0f * acc[i]);
  }
  __syncthreads();

  // layer3: 256 -> 128 (no activation)
  {
    float acc[8];
#pragma unroll
    for (int i = 0; i < 8; ++i) acc[i] = be3[e*DD + c8 + i];
    const float* W = We3 + (size_t)e*NHE*DD;
#pragma unroll 2
    for (int k = 0; k < NHE; ++k) {
      float s = hB[row][k];
      const float4* w4 = (const float4*)(W + (size_t)k*DD + c8);
#pragma unroll
      for (int q = 0; q < 2; ++q) {
        float4 wv = w4[q];
        acc[q*4+0] = fmaf(s, wv.x, acc[q*4+0]);
        acc[q*4+1] = fmaf(s, wv.y, acc[q*4+1]);
        acc[q*4+2] = fmaf(s, wv.z, acc[q*4+2]);
        acc[q*4+3] = fmaf(s, wv.w, acc[q*4+3]);
      }
    }
#pragma unroll
    for (int i = 0; i < 8; ++i) fT[row][c8+i] = acc[i];
  }
  __syncthreads();

  // layernorm over 128, write q into hA[row][0..127]
  {
    float sm = 0.f, sq = 0.f;
#pragma unroll
    for (int i = 0; i < 8; ++i) {
      float v = fT[row][c8 + i];
      sm += v; sq += v * v;
    }
#pragma unroll
    for (int m = 1; m < 16; m <<= 1) { sm += __shfl_xor(sm, m); sq += __shfl_xor(sq, m); }
    float mu = sm * (1.f/128.f);
    float var = sq * (1.f/128.f) - mu*mu;
    float rs = rsqrtf(var + 1e-5f);
#pragma unroll
    for (int i = 0; i < 8; ++i) {
      int ccc = c8 + i;
      hA[row][ccc] = (fT[row][ccc] - mu) * rs * ln_g[ccc] + ln_b[ccc];
    }
  }
  __syncthreads();

  // Q = q @ Wq[e]
  {
    float acc[8];
#pragma unroll
    for (int i = 0; i < 8; ++i) acc[i] = 0.f;
    const float* W = Wq + (size_t)e*DD*DD;
#pragma unroll 4
    for (int k = 0; k < DD; ++k) {
      float s = hA[row][k];
      const float4* w4 = (const float4*)(W + (size_t)k*DD + c8);
#pragma unroll
      for (int q = 0; q < 2; ++q) {
        float4 wv = w4[q];
        acc[q*4+0] = fmaf(s, wv.x, acc[q*4+0]);
        acc[q*4+1] = fmaf(s, wv.y, acc[q*4+1]);
        acc[q*4+2] = fmaf(s, wv.z, acc[q*4+2]);
        acc[q*4+3] = fmaf(s, wv.w, acc[q*4+3]);
      }
    }
    int slot = base + row;
    if (slot < count) {
      size_t o = ((size_t)e*NPTS + slot) * DD;
#pragma unroll
      for (int i = 0; i < 8; ++i) {
        featsC[o + c8 + i] = fT[row][c8 + i];
        QC[o + c8 + i] = acc[i];
      }
    }
  }
}

// ---------- kernel 4: fused scores + wave-distributed top-16 + softmax ----------
// block: 256 threads = 4 waves; block covers 16 slots (4 per wave).
// Wave's 64 lanes: lanes 16j..16j+15 hold slot j's sorted top-16 list (desc).
// Dot phase: lane = key (2 keys per lane per 128-key chunk), 4 slot-accumulators.
// NOTE: q-loop unroll capped at 4 — full unroll (32) blew past 256 VGPR and
// spilled 18 GB of scratch traffic to HBM (round-2 post-mortem).
__global__ __launch_bounds__(256) void k_scores(
    const float* __restrict__ QC, const float* __restrict__ Khat,
    const int* __restrict__ cnt,
    float* __restrict__ attnW, int* __restrict__ attnI)
{
  int e = blockIdx.y;
  int count = cnt[e];
  int sbase = blockIdx.x * 16;
  if (sbase >= count) return;
  __shared__ float Ks[128][132];  // 128-key chunk, padded
  __shared__ float Qs[16][128];   // 16 slots' Q rows (broadcast reads)
  int tid = threadIdx.x;
  int w = tid >> 6, lane = tid & 63;

  for (int idx = tid; idx < 16*32; idx += 256) {
    int s = idx >> 5, c4 = (idx & 31) * 4;
    int slot = sbase + s;
    float4 v = make_float4(0.f, 0.f, 0.f, 0.f);
    if (slot < count) v = *(const float4*)(QC + ((size_t)e*NPTS + slot)*DD + c4);
    Qs[s][c4+0] = v.x; Qs[s][c4+1] = v.y; Qs[s][c4+2] = v.z; Qs[s][c4+3] = v.w;
  }

  // distributed top-16 state: this lane holds element (lane&15) of slot (lane>>4)'s list
  float lv = NEG_INF;
  int   li = 0x7fffffff;
  const float* Kbase = Khat + (size_t)e*NM*DD;

  for (int ch = 0; ch < NM/128; ++ch) {
    __syncthreads();
    for (int idx = tid; idx < 128*32; idx += 256) {
      int r = idx >> 5, c4 = (idx & 31) * 4;
      float4 v = *(const float4*)(Kbase + ((size_t)(ch*128 + r))*DD + c4);
      Ks[r][c4+0] = v.x; Ks[r][c4+1] = v.y; Ks[r][c4+2] = v.z; Ks[r][c4+3] = v.w;
    }
    __syncthreads();

    float acc0[4], acc1[4];
#pragma unroll
    for (int j = 0; j < 4; ++j) { acc0[j] = 0.f; acc1[j] = 0.f; }
    const float* krA = &Ks[lane][0];
    const float* krB = &Ks[64 + lane][0];
#pragma unroll 4
    for (int q = 0; q < 32; ++q) {
      float4 ka = *(const float4*)(krA + q*4);
      float4 kb = *(const float4*)(krB + q*4);
#pragma unroll
      for (int j = 0; j < 4; ++j) {
        float4 qv = *(const float4*)&Qs[w*4 + j][q*4];
        acc0[j] = fmaf(ka.x, qv.x, acc0[j]); acc0[j] = fmaf(ka.y, qv.y, acc0[j]);
        acc0[j] = fmaf(ka.z, qv.z, acc0[j]); acc0[j] = fmaf(ka.w, qv.w, acc0[j]);
        acc1[j] = fmaf(kb.x, qv.x, acc1[j]); acc1[j] = fmaf(kb.y, qv.y, acc1[j]);
        acc1[j] = fmaf(kb.z, qv.z, acc1[j]); acc1[j] = fmaf(kb.w, qv.w, acc1[j]);
      }
    }

    // threshold-gated distributed inserts
#pragma unroll
    for (int j = 0; j < 4; ++j) {
      int slot = sbase + w*4 + j;
      if (slot >= count) continue;   // wave-uniform
#pragma unroll
      for (int h = 0; h < 2; ++h) {
        float v = h ? acc1[j] : acc0[j];
        int key = ch*128 + h*64 + lane;
        float Tv = __shfl(lv, j*16 + 15);
        int   Ti = __shfl(li, j*16 + 15);
        unsigned long long mb = __ballot(rank_gt(v, key, Tv, Ti));
        while (mb) {
          int b = __ffsll((unsigned long long)mb) - 1;
          mb &= mb - 1;
          float cv = __shfl(v, b);
          int   ck = ch*128 + h*64 + b;
          Tv = __shfl(lv, j*16 + 15);
          Ti = __shfl(li, j*16 + 15);
          if (!rank_gt(cv, ck, Tv, Ti)) continue;  // stale candidate (uniform branch)
          float pv = __shfl_up(lv, 1);
          int   pi = __shfl_up(li, 1);
          int p = lane & 15;
          bool abv_me   = rank_gt(lv, li, cv, ck);
          bool abv_prev = (p == 0) || rank_gt(pv, pi, cv, ck);
          float nv = abv_me ? lv : (abv_prev ? cv : pv);
          int   ni = abv_me ? li : (abv_prev ? ck : pi);
          if ((lane >> 4) == j) { lv = nv; li = ni; }
        }
      }
    }
  }

  // softmax over each slot's sorted 16 and write out
  const float inv_scale = 0.08838834764831845f;  // 1/sqrt(128)
#pragma unroll
  for (int j = 0; j < 4; ++j) {
    int slot = sbase + w*4 + j;
    if (slot >= count) continue;
    float m = __shfl(lv, j*16 + 0);
    float ev = expf((lv - m) * inv_scale);
    float s = ev;
    s += __shfl_xor(s, 1); s += __shfl_xor(s, 2);
    s += __shfl_xor(s, 4); s += __shfl_xor(s, 8);
    if ((lane >> 4) == j) {
      size_t off = ((size_t)e*NPTS + slot)*NTK + (lane & 15);
      attnW[off] = ev / s;
      attnI[off] = li;
    }
  }
}

// ---------- kernel 5: adapter MLP + LN + attention combine ----------
__global__ __launch_bounds__(256) void k_adapter(
    const float* __restrict__ Vhat, const float* __restrict__ pf,
    const float* __restrict__ A1, const float* __restrict__ a1,
    const float* __restrict__ A2, const float* __restrict__ a2,
    const float* __restrict__ alng, const float* __restrict__ alnb,
    const float* __restrict__ attnW, const int* __restrict__ attnI,
    const float* __restrict__ featsC, const float* __restrict__ slotW,
    const int* __restrict__ plist, const int* __restrict__ cnt,
    float* __restrict__ outC)
{
  int e = blockIdx.y;
  int count = cnt[e];
  int s0 = blockIdx.x * 2;
  if (s0 >= count) return;
  __shared__ float ain[32][200];
  __shared__ float hid[32][72];
  __shared__ float accv[2][128];
  __shared__ float attw[2][16];
  __shared__ int rti[32];
  __shared__ float wsl[2];
  __shared__ int ptl[2];
  int tid = threadIdx.x;
  if (tid < 32) {
    int sl = tid >> 4, key = tid & 15;
    int slot = s0 + sl;
    if (slot < count) {
      size_t o = ((size_t)e*NPTS + slot)*NTK + key;
      rti[tid] = attnI[o];
      attw[sl][key] = attnW[o];
    } else { rti[tid] = 0; attw[sl][key] = 0.f; }
  }
  if (tid >= 32 && tid < 34) {
    int sl = tid - 32;
    int slot = s0 + sl;
    wsl[sl] = (slot < count) ? slotW[e*NPTS + slot] : 0.f;
    ptl[sl] = (slot < count) ? plist[e*NPTS + slot] : 0;
  }
  if (tid < 256) { accv[tid >> 7][tid & 127] = 0.f; }
  __syncthreads();
  // gather ain = [Vhat[ti] (128) | pf[pt] (64)]
  for (int idx = tid; idx < 32*48; idx += 256) {
    int r = idx / 48, f4 = idx - r*48;
    float4 v;
    if (f4 < 32) v = *(const float4*)(Vhat + ((size_t)e*NM + rti[r])*DD + f4*4);
    else         v = *(const float4*)(pf + (size_t)ptl[r >> 4]*64 + (f4-32)*4);
    *((float4*)&ain[r][f4*4]) = v;
  }
  __syncthreads();

  int r = tid >> 3;
  int hb = (tid & 7) * 8;
  int cb = (tid & 7) * 16;

  // hidden = relu(ain @ A1 + a1), 192 -> 64
  {
    float acc[8];
#pragma unroll
    for (int i = 0; i < 8; ++i) acc[i] = a1[e*64 + hb + i];
    const float* W = A1 + (size_t)e*192*64;
#pragma unroll 4
    for (int k = 0; k < 192; ++k) {
      float s = ain[r][k];
      const float4* w4 = (const float4*)(W + (size_t)k*64 + hb);
#pragma unroll
      for (int q = 0; q < 2; ++q) {
        float4 wv = w4[q];
        acc[q*4+0] = fmaf(s, wv.x, acc[q*4+0]);
        acc[q*4+1] = fmaf(s, wv.y, acc[q*4+1]);
        acc[q*4+2] = fmaf(s, wv.z, acc[q*4+2]);
        acc[q*4+3] = fmaf(s, wv.w, acc[q*4+3]);
      }
    }
#pragma unroll
    for (int i = 0; i < 8; ++i) hid[r][hb+i] = fmaxf(acc[i], 0.f);
  }
  __syncthreads();

  // ad = hidden @ A2 + a2, 64 -> 128; then LN; Va; weighted accumulate
  {
    float ad[16];
#pragma unroll
    for (int i = 0; i < 16; ++i) ad[i] = a2[e*DD + cb + i];
    const float* W = A2 + (size_t)e*64*DD;
#pragma unroll 4
    for (int k = 0; k < 64; ++k) {
      float s = hid[r][k];
      const float4* w4 = (const float4*)(W + (size_t)k*DD + cb);
#pragma unroll
      for (int q = 0; q < 4; ++q) {
        float4 wv = w4[q];
        ad[q*4+0] = fmaf(s, wv.x, ad[q*4+0]);
        ad[q*4+1] = fmaf(s, wv.y, ad[q*4+1]);
        ad[q*4+2] = fmaf(s, wv.z, ad[q*4+2]);
        ad[q*4+3] = fmaf(s, wv.w, ad[q*4+3]);
      }
    }
    float sm = 0.f, sq = 0.f;
#pragma unroll
    for (int i = 0; i < 16; ++i) { sm += ad[i]; sq += ad[i]*ad[i]; }
#pragma unroll
    for (int m = 1; m < 8; m <<= 1) { sm += __shfl_xor(sm, m); sq += __shfl_xor(sq, m); }
    float mu = sm * (1.f/128.f);
    float var = sq * (1.f/128.f) - mu*mu;
    float rs = rsqrtf(var + 1e-5f);
    int sl = r >> 4, key = r & 15;
    float w = attw[sl][key];
#pragma unroll
    for (int i = 0; i < 16; ++i) {
      int ccc = cb + i;
      float va = ain[r][ccc] + ((ad[i] - mu) * rs * alng[e*DD + ccc] + alnb[e*DD + ccc]);
      atomicAdd(&accv[sl][ccc], w * va);
    }
  }
  __syncthreads();
  for (int idx = tid; idx < 2*128; idx += 256) {
    int sl = idx >> 7, ccc = idx & 127;
    int slot = s0 + sl;
    if (slot < count) {
      size_t o = ((size_t)e*NPTS + slot)*DD;
      outC[o + ccc] = wsl[sl] * (accv[sl][ccc] + featsC[o + ccc]);
    }
  }
}

// ---------- kernel 6: gather pairs + final MLP + sigmoid ----------
// 32 rows/block, weights staged through LDS in 8-row chunks (2 blocks/CU).
#define FR 32
__device__ __forceinline__ void mlp_layer_f(
    const float (*X)[260], float (*Y)[260], float (*Wt)[260],
    const float* __restrict__ W, const float* __restrict__ bias,
    int K, int tid)
{
  int rg = tid >> 4;          // 16 row-groups of 2 rows
  int cg = tid & 15;          // 16 col-groups of 16 cols
  int r0 = rg * 2;
  int c16 = cg * 16;
  float acc0[16], acc1[16];
#pragma unroll
  for (int i = 0; i < 16; ++i) { acc0[i] = 0.f; acc1[i] = 0.f; }
  int nkc = K >> 3;
  for (int kc = 0; kc < nkc; ++kc) {
    __syncthreads();
    for (int idx = tid; idx < 512; idx += 256) {
      int rr = idx >> 6, c4 = (idx & 63) * 4;
      *(float4*)&Wt[rr][c4] = *(const float4*)(W + (size_t)(kc*8 + rr)*NHM + c4);
    }
    __syncthreads();
#pragma unroll
    for (int kk = 0; kk < 8; ++kk) {
      float a0 = X[r0][kc*8 + kk];
      float a1 = X[r0+1][kc*8 + kk];
#pragma unroll
      for (int q = 0; q < 4; ++q) {
        float4 wv = *(const float4*)&Wt[kk][c16 + q*4];
        acc0[q*4+0] = fmaf(a0, wv.x, acc0[q*4+0]);
        acc0[q*4+1] = fmaf(a0, wv.y, acc0[q*4+1]);
        acc0[q*4+2] = fmaf(a0, wv.z, acc0[q*4+2]);
        acc0[q*4+3] = fmaf(a0, wv.w, acc0[q*4+3]);
        acc1[q*4+0] = fmaf(a1, wv.x, acc1[q*4+0]);
        acc1[q*4+1] = fmaf(a1, wv.y, acc1[q*4+1]);
        acc1[q*4+2] = fmaf(a1, wv.z, acc1[q*4+2]);
        acc1[q*4+3] = fmaf(a1, wv.w, acc1[q*4+3]);
      }
    }
  }
  float4 b0 = *(const float4*)(bias + c16);
  float4 b1 = *(const float4*)(bias + c16 + 4);
  float4 b2 = *(const float4*)(bias + c16 + 8);
  float4 b3 = *(const float4*)(bias + c16 + 12);
  float bb[16] = {b0.x,b0.y,b0.z,b0.w, b1.x,b1.y,b1.z,b1.w,
                  b2.x,b2.y,b2.z,b2.w, b3.x,b3.y,b3.z,b3.w};
  __syncthreads();
#pragma unroll
  for (int i = 0; i < 16; ++i) {
    Y[r0][c16+i]   = fmaxf(acc0[i] + bb[i], 0.f);
    Y[r0+1][c16+i] = fmaxf(acc1[i] + bb[i], 0.f);
  }
}

__global__ __launch_bounds__(256) void k_final(
    const float* __restrict__ outC, const int* __restrict__ pairE, const int* __restrict__ pairS,
    const float* __restrict__ M1, const float* __restrict__ c1,
    const float* __restrict__ M2, const float* __restrict__ c2,
    const float* __restrict__ M3, const float* __restrict__ c3,
    const float* __restrict__ M4, const float* __restrict__ c4,
    float* __restrict__ out)
{
  int base = blockIdx.x * FR;
  __shared__ float A[FR][260];
  __shared__ float B[FR][260];
  __shared__ float Wt[8][260];
  __shared__ int prE[FR*2];
  __shared__ int prS[FR*2];
  int tid = threadIdx.x;
  if (tid < FR*2) {
    prE[tid] = pairE[(size_t)base*2 + tid];
    prS[tid] = pairS[(size_t)base*2 + tid];
  }
  __syncthreads();
  for (int idx = tid; idx < FR*32; idx += 256) {
    int rr = idx >> 5, c4 = (idx & 31) * 4;
    float4 a = *(const float4*)(outC + ((size_t)prE[rr*2+0]*NPTS + prS[rr*2+0])*DD + c4);
    float4 b = *(const float4*)(outC + ((size_t)prE[rr*2+1]*NPTS + prS[rr*2+1])*DD + c4);
    A[rr][c4+0] = a.x + b.x; A[rr][c4+1] = a.y + b.y;
    A[rr][c4+2] = a.z + b.z; A[rr][c4+3] = a.w + b.w;
  }
  // (mlp_layer_f starts with __syncthreads before staging Wt)

  mlp_layer_f(A, B, Wt, M1, c1, 128, tid);  // 128 -> 256 relu
  mlp_layer_f(B, A, Wt, M2, c2, 256, tid);  // 256 -> 256 relu
  mlp_layer_f(A, B, Wt, M3, c3, 256, tid);  // 256 -> 256 relu

  // final: dot(B_row, M4) + c4 -> sigmoid
  __syncthreads();
  {
    int rg = tid >> 4, cg = tid & 15;
    int r0 = rg * 2, c16 = cg * 16;
    float p0 = 0.f, p1 = 0.f;
#pragma unroll
    for (int q = 0; q < 4; ++q) {
      float4 mv = *(const float4*)(M4 + c16 + q*4);
      p0 = fmaf(B[r0][c16+q*4+0], mv.x, p0); p0 = fmaf(B[r0][c16+q*4+1], mv.y, p0);
      p0 = fmaf(B[r0][c16+q*4+2], mv.z, p0); p0 = fmaf(B[r0][c16+q*4+3], mv.w, p0);
      p1 = fmaf(B[r0+1][c16+q*4+0], mv.x, p1); p1 = fmaf(B[r0+1][c16+q*4+1], mv.y, p1);
      p1 = fmaf(B[r0+1][c16+q*4+2], mv.z, p1); p1 = fmaf(B[r0+1][c16+q*4+3], mv.w, p1);
    }
#pragma unroll
    for (int m = 1; m < 16; m <<= 1) {
      p0 += __shfl_xor(p0, m);
      p1 += __shfl_xor(p1, m);
    }
    if (cg == 0) {
      float z0 = p0 + c4[0];
      float z1 = p1 + c4[0];
      out[base + r0]     = 1.f / (1.f + expf(-z0));
      out[base + r0 + 1] = 1.f / (1.f + expf(-z1));
    }
  }
}

// ---------- launcher ----------
extern "C" void kernel_launch(void* const* d_in, const int* in_sizes, int n_in,
                              void* d_out, int out_size, void* d_ws, size_t ws_size,
                              hipStream_t stream)
{
  const float* x    = (const float*)d_in[0];
  const float* lines= (const float*)d_in[1];
  const float* Wm1  = (const float*)d_in[2];
  const float* bm1  = (const float*)d_in[3];
  const float* Wm2  = (const float*)d_in[4];
  const float* bm2  = (const float*)d_in[5];
  const float* We1  = (const float*)d_in[6];
  const float* be1  = (const float*)d_in[7];
  const float* We2  = (const float*)d_in[8];
  const float* be2  = (const float*)d_in[9];
  const float* We3  = (const float*)d_in[10];
  const float* be3  = (const float*)d_in[11];
  const float* ln_g = (const float*)d_in[12];
  const float* ln_b = (const float*)d_in[13];
  const float* Wq   = (const float*)d_in[14];
  const float* Wk   = (const float*)d_in[15];
  const float* Wv   = (const float*)d_in[16];
  const float* A1   = (const float*)d_in[17];
  const float* a1   = (const float*)d_in[18];
  const float* A2   = (const float*)d_in[19];
  const float* a2   = (const float*)d_in[20];
  const float* alng = (const float*)d_in[21];
  const float* alnb = (const float*)d_in[22];
  const float* mem_k= (const float*)d_in[23];
  const float* mem_v= (const float*)d_in[24];
  const float* M1   = (const float*)d_in[25];
  const float* c1   = (const float*)d_in[26];
  const float* M2   = (const float*)d_in[27];
  const float* c2   = (const float*)d_in[28];
  const float* M3   = (const float*)d_in[29];
  const float* c3   = (const float*)d_in[30];
  const float* M4   = (const float*)d_in[31];
  const float* c4   = (const float*)d_in[32];
  float* out = (float*)d_out;

  char* wp = (char*)d_ws;
  auto alloc = [&](size_t bytes) -> void* {
    void* p = (void*)wp;
    wp += (bytes + 255) & ~(size_t)255;
    return p;
  };
  float* pf     = (float*)alloc((size_t)NPTS*64*4);
  float* pe     = (float*)alloc((size_t)NPTS*64*4);
  float* Khat   = (float*)alloc((size_t)NE*NM*DD*4);
  float* Vhat   = (float*)alloc((size_t)NE*NM*DD*4);
  float* featsC = (float*)alloc((size_t)NE*NPTS*DD*4);
  float* QoutC  = (float*)alloc((size_t)NE*NPTS*DD*4);  // QC then reused as outC
  float* attnWb = (float*)alloc((size_t)NE*NPTS*NTK*4);
  float* slotW  = (float*)alloc((size_t)NE*NPTS*4);
  int*   attnIb = (int*)alloc((size_t)NE*NPTS*NTK*4);
  int*   plist  = (int*)alloc((size_t)NE*NPTS*4);
  int*   pairE  = (int*)alloc((size_t)NPTS*2*4);
  int*   pairS  = (int*)alloc((size_t)NPTS*2*4);
  int*   cnt    = (int*)alloc(64);

  hipMemsetAsync(cnt, 0, 64, stream);
  k_preproc<<<NPTS/256, 256, 0, stream>>>(x, lines, Wm1, bm1, Wm2, bm2,
                                          pf, pe, slotW, plist, pairE, pairS, cnt);
  k_kv<<<dim3(NM/32, NE, 2), 256, 0, stream>>>(mem_k, mem_v, Wk, Wv, Khat, Vhat);
  k_expert<<<dim3(NPTS/16, NE), 256, 0, stream>>>(pe, We1, be1, We2, be2, We3, be3,
                                                  ln_g, ln_b, Wq, plist, cnt, featsC, QoutC);
  k_scores<<<dim3(NPTS/16, NE), 256, 0, stream>>>(QoutC, Khat, cnt, attnWb, attnIb);
  k_adapter<<<dim3(NPTS/2, NE), 256, 0, stream>>>(Vhat, pf, A1, a1, A2, a2, alng, alnb,
                                                  attnWb, attnIb, featsC, slotW, plist, cnt,
                                                  QoutC);
  k_final<<<NPTS/FR, 256, 0, stream>>>(QoutC, pairE, pairS, M1, c1, M2, c2, M3, c3, M4, c4, out);
}

// Round 4
// 2666.289 us; speedup vs baseline: 4.0531x; 1.5477x over previous
//
#include <hip/hip_runtime.h>
#include <hip/hip_bf16.h>
#include <math.h>

#define NPTS 16384
#define NE 4
#define NM 2048
#define DD 128    // D3
#define DP 64     // D1
#define NHE 256
#define NHM 256
#define NRES 64
#define NTK 16
#define NEG_INF -3.402823466e38f

// ---------- helpers ----------
__device__ __forceinline__ bool rank_gt(float av, int ai, float bv, int bi) {
  // "ranks higher in top-k": larger value, ties broken by lower index (jax top_k)
  return (av > bv) || (av == bv && ai < bi);
}

// ---------- kernel 1: per-point preproc ----------
__global__ __launch_bounds__(256) void k_preproc(
    const float* __restrict__ x, const float* __restrict__ lines,
    const float* __restrict__ Wm1, const float* __restrict__ bm1,
    const float* __restrict__ Wm2, const float* __restrict__ bm2,
    float* __restrict__ pf, float* __restrict__ pe,
    float* __restrict__ slotW, int* __restrict__ plist,
    int* __restrict__ pairE, int* __restrict__ pairS, int* __restrict__ cnt)
{
  int n = blockIdx.x * 256 + threadIdx.x;
  if (n >= NPTS) return;
  float c0 = x[n*5+0], c1 = x[n*5+1], c2 = x[n*5+2];

  // ---- gating MLP ----
  float l0 = bm2[0], l1 = bm2[1], l2 = bm2[2], l3 = bm2[3];
#pragma unroll 4
  for (int j = 0; j < 64; ++j) {
    float h = fmaf(c0, Wm1[j], fmaf(c1, Wm1[64+j], fmaf(c2, Wm1[128+j], bm1[j])));
    h = fmaxf(h, 0.f);
    l0 = fmaf(h, Wm2[j*4+0], l0);
    l1 = fmaf(h, Wm2[j*4+1], l1);
    l2 = fmaf(h, Wm2[j*4+2], l2);
    l3 = fmaf(h, Wm2[j*4+3], l3);
  }
  float lg[4] = {l0, l1, l2, l3};
  float mx = fmaxf(fmaxf(l0, l1), fmaxf(l2, l3));
  float pr[4]; float ssum = 0.f;
#pragma unroll
  for (int k = 0; k < 4; ++k) { pr[k] = expf(lg[k] - mx); ssum += pr[k]; }
#pragma unroll
  for (int k = 0; k < 4; ++k) pr[k] /= ssum;
  int i0 = 0;
#pragma unroll
  for (int k = 1; k < 4; ++k) if (pr[k] > pr[i0]) i0 = k;
  int i1 = (i0 == 0) ? 1 : 0;
#pragma unroll
  for (int k = 0; k < 4; ++k) if (k != i0 && pr[k] > pr[i1]) i1 = k;
  float g0 = pr[i0], g1 = pr[i1], gs = g0 + g1;
  g0 /= gs; g1 /= gs;
  int s0 = atomicAdd(&cnt[i0], 1);
  int s1 = atomicAdd(&cnt[i1], 1);
  plist[i0*NPTS + s0] = n; slotW[i0*NPTS + s0] = g0;
  plist[i1*NPTS + s1] = n; slotW[i1*NPTS + s1] = g1;
  pairE[n*2+0] = i0; pairE[n*2+1] = i1;
  pairS[n*2+0] = s0; pairS[n*2+1] = s1;

  // ---- positional encoding (accurate sinf/cosf: args up to 512*pi) ----
  pe[(size_t)n*64 + 0] = c0;
  pe[(size_t)n*64 + 1] = c1;
  pe[(size_t)n*64 + 2] = c2;
  float cc[3] = {c0, c1, c2};
#pragma unroll
  for (int i = 0; i < 10; ++i) {
    float sc = 3.14159274101257324f * (float)(1 << i);
#pragma unroll
    for (int j = 0; j < 3; ++j) {
      float a = sc * cc[j];
      pe[(size_t)n*64 + 3 + (i*3+j)*2 + 0] = sinf(a);
      pe[(size_t)n*64 + 3 + (i*3+j)*2 + 1] = cosf(a);
    }
  }
  pe[(size_t)n*64 + 63] = 0.f;

  // ---- param feats: product of 2 line interpolations ----
  float pfv[64];
#pragma unroll
  for (int d = 0; d < 64; ++d) pfv[d] = 1.f;
  for (int i = 0; i < 2; ++i) {
    float p = x[n*5 + 3 + i] * 63.0f;
    float f = floorf(p);
    float wfr = p - f;
    int j0 = (int)f;
    int j1 = (int)fminf(f + 1.0f, 63.0f);
    const float* L = lines + (size_t)i * 64 * 64;
#pragma unroll
    for (int d = 0; d < 64; ++d) {
      float a = L[d*64 + j0];
      float b = L[d*64 + j1];
      pfv[d] *= a + wfr * (b - a);
    }
  }
#pragma unroll
  for (int d = 0; d < 64; ++d) pf[(size_t)n*64 + d] = pfv[d];
}

// ---------- kernel 2: K/V projection ----------
__global__ __launch_bounds__(256) void k_kv(
    const float* __restrict__ mem_k, const float* __restrict__ mem_v,
    const float* __restrict__ Wk, const float* __restrict__ Wv,
    float* __restrict__ Khat, float* __restrict__ Vhat)
{
  int e = blockIdx.y;
  int which = blockIdx.z;
  const float* src = which ? mem_v : mem_k;
  const float* W   = which ? Wv : Wk;
  float* dst       = which ? Vhat : Khat;
  int r0 = blockIdx.x * 32;
  __shared__ float sm[32][130];
  int tid = threadIdx.x;
  for (int idx = tid; idx < 32*32; idx += 256) {
    int r = idx >> 5, c4 = (idx & 31) * 4;
    float4 v = *(const float4*)(src + ((size_t)e*NM + r0 + r)*DD + c4);
    sm[r][c4+0] = v.x; sm[r][c4+1] = v.y; sm[r][c4+2] = v.z; sm[r][c4+3] = v.w;
  }
  __syncthreads();
  int r = tid >> 3, cb = (tid & 7) * 16;
  float acc[16];
#pragma unroll
  for (int i = 0; i < 16; ++i) acc[i] = 0.f;
  const float* We = W + (size_t)e*DD*DD;
#pragma unroll 4
  for (int k = 0; k < 128; ++k) {
    float s = sm[r][k];
    const float4* w4 = (const float4*)(We + (size_t)k*DD + cb);
#pragma unroll
    for (int q = 0; q < 4; ++q) {
      float4 wv = w4[q];
      acc[q*4+0] = fmaf(s, wv.x, acc[q*4+0]);
      acc[q*4+1] = fmaf(s, wv.y, acc[q*4+1]);
      acc[q*4+2] = fmaf(s, wv.z, acc[q*4+2]);
      acc[q*4+3] = fmaf(s, wv.w, acc[q*4+3]);
    }
  }
  float* drow = dst + ((size_t)e*NM + r0 + r)*DD + cb;
#pragma unroll
  for (int i = 0; i < 16; ++i) drow[i] = acc[i];
}

// ---------- kernel 3: routed expert SIREN MLP + LN + Q-proj (LDS-staged weights) ----------
// 32 slots/block; 256 threads: rg=tid>>4 -> 2 rows, cg=tid&15 -> 16 (or 8) cols.
// All weight matrices stream through a shared Wt chunk buffer (coalesced co-op loads),
// fixing the per-thread L2-latency weight restream (R3: VALUBusy 7.7%, 41ms flush-replay).
__global__ __launch_bounds__(256) void k_expert(
    const float* __restrict__ pe,
    const float* __restrict__ We1, const float* __restrict__ be1,
    const float* __restrict__ We2, const float* __restrict__ be2,
    const float* __restrict__ We3, const float* __restrict__ be3,
    const float* __restrict__ ln_g, const float* __restrict__ ln_b,
    const float* __restrict__ Wq,
    const int* __restrict__ plist, const int* __restrict__ cnt,
    float* __restrict__ featsC, float* __restrict__ QC)
{
  int e = blockIdx.y;
  int count = cnt[e];
  int base = blockIdx.x * 32;
  if (base >= count) return;
  __shared__ float A[32][260];
  __shared__ float B[32][260];
  __shared__ float Wt[2176];
  __shared__ int pts[32];
  int tid = threadIdx.x;
  if (tid < 32) {
    int slot = base + tid;
    pts[tid] = (slot < count) ? plist[e*NPTS + slot] : 0;
  }
  __syncthreads();
  // pe rows into A[r][0..63]
  for (int idx = tid; idx < 32*16; idx += 256) {
    int rr = idx >> 4, c4 = (idx & 15) * 4;
    *(float4*)&A[rr][c4] = *(const float4*)(pe + (size_t)pts[rr]*64 + c4);
  }
  int rg = tid >> 4, cg = tid & 15;
  int r0 = rg*2, r1 = r0+1, c16 = cg*16, c8 = cg*8;
  int slot0 = base + r0, slot1 = base + r1;

  float acc0[16], acc1[16];

  // ---- L1: 63 -> 256, sin(30x): A[.][0..62] -> B ----
  {
    const float* be = be1 + e*NHE;
#pragma unroll
    for (int i = 0; i < 16; ++i) { acc0[i] = be[c16+i]; acc1[i] = acc0[i]; }
    const float* W = We1 + (size_t)e*63*NHE;
    for (int kc = 0; kc < 8; ++kc) {
      int kbase = kc*8;
      int rows = (kc == 7) ? 7 : 8;
      __syncthreads();
      for (int idx = tid; idx < rows*64; idx += 256) {
        int kk = idx >> 6, c4 = (idx & 63) * 4;
        *(float4*)&Wt[kk*260 + c4] = *(const float4*)(W + (size_t)(kbase+kk)*NHE + c4);
      }
      __syncthreads();
      for (int kk = 0; kk < rows; ++kk) {
        float a0 = A[r0][kbase+kk], a1v = A[r1][kbase+kk];
        const float* wr = &Wt[kk*260 + c16];
#pragma unroll
        for (int q = 0; q < 4; ++q) {
          float4 wv = *(const float4*)(wr + q*4);
          acc0[q*4+0] = fmaf(a0, wv.x, acc0[q*4+0]);
          acc0[q*4+1] = fmaf(a0, wv.y, acc0[q*4+1]);
          acc0[q*4+2] = fmaf(a0, wv.z, acc0[q*4+2]);
          acc0[q*4+3] = fmaf(a0, wv.w, acc0[q*4+3]);
          acc1[q*4+0] = fmaf(a1v, wv.x, acc1[q*4+0]);
          acc1[q*4+1] = fmaf(a1v, wv.y, acc1[q*4+1]);
          acc1[q*4+2] = fmaf(a1v, wv.z, acc1[q*4+2]);
          acc1[q*4+3] = fmaf(a1v, wv.w, acc1[q*4+3]);
        }
      }
    }
#pragma unroll
    for (int i = 0; i < 16; ++i) {
      B[r0][c16+i] = sinf(30.0f*acc0[i]);
      B[r1][c16+i] = sinf(30.0f*acc1[i]);
    }
  }

  // ---- L2: 256 -> 256, sin(30x): B -> A ----
  {
    const float* be = be2 + e*NHE;
#pragma unroll
    for (int i = 0; i < 16; ++i) { acc0[i] = be[c16+i]; acc1[i] = acc0[i]; }
    const float* W = We2 + (size_t)e*NHE*NHE;
    for (int kc = 0; kc < 32; ++kc) {
      __syncthreads();
      for (int idx = tid; idx < 512; idx += 256) {
        int kk = idx >> 6, c4 = (idx & 63) * 4;
        *(float4*)&Wt[kk*260 + c4] = *(const float4*)(W + (size_t)(kc*8+kk)*NHE + c4);
      }
      __syncthreads();
#pragma unroll
      for (int kk = 0; kk < 8; ++kk) {
        float a0 = B[r0][kc*8+kk], a1v = B[r1][kc*8+kk];
        const float* wr = &Wt[kk*260 + c16];
#pragma unroll
        for (int q = 0; q < 4; ++q) {
          float4 wv = *(const float4*)(wr + q*4);
          acc0[q*4+0] = fmaf(a0, wv.x, acc0[q*4+0]);
          acc0[q*4+1] = fmaf(a0, wv.y, acc0[q*4+1]);
          acc0[q*4+2] = fmaf(a0, wv.z, acc0[q*4+2]);
          acc0[q*4+3] = fmaf(a0, wv.w, acc0[q*4+3]);
          acc1[q*4+0] = fmaf(a1v, wv.x, acc1[q*4+0]);
          acc1[q*4+1] = fmaf(a1v, wv.y, acc1[q*4+1]);
          acc1[q*4+2] = fmaf(a1v, wv.z, acc1[q*4+2]);
          acc1[q*4+3] = fmaf(a1v, wv.w, acc1[q*4+3]);
        }
      }
    }
#pragma unroll
    for (int i = 0; i < 16; ++i) {
      A[r0][c16+i] = sinf(30.0f*acc0[i]);
      A[r1][c16+i] = sinf(30.0f*acc1[i]);
    }
  }

  // ---- L3: 256 -> 128 linear: A -> feats (regs) ----
  float f0[8], f1[8];
  {
    const float* be = be3 + e*DD;
#pragma unroll
    for (int i = 0; i < 8; ++i) { f0[i] = be[c8+i]; f1[i] = f0[i]; }
    const float* W = We3 + (size_t)e*NHE*DD;
    for (int kc = 0; kc < 16; ++kc) {
      __syncthreads();
      for (int idx = tid; idx < 512; idx += 256) {
        int kk = idx >> 5, c4 = (idx & 31) * 4;
        *(float4*)&Wt[kk*132 + c4] = *(const float4*)(W + (size_t)(kc*16+kk)*DD + c4);
      }
      __syncthreads();
#pragma unroll
      for (int kk = 0; kk < 16; ++kk) {
        float a0 = A[r0][kc*16+kk], a1v = A[r1][kc*16+kk];
        const float* wr = &Wt[kk*132 + c8];
#pragma unroll
        for (int q = 0; q < 2; ++q) {
          float4 wv = *(const float4*)(wr + q*4);
          f0[q*4+0] = fmaf(a0, wv.x, f0[q*4+0]);
          f0[q*4+1] = fmaf(a0, wv.y, f0[q*4+1]);
          f0[q*4+2] = fmaf(a0, wv.z, f0[q*4+2]);
          f0[q*4+3] = fmaf(a0, wv.w, f0[q*4+3]);
          f1[q*4+0] = fmaf(a1v, wv.x, f1[q*4+0]);
          f1[q*4+1] = fmaf(a1v, wv.y, f1[q*4+1]);
          f1[q*4+2] = fmaf(a1v, wv.z, f1[q*4+2]);
          f1[q*4+3] = fmaf(a1v, wv.w, f1[q*4+3]);
        }
      }
    }
  }

  // ---- LN (register + cg-shuffle) -> q into B[r][128..255]; feats to global ----
  {
    float sm0=0.f, sq0=0.f, sm1=0.f, sq1=0.f;
#pragma unroll
    for (int i = 0; i < 8; ++i) {
      sm0 += f0[i]; sq0 += f0[i]*f0[i];
      sm1 += f1[i]; sq1 += f1[i]*f1[i];
    }
#pragma unroll
    for (int m = 1; m < 16; m <<= 1) {
      sm0 += __shfl_xor(sm0, m); sq0 += __shfl_xor(sq0, m);
      sm1 += __shfl_xor(sm1, m); sq1 += __shfl_xor(sq1, m);
    }
    float mu0 = sm0*(1.f/128.f), mu1 = sm1*(1.f/128.f);
    float rs0 = rsqrtf(sq0*(1.f/128.f) - mu0*mu0 + 1e-5f);
    float rs1 = rsqrtf(sq1*(1.f/128.f) - mu1*mu1 + 1e-5f);
#pragma unroll
    for (int i = 0; i < 8; ++i) {
      float g = ln_g[c8+i], b = ln_b[c8+i];
      B[r0][128+c8+i] = (f0[i]-mu0)*rs0*g + b;
      B[r1][128+c8+i] = (f1[i]-mu1)*rs1*g + b;
    }
    if (slot0 < count) {
      size_t o = ((size_t)e*NPTS + slot0)*DD;
#pragma unroll
      for (int i = 0; i < 8; ++i) featsC[o + c8 + i] = f0[i];
    }
    if (slot1 < count) {
      size_t o = ((size_t)e*NPTS + slot1)*DD;
#pragma unroll
      for (int i = 0; i < 8; ++i) featsC[o + c8 + i] = f1[i];
    }
  }

  // ---- Wq: q(128) -> Q(128): B[.][128..255] -> QC ----
  {
    float g0[8], g1[8];
#pragma unroll
    for (int i = 0; i < 8; ++i) { g0[i] = 0.f; g1[i] = 0.f; }
    const float* W = Wq + (size_t)e*DD*DD;
    for (int kc = 0; kc < 8; ++kc) {
      __syncthreads();
      for (int idx = tid; idx < 512; idx += 256) {
        int kk = idx >> 5, c4 = (idx & 31) * 4;
        *(float4*)&Wt[kk*132 + c4] = *(const float4*)(W + (size_t)(kc*16+kk)*DD + c4);
      }
      __syncthreads();
#pragma unroll
      for (int kk = 0; kk < 16; ++kk) {
        float a0 = B[r0][128+kc*16+kk], a1v = B[r1][128+kc*16+kk];
        const float* wr = &Wt[kk*132 + c8];
#pragma unroll
        for (int q = 0; q < 2; ++q) {
          float4 wv = *(const float4*)(wr + q*4);
          g0[q*4+0] = fmaf(a0, wv.x, g0[q*4+0]);
          g0[q*4+1] = fmaf(a0, wv.y, g0[q*4+1]);
          g0[q*4+2] = fmaf(a0, wv.z, g0[q*4+2]);
          g0[q*4+3] = fmaf(a0, wv.w, g0[q*4+3]);
          g1[q*4+0] = fmaf(a1v, wv.x, g1[q*4+0]);
          g1[q*4+1] = fmaf(a1v, wv.y, g1[q*4+1]);
          g1[q*4+2] = fmaf(a1v, wv.z, g1[q*4+2]);
          g1[q*4+3] = fmaf(a1v, wv.w, g1[q*4+3]);
        }
      }
    }
    if (slot0 < count) {
      size_t o = ((size_t)e*NPTS + slot0)*DD;
#pragma unroll
      for (int i = 0; i < 8; ++i) QC[o + c8 + i] = g0[i];
    }
    if (slot1 < count) {
      size_t o = ((size_t)e*NPTS + slot1)*DD;
#pragma unroll
      for (int i = 0; i < 8; ++i) QC[o + c8 + i] = g1[i];
    }
  }
}

// ---------- kernel 4: fused scores + wave-distributed top-16 + softmax ----------
// NOTE: q-loop unroll capped at 4 — full unroll blew past 256 VGPR (R2 post-mortem).
__global__ __launch_bounds__(256) void k_scores(
    const float* __restrict__ QC, const float* __restrict__ Khat,
    const int* __restrict__ cnt,
    float* __restrict__ attnW, int* __restrict__ attnI)
{
  int e = blockIdx.y;
  int count = cnt[e];
  int sbase = blockIdx.x * 16;
  if (sbase >= count) return;
  __shared__ float Ks[128][132];
  __shared__ float Qs[16][128];
  int tid = threadIdx.x;
  int w = tid >> 6, lane = tid & 63;

  for (int idx = tid; idx < 16*32; idx += 256) {
    int s = idx >> 5, c4 = (idx & 31) * 4;
    int slot = sbase + s;
    float4 v = make_float4(0.f, 0.f, 0.f, 0.f);
    if (slot < count) v = *(const float4*)(QC + ((size_t)e*NPTS + slot)*DD + c4);
    Qs[s][c4+0] = v.x; Qs[s][c4+1] = v.y; Qs[s][c4+2] = v.z; Qs[s][c4+3] = v.w;
  }

  float lv = NEG_INF;
  int   li = 0x7fffffff;
  const float* Kbase = Khat + (size_t)e*NM*DD;

  for (int ch = 0; ch < NM/128; ++ch) {
    __syncthreads();
    for (int idx = tid; idx < 128*32; idx += 256) {
      int r = idx >> 5, c4 = (idx & 31) * 4;
      float4 v = *(const float4*)(Kbase + ((size_t)(ch*128 + r))*DD + c4);
      Ks[r][c4+0] = v.x; Ks[r][c4+1] = v.y; Ks[r][c4+2] = v.z; Ks[r][c4+3] = v.w;
    }
    __syncthreads();

    float acc0[4], acc1[4];
#pragma unroll
    for (int j = 0; j < 4; ++j) { acc0[j] = 0.f; acc1[j] = 0.f; }
    const float* krA = &Ks[lane][0];
    const float* krB = &Ks[64 + lane][0];
#pragma unroll 4
    for (int q = 0; q < 32; ++q) {
      float4 ka = *(const float4*)(krA + q*4);
      float4 kb = *(const float4*)(krB + q*4);
#pragma unroll
      for (int j = 0; j < 4; ++j) {
        float4 qv = *(const float4*)&Qs[w*4 + j][q*4];
        acc0[j] = fmaf(ka.x, qv.x, acc0[j]); acc0[j] = fmaf(ka.y, qv.y, acc0[j]);
        acc0[j] = fmaf(ka.z, qv.z, acc0[j]); acc0[j] = fmaf(ka.w, qv.w, acc0[j]);
        acc1[j] = fmaf(kb.x, qv.x, acc1[j]); acc1[j] = fmaf(kb.y, qv.y, acc1[j]);
        acc1[j] = fmaf(kb.z, qv.z, acc1[j]); acc1[j] = fmaf(kb.w, qv.w, acc1[j]);
      }
    }

#pragma unroll
    for (int j = 0; j < 4; ++j) {
      int slot = sbase + w*4 + j;
      if (slot >= count) continue;
#pragma unroll
      for (int h = 0; h < 2; ++h) {
        float v = h ? acc1[j] : acc0[j];
        int key = ch*128 + h*64 + lane;
        float Tv = __shfl(lv, j*16 + 15);
        int   Ti = __shfl(li, j*16 + 15);
        unsigned long long mb = __ballot(rank_gt(v, key, Tv, Ti));
        while (mb) {
          int b = __ffsll((unsigned long long)mb) - 1;
          mb &= mb - 1;
          float cv = __shfl(v, b);
          int   ck = ch*128 + h*64 + b;
          Tv = __shfl(lv, j*16 + 15);
          Ti = __shfl(li, j*16 + 15);
          if (!rank_gt(cv, ck, Tv, Ti)) continue;
          float pv = __shfl_up(lv, 1);
          int   pi = __shfl_up(li, 1);
          int p = lane & 15;
          bool abv_me   = rank_gt(lv, li, cv, ck);
          bool abv_prev = (p == 0) || rank_gt(pv, pi, cv, ck);
          float nv = abv_me ? lv : (abv_prev ? cv : pv);
          int   ni = abv_me ? li : (abv_prev ? ck : pi);
          if ((lane >> 4) == j) { lv = nv; li = ni; }
        }
      }
    }
  }

  const float inv_scale = 0.08838834764831845f;  // 1/sqrt(128)
#pragma unroll
  for (int j = 0; j < 4; ++j) {
    int slot = sbase + w*4 + j;
    if (slot >= count) continue;
    float m = __shfl(lv, j*16 + 0);
    float ev = expf((lv - m) * inv_scale);
    float s = ev;
    s += __shfl_xor(s, 1); s += __shfl_xor(s, 2);
    s += __shfl_xor(s, 4); s += __shfl_xor(s, 8);
    if ((lane >> 4) == j) {
      size_t off = ((size_t)e*NPTS + slot)*NTK + (lane & 15);
      attnW[off] = ev / s;
      attnI[off] = li;
    }
  }
}

// ---------- kernel 5: adapter MLP + LN + attention combine (wave=slot) ----------
// 4 slots/block, 1 wave per slot; lane = (key<<2)|colgroup. A1/A2 staged through
// LDS chunks; per-key weighted sum via shfl_xor over key-lanes (no LDS atomics).
__global__ __launch_bounds__(256) void k_adapter(
    const float* __restrict__ Vhat, const float* __restrict__ pf,
    const float* __restrict__ A1, const float* __restrict__ a1,
    const float* __restrict__ A2, const float* __restrict__ a2,
    const float* __restrict__ alng, const float* __restrict__ alnb,
    const float* __restrict__ attnW, const int* __restrict__ attnI,
    const float* __restrict__ featsC, const float* __restrict__ slotW,
    const int* __restrict__ plist, const int* __restrict__ cnt,
    float* __restrict__ outC)
{
  int e = blockIdx.y;
  int count = cnt[e];
  int s0 = blockIdx.x * 4;
  if (s0 >= count) return;
  __shared__ float ainV[64][132];   // 4 slots x 16 keys of Vhat rows
  __shared__ float pfS[4][68];      // per-slot param feats
  __shared__ float hid[64][68];
  __shared__ float Wt[2176];
  __shared__ float attwS[4][16];
  __shared__ float alnS[132], albS[132];
  __shared__ int   rtiS[64];
  __shared__ float wslS[4];
  __shared__ int   ptlS[4];
  int tid = threadIdx.x;
  if (tid < 64) {
    int sl = tid >> 4, key = tid & 15;
    int slot = s0 + sl;
    if (slot < count) {
      size_t o = ((size_t)e*NPTS + slot)*NTK + key;
      rtiS[tid] = attnI[o];
      attwS[sl][key] = attnW[o];
    } else { rtiS[tid] = 0; attwS[sl][key] = 0.f; }
  } else if (tid < 68) {
    int sl = tid - 64;
    int slot = s0 + sl;
    wslS[sl] = (slot < count) ? slotW[e*NPTS + slot] : 0.f;
    ptlS[sl] = (slot < count) ? plist[e*NPTS + slot] : 0;
  } else if (tid >= 128 && tid < 192) {
    int c2 = (tid - 128) * 2;
    alnS[c2]   = alng[e*DD + c2];
    alnS[c2+1] = alng[e*DD + c2+1];
    albS[c2]   = alnb[e*DD + c2];
    albS[c2+1] = alnb[e*DD + c2+1];
  }
  __syncthreads();
  for (int idx = tid; idx < 64*32; idx += 256) {
    int r = idx >> 5, c4 = (idx & 31) * 4;
    *(float4*)&ainV[r][c4] = *(const float4*)(Vhat + ((size_t)e*NM + rtiS[r])*DD + c4);
  }
  if (tid < 64) {
    int sl = tid >> 4, c4 = (tid & 15) * 4;
    *(float4*)&pfS[sl][c4] = *(const float4*)(pf + (size_t)ptlS[sl]*64 + c4);
  }

  int lane = tid & 63;
  int wv = tid >> 6;        // slot within block
  int key = lane >> 2;
  int cg  = lane & 3;
  int r   = wv*16 + key;
  int slot = s0 + wv;

  // ---- L1: 192 -> 64, relu. acc cols = cg*16..+16 ----
  float acc[16];
  const float* a1e = a1 + e*64;
#pragma unroll
  for (int i = 0; i < 16; ++i) acc[i] = a1e[cg*16 + i];
  const float* A1e = A1 + (size_t)e*192*64;
  for (int kc = 0; kc < 12; ++kc) {
    __syncthreads();
    { int kk = tid >> 4, c4 = (tid & 15) * 4;
      *(float4*)&Wt[kk*68 + c4] = *(const float4*)(A1e + (size_t)(kc*16+kk)*64 + c4); }
    __syncthreads();
#pragma unroll
    for (int kk = 0; kk < 16; ++kk) {
      float s = (kc < 8) ? ainV[r][kc*16+kk] : pfS[wv][kc*16+kk-128];
      const float* wr = &Wt[kk*68 + cg*16];
#pragma unroll
      for (int q = 0; q < 4; ++q) {
        float4 wv4 = *(const float4*)(wr + q*4);
        acc[q*4+0] = fmaf(s, wv4.x, acc[q*4+0]);
        acc[q*4+1] = fmaf(s, wv4.y, acc[q*4+1]);
        acc[q*4+2] = fmaf(s, wv4.z, acc[q*4+2]);
        acc[q*4+3] = fmaf(s, wv4.w, acc[q*4+3]);
      }
    }
  }
  __syncthreads();
#pragma unroll
  for (int q = 0; q < 4; ++q) {
    float4 hv;
    hv.x = fmaxf(acc[q*4+0], 0.f); hv.y = fmaxf(acc[q*4+1], 0.f);
    hv.z = fmaxf(acc[q*4+2], 0.f); hv.w = fmaxf(acc[q*4+3], 0.f);
    *(float4*)&hid[r][cg*16 + q*4] = hv;
  }

  // ---- L2: 64 -> 128 (+bias), 2 col passes; LN via shuffles ----
  float adA[16], adB[16];
  const float* a2e = a2 + e*DD;
  int cA = cg*16, cB = 64 + cg*16;
#pragma unroll
  for (int i = 0; i < 16; ++i) { adA[i] = a2e[cA+i]; adB[i] = a2e[cB+i]; }
  const float* A2e = A2 + (size_t)e*64*DD;
  for (int kc = 0; kc < 4; ++kc) {
    __syncthreads();
    for (int idx = tid; idx < 512; idx += 256) {
      int kk = idx >> 5, c4 = (idx & 31) * 4;
      *(float4*)&Wt[kk*132 + c4] = *(const float4*)(A2e + (size_t)(kc*16+kk)*DD + c4);
    }
    __syncthreads();
#pragma unroll
    for (int kk = 0; kk < 16; ++kk) {
      float s = hid[r][kc*16+kk];
      const float* wrA = &Wt[kk*132 + cA];
      const float* wrB = &Wt[kk*132 + cB];
#pragma unroll
      for (int q = 0; q < 4; ++q) {
        float4 wa = *(const float4*)(wrA + q*4);
        float4 wb = *(const float4*)(wrB + q*4);
        adA[q*4+0] = fmaf(s, wa.x, adA[q*4+0]);
        adA[q*4+1] = fmaf(s, wa.y, adA[q*4+1]);
        adA[q*4+2] = fmaf(s, wa.z, adA[q*4+2]);
        adA[q*4+3] = fmaf(s, wa.w, adA[q*4+3]);
        adB[q*4+0] = fmaf(s, wb.x, adB[q*4+0]);
        adB[q*4+1] = fmaf(s, wb.y, adB[q*4+1]);
        adB[q*4+2] = fmaf(s, wb.z, adB[q*4+2]);
        adB[q*4+3] = fmaf(s, wb.w, adB[q*4+3]);
      }
    }
  }
  // LN stats over 128 (own 32 + 4 cg-lanes)
  float sm = 0.f, sq = 0.f;
#pragma unroll
  for (int i = 0; i < 16; ++i) {
    sm += adA[i] + adB[i];
    sq += adA[i]*adA[i] + adB[i]*adB[i];
  }
  sm += __shfl_xor(sm, 1); sq += __shfl_xor(sq, 1);
  sm += __shfl_xor(sm, 2); sq += __shfl_xor(sq, 2);
  float mu = sm * (1.f/128.f);
  float var = sq * (1.f/128.f) - mu*mu;
  float rs = rsqrtf(var + 1e-5f);

  // Va = Vt + LN(ad)*g + b, weighted by attn; reduce over 16 key-lanes
  float w = attwS[wv][key];
  float vA[16], vB[16];
#pragma unroll
  for (int q = 0; q < 4; ++q) {
    float4 tA = *(const float4*)&ainV[r][cA + q*4];
    float4 tB = *(const float4*)&ainV[r][cB + q*4];
    vA[q*4+0] = w * (tA.x + (adA[q*4+0]-mu)*rs*alnS[cA+q*4+0] + albS[cA+q*4+0]);
    vA[q*4+1] = w * (tA.y + (adA[q*4+1]-mu)*rs*alnS[cA+q*4+1] + albS[cA+q*4+1]);
    vA[q*4+2] = w * (tA.z + (adA[q*4+2]-mu)*rs*alnS[cA+q*4+2] + albS[cA+q*4+2]);
    vA[q*4+3] = w * (tA.w + (adA[q*4+3]-mu)*rs*alnS[cA+q*4+3] + albS[cA+q*4+3]);
    vB[q*4+0] = w * (tB.x + (adB[q*4+0]-mu)*rs*alnS[cB+q*4+0] + albS[cB+q*4+0]);
    vB[q*4+1] = w * (tB.y + (adB[q*4+1]-mu)*rs*alnS[cB+q*4+1] + albS[cB+q*4+1]);
    vB[q*4+2] = w * (tB.z + (adB[q*4+2]-mu)*rs*alnS[cB+q*4+2] + albS[cB+q*4+2]);
    vB[q*4+3] = w * (tB.w + (adB[q*4+3]-mu)*rs*alnS[cB+q*4+3] + albS[cB+q*4+3]);
  }
#pragma unroll
  for (int m = 4; m <= 32; m <<= 1) {
#pragma unroll
    for (int i = 0; i < 16; ++i) {
      vA[i] += __shfl_xor(vA[i], m);
      vB[i] += __shfl_xor(vB[i], m);
    }
  }
  if (key == 0 && slot < count) {
    size_t o = ((size_t)e*NPTS + slot)*DD;
    float wg = wslS[wv];
#pragma unroll
    for (int i = 0; i < 16; ++i) {
      outC[o + cA + i] = wg * (vA[i] + featsC[o + cA + i]);
      outC[o + cB + i] = wg * (vB[i] + featsC[o + cB + i]);
    }
  }
}

// ---------- kernel 6: gather pairs + final MLP + sigmoid ----------
#define FR 32
__device__ __forceinline__ void mlp_layer_f(
    const float (*X)[260], float (*Y)[260], float (*Wt)[260],
    const float* __restrict__ W, const float* __restrict__ bias,
    int K, int tid)
{
  int rg = tid >> 4;
  int cg = tid & 15;
  int r0 = rg * 2;
  int c16 = cg * 16;
  float acc0[16], acc1[16];
#pragma unroll
  for (int i = 0; i < 16; ++i) { acc0[i] = 0.f; acc1[i] = 0.f; }
  int nkc = K >> 3;
  for (int kc = 0; kc < nkc; ++kc) {
    __syncthreads();
    for (int idx = tid; idx < 512; idx += 256) {
      int rr = idx >> 6, c4 = (idx & 63) * 4;
      *(float4*)&Wt[rr][c4] = *(const float4*)(W + (size_t)(kc*8 + rr)*NHM + c4);
    }
    __syncthreads();
#pragma unroll
    for (int kk = 0; kk < 8; ++kk) {
      float a0 = X[r0][kc*8 + kk];
      float a1 = X[r0+1][kc*8 + kk];
#pragma unroll
      for (int q = 0; q < 4; ++q) {
        float4 wv = *(const float4*)&Wt[kk][c16 + q*4];
        acc0[q*4+0] = fmaf(a0, wv.x, acc0[q*4+0]);
        acc0[q*4+1] = fmaf(a0, wv.y, acc0[q*4+1]);
        acc0[q*4+2] = fmaf(a0, wv.z, acc0[q*4+2]);
        acc0[q*4+3] = fmaf(a0, wv.w, acc0[q*4+3]);
        acc1[q*4+0] = fmaf(a1, wv.x, acc1[q*4+0]);
        acc1[q*4+1] = fmaf(a1, wv.y, acc1[q*4+1]);
        acc1[q*4+2] = fmaf(a1, wv.z, acc1[q*4+2]);
        acc1[q*4+3] = fmaf(a1, wv.w, acc1[q*4+3]);
      }
    }
  }
  float4 b0 = *(const float4*)(bias + c16);
  float4 b1 = *(const float4*)(bias + c16 + 4);
  float4 b2 = *(const float4*)(bias + c16 + 8);
  float4 b3 = *(const float4*)(bias + c16 + 12);
  float bb[16] = {b0.x,b0.y,b0.z,b0.w, b1.x,b1.y,b1.z,b1.w,
                  b2.x,b2.y,b2.z,b2.w, b3.x,b3.y,b3.z,b3.w};
  __syncthreads();
#pragma unroll
  for (int i = 0; i < 16; ++i) {
    Y[r0][c16+i]   = fmaxf(acc0[i] + bb[i], 0.f);
    Y[r0+1][c16+i] = fmaxf(acc1[i] + bb[i], 0.f);
  }
}

__global__ __launch_bounds__(256) void k_final(
    const float* __restrict__ outC, const int* __restrict__ pairE, const int* __restrict__ pairS,
    const float* __restrict__ M1, const float* __restrict__ c1,
    const float* __restrict__ M2, const float* __restrict__ c2,
    const float* __restrict__ M3, const float* __restrict__ c3,
    const float* __restrict__ M4, const float* __restrict__ c4,
    float* __restrict__ out)
{
  int base = blockIdx.x * FR;
  __shared__ float A[FR][260];
  __shared__ float B[FR][260];
  __shared__ float Wt[8][260];
  __shared__ int prE[FR*2];
  __shared__ int prS[FR*2];
  int tid = threadIdx.x;
  if (tid < FR*2) {
    prE[tid] = pairE[(size_t)base*2 + tid];
    prS[tid] = pairS[(size_t)base*2 + tid];
  }
  __syncthreads();
  for (int idx = tid; idx < FR*32; idx += 256) {
    int rr = idx >> 5, c4 = (idx & 31) * 4;
    float4 a = *(const float4*)(outC + ((size_t)prE[rr*2+0]*NPTS + prS[rr*2+0])*DD + c4);
    float4 b = *(const float4*)(outC + ((size_t)prE[rr*2+1]*NPTS + prS[rr*2+1])*DD + c4);
    A[rr][c4+0] = a.x + b.x; A[rr][c4+1] = a.y + b.y;
    A[rr][c4+2] = a.z + b.z; A[rr][c4+3] = a.w + b.w;
  }

  mlp_layer_f(A, B, Wt, M1, c1, 128, tid);
  mlp_layer_f(B, A, Wt, M2, c2, 256, tid);
  mlp_layer_f(A, B, Wt, M3, c3, 256, tid);

  __syncthreads();
  {
    int rg = tid >> 4, cg = tid & 15;
    int r0 = rg * 2, c16 = cg * 16;
    float p0 = 0.f, p1 = 0.f;
#pragma unroll
    for (int q = 0; q < 4; ++q) {
      float4 mv = *(const float4*)(M4 + c16 + q*4);
      p0 = fmaf(B[r0][c16+q*4+0], mv.x, p0); p0 = fmaf(B[r0][c16+q*4+1], mv.y, p0);
      p0 = fmaf(B[r0][c16+q*4+2], mv.z, p0); p0 = fmaf(B[r0][c16+q*4+3], mv.w, p0);
      p1 = fmaf(B[r0+1][c16+q*4+0], mv.x, p1); p1 = fmaf(B[r0+1][c16+q*4+1], mv.y, p1);
      p1 = fmaf(B[r0+1][c16+q*4+2], mv.z, p1); p1 = fmaf(B[r0+1][c16+q*4+3], mv.w, p1);
    }
#pragma unroll
    for (int m = 1; m < 16; m <<= 1) {
      p0 += __shfl_xor(p0, m);
      p1 += __shfl_xor(p1, m);
    }
    if (cg == 0) {
      float z0 = p0 + c4[0];
      float z1 = p1 + c4[0];
      out[base + r0]     = 1.f / (1.f + expf(-z0));
      out[base + r0 + 1] = 1.f / (1.f + expf(-z1));
    }
  }
}

// ---------- launcher ----------
extern "C" void kernel_launch(void* const* d_in, const int* in_sizes, int n_in,
                              void* d_out, int out_size, void* d_ws, size_t ws_size,
                              hipStream_t stream)
{
  const float* x    = (const float*)d_in[0];
  const float* lines= (const float*)d_in[1];
  const float* Wm1  = (const float*)d_in[2];
  const float* bm1  = (const float*)d_in[3];
  const float* Wm2  = (const float*)d_in[4];
  const float* bm2  = (const float*)d_in[5];
  const float* We1  = (const float*)d_in[6];
  const float* be1  = (const float*)d_in[7];
  const float* We2  = (const float*)d_in[8];
  const float* be2  = (const float*)d_in[9];
  const float* We3  = (const float*)d_in[10];
  const float* be3  = (const float*)d_in[11];
  const float* ln_g = (const float*)d_in[12];
  const float* ln_b = (const float*)d_in[13];
  const float* Wq   = (const float*)d_in[14];
  const float* Wk   = (const float*)d_in[15];
  const float* Wv   = (const float*)d_in[16];
  const float* A1   = (const float*)d_in[17];
  const float* a1   = (const float*)d_in[18];
  const float* A2   = (const float*)d_in[19];
  const float* a2   = (const float*)d_in[20];
  const float* alng = (const float*)d_in[21];
  const float* alnb = (const float*)d_in[22];
  const float* mem_k= (const float*)d_in[23];
  const float* mem_v= (const float*)d_in[24];
  const float* M1   = (const float*)d_in[25];
  const float* c1   = (const float*)d_in[26];
  const float* M2   = (const float*)d_in[27];
  const float* c2   = (const float*)d_in[28];
  const float* M3   = (const float*)d_in[29];
  const float* c3   = (const float*)d_in[30];
  const float* M4   = (const float*)d_in[31];
  const float* c4   = (const float*)d_in[32];
  float* out = (float*)d_out;

  char* wp = (char*)d_ws;
  auto alloc = [&](size_t bytes) -> void* {
    void* p = (void*)wp;
    wp += (bytes + 255) & ~(size_t)255;
    return p;
  };
  float* pf     = (float*)alloc((size_t)NPTS*64*4);
  float* pe     = (float*)alloc((size_t)NPTS*64*4);
  float* Khat   = (float*)alloc((size_t)NE*NM*DD*4);
  float* Vhat   = (float*)alloc((size_t)NE*NM*DD*4);
  float* featsC = (float*)alloc((size_t)NE*NPTS*DD*4);
  float* QoutC  = (float*)alloc((size_t)NE*NPTS*DD*4);  // QC then reused as outC
  float* attnWb = (float*)alloc((size_t)NE*NPTS*NTK*4);
  float* slotW  = (float*)alloc((size_t)NE*NPTS*4);
  int*   attnIb = (int*)alloc((size_t)NE*NPTS*NTK*4);
  int*   plist  = (int*)alloc((size_t)NE*NPTS*4);
  int*   pairE  = (int*)alloc((size_t)NPTS*2*4);
  int*   pairS  = (int*)alloc((size_t)NPTS*2*4);
  int*   cnt    = (int*)alloc(64);

  hipMemsetAsync(cnt, 0, 64, stream);
  k_preproc<<<NPTS/256, 256, 0, stream>>>(x, lines, Wm1, bm1, Wm2, bm2,
                                          pf, pe, slotW, plist, pairE, pairS, cnt);
  k_kv<<<dim3(NM/32, NE, 2), 256, 0, stream>>>(mem_k, mem_v, Wk, Wv, Khat, Vhat);
  k_expert<<<dim3(NPTS/32, NE), 256, 0, stream>>>(pe, We1, be1, We2, be2, We3, be3,
                                                  ln_g, ln_b, Wq, plist, cnt, featsC, QoutC);
  k_scores<<<dim3(NPTS/16, NE), 256, 0, stream>>>(QoutC, Khat, cnt, attnWb, attnIb);
  k_adapter<<<dim3(NPTS/4, NE), 256, 0, stream>>>(Vhat, pf, A1, a1, A2, a2, alng, alnb,
                                                  attnWb, attnIb, featsC, slotW, plist, cnt,
                                                  QoutC);
  k_final<<<NPTS/FR, 256, 0, stream>>>(QoutC, pairE, pairS, M1, c1, M2, c2, M3, c3, M4, c4, out);
}

// Round 5
// 2347.857 us; speedup vs baseline: 4.6028x; 1.1356x over previous
//
#include <hip/hip_runtime.h>
#include <hip/hip_bf16.h>
#include <math.h>

#define NPTS 16384
#define NE 4
#define NM 2048
#define DD 128    // D3
#define DP 64     // D1
#define NHE 256
#define NHM 256
#define NRES 64
#define NTK 16
#define NEG_INF -3.402823466e38f

// ---------- helpers ----------
__device__ __forceinline__ bool rank_gt(float av, int ai, float bv, int bi) {
  // "ranks higher in top-k": larger value, ties broken by lower index (jax top_k)
  return (av > bv) || (av == bv && ai < bi);
}

// ---------- kernel 1: per-point preproc ----------
__global__ __launch_bounds__(256) void k_preproc(
    const float* __restrict__ x, const float* __restrict__ lines,
    const float* __restrict__ Wm1, const float* __restrict__ bm1,
    const float* __restrict__ Wm2, const float* __restrict__ bm2,
    float* __restrict__ pf, float* __restrict__ pe,
    float* __restrict__ slotW, int* __restrict__ plist,
    int* __restrict__ pairE, int* __restrict__ pairS, int* __restrict__ cnt)
{
  int n = blockIdx.x * 256 + threadIdx.x;
  if (n >= NPTS) return;
  float c0 = x[n*5+0], c1 = x[n*5+1], c2 = x[n*5+2];

  // ---- gating MLP ----
  float l0 = bm2[0], l1 = bm2[1], l2 = bm2[2], l3 = bm2[3];
#pragma unroll 4
  for (int j = 0; j < 64; ++j) {
    float h = fmaf(c0, Wm1[j], fmaf(c1, Wm1[64+j], fmaf(c2, Wm1[128+j], bm1[j])));
    h = fmaxf(h, 0.f);
    l0 = fmaf(h, Wm2[j*4+0], l0);
    l1 = fmaf(h, Wm2[j*4+1], l1);
    l2 = fmaf(h, Wm2[j*4+2], l2);
    l3 = fmaf(h, Wm2[j*4+3], l3);
  }
  float lg[4] = {l0, l1, l2, l3};
  float mx = fmaxf(fmaxf(l0, l1), fmaxf(l2, l3));
  float pr[4]; float ssum = 0.f;
#pragma unroll
  for (int k = 0; k < 4; ++k) { pr[k] = expf(lg[k] - mx); ssum += pr[k]; }
#pragma unroll
  for (int k = 0; k < 4; ++k) pr[k] /= ssum;
  int i0 = 0;
#pragma unroll
  for (int k = 1; k < 4; ++k) if (pr[k] > pr[i0]) i0 = k;
  int i1 = (i0 == 0) ? 1 : 0;
#pragma unroll
  for (int k = 0; k < 4; ++k) if (k != i0 && pr[k] > pr[i1]) i1 = k;
  float g0 = pr[i0], g1 = pr[i1], gs = g0 + g1;
  g0 /= gs; g1 /= gs;
  int s0 = atomicAdd(&cnt[i0], 1);
  int s1 = atomicAdd(&cnt[i1], 1);
  plist[i0*NPTS + s0] = n; slotW[i0*NPTS + s0] = g0;
  plist[i1*NPTS + s1] = n; slotW[i1*NPTS + s1] = g1;
  pairE[n*2+0] = i0; pairE[n*2+1] = i1;
  pairS[n*2+0] = s0; pairS[n*2+1] = s1;

  // ---- positional encoding (accurate sinf/cosf: args up to 512*pi) ----
  pe[(size_t)n*64 + 0] = c0;
  pe[(size_t)n*64 + 1] = c1;
  pe[(size_t)n*64 + 2] = c2;
  float cc[3] = {c0, c1, c2};
#pragma unroll
  for (int i = 0; i < 10; ++i) {
    float sc = 3.14159274101257324f * (float)(1 << i);
#pragma unroll
    for (int j = 0; j < 3; ++j) {
      float a = sc * cc[j];
      pe[(size_t)n*64 + 3 + (i*3+j)*2 + 0] = sinf(a);
      pe[(size_t)n*64 + 3 + (i*3+j)*2 + 1] = cosf(a);
    }
  }
  pe[(size_t)n*64 + 63] = 0.f;

  // ---- param feats: product of 2 line interpolations ----
  float pfv[64];
#pragma unroll
  for (int d = 0; d < 64; ++d) pfv[d] = 1.f;
  for (int i = 0; i < 2; ++i) {
    float p = x[n*5 + 3 + i] * 63.0f;
    float f = floorf(p);
    float wfr = p - f;
    int j0 = (int)f;
    int j1 = (int)fminf(f + 1.0f, 63.0f);
    const float* L = lines + (size_t)i * 64 * 64;
#pragma unroll
    for (int d = 0; d < 64; ++d) {
      float a = L[d*64 + j0];
      float b = L[d*64 + j1];
      pfv[d] *= a + wfr * (b - a);
    }
  }
#pragma unroll
  for (int d = 0; d < 64; ++d) pf[(size_t)n*64 + d] = pfv[d];
}

// ---------- kernel 2: K/V projection ----------
// K is written TRANSPOSED at float4 granularity: Khat4[e][q][key] = float4 of
// dims 4q..4q+3 of key's row. This makes k_scores' per-lane K reads
// lane-contiguous in LDS (conflict-free b128). V stays row-major (adapter gathers rows).
__global__ __launch_bounds__(256) void k_kv(
    const float* __restrict__ mem_k, const float* __restrict__ mem_v,
    const float* __restrict__ Wk, const float* __restrict__ Wv,
    float* __restrict__ Khat, float* __restrict__ Vhat)
{
  int e = blockIdx.y;
  int which = blockIdx.z;
  const float* src = which ? mem_v : mem_k;
  const float* W   = which ? Wv : Wk;
  int r0 = blockIdx.x * 32;
  __shared__ float sm[32][130];
  int tid = threadIdx.x;
  for (int idx = tid; idx < 32*32; idx += 256) {
    int r = idx >> 5, c4 = (idx & 31) * 4;
    float4 v = *(const float4*)(src + ((size_t)e*NM + r0 + r)*DD + c4);
    sm[r][c4+0] = v.x; sm[r][c4+1] = v.y; sm[r][c4+2] = v.z; sm[r][c4+3] = v.w;
  }
  __syncthreads();
  int r = tid >> 3, cb = (tid & 7) * 16;
  float acc[16];
#pragma unroll
  for (int i = 0; i < 16; ++i) acc[i] = 0.f;
  const float* We = W + (size_t)e*DD*DD;
#pragma unroll 4
  for (int k = 0; k < 128; ++k) {
    float s = sm[r][k];
    const float4* w4 = (const float4*)(We + (size_t)k*DD + cb);
#pragma unroll
    for (int q = 0; q < 4; ++q) {
      float4 wv = w4[q];
      acc[q*4+0] = fmaf(s, wv.x, acc[q*4+0]);
      acc[q*4+1] = fmaf(s, wv.y, acc[q*4+1]);
      acc[q*4+2] = fmaf(s, wv.z, acc[q*4+2]);
      acc[q*4+3] = fmaf(s, wv.w, acc[q*4+3]);
    }
  }
  if (which) {
    float* drow = Vhat + ((size_t)e*NM + r0 + r)*DD + cb;
#pragma unroll
    for (int i = 0; i < 16; ++i) drow[i] = acc[i];
  } else {
    float4* K4 = (float4*)Khat + (size_t)e*32*NM;
    int q0 = (tid & 7) * 4;
    int key = r0 + r;
#pragma unroll
    for (int j = 0; j < 4; ++j) {
      K4[(size_t)(q0+j)*NM + key] = make_float4(acc[j*4+0], acc[j*4+1], acc[j*4+2], acc[j*4+3]);
    }
  }
}

// ---------- kernel 3: routed expert SIREN MLP + LN + Q-proj (LDS-staged weights) ----------
__global__ __launch_bounds__(256) void k_expert(
    const float* __restrict__ pe,
    const float* __restrict__ We1, const float* __restrict__ be1,
    const float* __restrict__ We2, const float* __restrict__ be2,
    const float* __restrict__ We3, const float* __restrict__ be3,
    const float* __restrict__ ln_g, const float* __restrict__ ln_b,
    const float* __restrict__ Wq,
    const int* __restrict__ plist, const int* __restrict__ cnt,
    float* __restrict__ featsC, float* __restrict__ QC)
{
  int e = blockIdx.y;
  int count = cnt[e];
  int base = blockIdx.x * 32;
  if (base >= count) return;
  __shared__ float A[32][260];
  __shared__ float B[32][260];
  __shared__ float Wt[2176];
  __shared__ int pts[32];
  int tid = threadIdx.x;
  if (tid < 32) {
    int slot = base + tid;
    pts[tid] = (slot < count) ? plist[e*NPTS + slot] : 0;
  }
  __syncthreads();
  // pe rows into A[r][0..63]
  for (int idx = tid; idx < 32*16; idx += 256) {
    int rr = idx >> 4, c4 = (idx & 15) * 4;
    *(float4*)&A[rr][c4] = *(const float4*)(pe + (size_t)pts[rr]*64 + c4);
  }
  int rg = tid >> 4, cg = tid & 15;
  int r0 = rg*2, r1 = r0+1, c16 = cg*16, c8 = cg*8;
  int slot0 = base + r0, slot1 = base + r1;

  float acc0[16], acc1[16];

  // ---- L1: 63 -> 256, sin(30x): A[.][0..62] -> B ----
  {
    const float* be = be1 + e*NHE;
#pragma unroll
    for (int i = 0; i < 16; ++i) { acc0[i] = be[c16+i]; acc1[i] = acc0[i]; }
    const float* W = We1 + (size_t)e*63*NHE;
    for (int kc = 0; kc < 8; ++kc) {
      int kbase = kc*8;
      int rows = (kc == 7) ? 7 : 8;
      __syncthreads();
      for (int idx = tid; idx < rows*64; idx += 256) {
        int kk = idx >> 6, c4 = (idx & 63) * 4;
        *(float4*)&Wt[kk*260 + c4] = *(const float4*)(W + (size_t)(kbase+kk)*NHE + c4);
      }
      __syncthreads();
      for (int kk = 0; kk < rows; ++kk) {
        float a0 = A[r0][kbase+kk], a1v = A[r1][kbase+kk];
        const float* wr = &Wt[kk*260 + c16];
#pragma unroll
        for (int q = 0; q < 4; ++q) {
          float4 wv = *(const float4*)(wr + q*4);
          acc0[q*4+0] = fmaf(a0, wv.x, acc0[q*4+0]);
          acc0[q*4+1] = fmaf(a0, wv.y, acc0[q*4+1]);
          acc0[q*4+2] = fmaf(a0, wv.z, acc0[q*4+2]);
          acc0[q*4+3] = fmaf(a0, wv.w, acc0[q*4+3]);
          acc1[q*4+0] = fmaf(a1v, wv.x, acc1[q*4+0]);
          acc1[q*4+1] = fmaf(a1v, wv.y, acc1[q*4+1]);
          acc1[q*4+2] = fmaf(a1v, wv.z, acc1[q*4+2]);
          acc1[q*4+3] = fmaf(a1v, wv.w, acc1[q*4+3]);
        }
      }
    }
#pragma unroll
    for (int i = 0; i < 16; ++i) {
      B[r0][c16+i] = sinf(30.0f*acc0[i]);
      B[r1][c16+i] = sinf(30.0f*acc1[i]);
    }
  }

  // ---- L2: 256 -> 256, sin(30x): B -> A ----
  {
    const float* be = be2 + e*NHE;
#pragma unroll
    for (int i = 0; i < 16; ++i) { acc0[i] = be[c16+i]; acc1[i] = acc0[i]; }
    const float* W = We2 + (size_t)e*NHE*NHE;
    for (int kc = 0; kc < 32; ++kc) {
      __syncthreads();
      for (int idx = tid; idx < 512; idx += 256) {
        int kk = idx >> 6, c4 = (idx & 63) * 4;
        *(float4*)&Wt[kk*260 + c4] = *(const float4*)(W + (size_t)(kc*8+kk)*NHE + c4);
      }
      __syncthreads();
#pragma unroll
      for (int kk = 0; kk < 8; ++kk) {
        float a0 = B[r0][kc*8+kk], a1v = B[r1][kc*8+kk];
        const float* wr = &Wt[kk*260 + c16];
#pragma unroll
        for (int q = 0; q < 4; ++q) {
          float4 wv = *(const float4*)(wr + q*4);
          acc0[q*4+0] = fmaf(a0, wv.x, acc0[q*4+0]);
          acc0[q*4+1] = fmaf(a0, wv.y, acc0[q*4+1]);
          acc0[q*4+2] = fmaf(a0, wv.z, acc0[q*4+2]);
          acc0[q*4+3] = fmaf(a0, wv.w, acc0[q*4+3]);
          acc1[q*4+0] = fmaf(a1v, wv.x, acc1[q*4+0]);
          acc1[q*4+1] = fmaf(a1v, wv.y, acc1[q*4+1]);
          acc1[q*4+2] = fmaf(a1v, wv.z, acc1[q*4+2]);
          acc1[q*4+3] = fmaf(a1v, wv.w, acc1[q*4+3]);
        }
      }
    }
#pragma unroll
    for (int i = 0; i < 16; ++i) {
      A[r0][c16+i] = sinf(30.0f*acc0[i]);
      A[r1][c16+i] = sinf(30.0f*acc1[i]);
    }
  }

  // ---- L3: 256 -> 128 linear: A -> feats (regs) ----
  float f0[8], f1[8];
  {
    const float* be = be3 + e*DD;
#pragma unroll
    for (int i = 0; i < 8; ++i) { f0[i] = be[c8+i]; f1[i] = f0[i]; }
    const float* W = We3 + (size_t)e*NHE*DD;
    for (int kc = 0; kc < 16; ++kc) {
      __syncthreads();
      for (int idx = tid; idx < 512; idx += 256) {
        int kk = idx >> 5, c4 = (idx & 31) * 4;
        *(float4*)&Wt[kk*132 + c4] = *(const float4*)(W + (size_t)(kc*16+kk)*DD + c4);
      }
      __syncthreads();
#pragma unroll
      for (int kk = 0; kk < 16; ++kk) {
        float a0 = A[r0][kc*16+kk], a1v = A[r1][kc*16+kk];
        const float* wr = &Wt[kk*132 + c8];
#pragma unroll
        for (int q = 0; q < 2; ++q) {
          float4 wv = *(const float4*)(wr + q*4);
          f0[q*4+0] = fmaf(a0, wv.x, f0[q*4+0]);
          f0[q*4+1] = fmaf(a0, wv.y, f0[q*4+1]);
          f0[q*4+2] = fmaf(a0, wv.z, f0[q*4+2]);
          f0[q*4+3] = fmaf(a0, wv.w, f0[q*4+3]);
          f1[q*4+0] = fmaf(a1v, wv.x, f1[q*4+0]);
          f1[q*4+1] = fmaf(a1v, wv.y, f1[q*4+1]);
          f1[q*4+2] = fmaf(a1v, wv.z, f1[q*4+2]);
          f1[q*4+3] = fmaf(a1v, wv.w, f1[q*4+3]);
        }
      }
    }
  }

  // ---- LN (register + cg-shuffle) -> q into B[r][128..255]; feats to global ----
  {
    float sm0=0.f, sq0=0.f, sm1=0.f, sq1=0.f;
#pragma unroll
    for (int i = 0; i < 8; ++i) {
      sm0 += f0[i]; sq0 += f0[i]*f0[i];
      sm1 += f1[i]; sq1 += f1[i]*f1[i];
    }
#pragma unroll
    for (int m = 1; m < 16; m <<= 1) {
      sm0 += __shfl_xor(sm0, m); sq0 += __shfl_xor(sq0, m);
      sm1 += __shfl_xor(sm1, m); sq1 += __shfl_xor(sq1, m);
    }
    float mu0 = sm0*(1.f/128.f), mu1 = sm1*(1.f/128.f);
    float rs0 = rsqrtf(sq0*(1.f/128.f) - mu0*mu0 + 1e-5f);
    float rs1 = rsqrtf(sq1*(1.f/128.f) - mu1*mu1 + 1e-5f);
#pragma unroll
    for (int i = 0; i < 8; ++i) {
      float g = ln_g[c8+i], b = ln_b[c8+i];
      B[r0][128+c8+i] = (f0[i]-mu0)*rs0*g + b;
      B[r1][128+c8+i] = (f1[i]-mu1)*rs1*g + b;
    }
    if (slot0 < count) {
      size_t o = ((size_t)e*NPTS + slot0)*DD;
#pragma unroll
      for (int i = 0; i < 8; ++i) featsC[o + c8 + i] = f0[i];
    }
    if (slot1 < count) {
      size_t o = ((size_t)e*NPTS + slot1)*DD;
#pragma unroll
      for (int i = 0; i < 8; ++i) featsC[o + c8 + i] = f1[i];
    }
  }

  // ---- Wq: q(128) -> Q(128): B[.][128..255] -> QC ----
  {
    float g0[8], g1[8];
#pragma unroll
    for (int i = 0; i < 8; ++i) { g0[i] = 0.f; g1[i] = 0.f; }
    const float* W = Wq + (size_t)e*DD*DD;
    for (int kc = 0; kc < 8; ++kc) {
      __syncthreads();
      for (int idx = tid; idx < 512; idx += 256) {
        int kk = idx >> 5, c4 = (idx & 31) * 4;
        *(float4*)&Wt[kk*132 + c4] = *(const float4*)(W + (size_t)(kc*16+kk)*DD + c4);
      }
      __syncthreads();
#pragma unroll
      for (int kk = 0; kk < 16; ++kk) {
        float a0 = B[r0][128+kc*16+kk], a1v = B[r1][128+kc*16+kk];
        const float* wr = &Wt[kk*132 + c8];
#pragma unroll
        for (int q = 0; q < 2; ++q) {
          float4 wv = *(const float4*)(wr + q*4);
          g0[q*4+0] = fmaf(a0, wv.x, g0[q*4+0]);
          g0[q*4+1] = fmaf(a0, wv.y, g0[q*4+1]);
          g0[q*4+2] = fmaf(a0, wv.z, g0[q*4+2]);
          g0[q*4+3] = fmaf(a0, wv.w, g0[q*4+3]);
          g1[q*4+0] = fmaf(a1v, wv.x, g1[q*4+0]);
          g1[q*4+1] = fmaf(a1v, wv.y, g1[q*4+1]);
          g1[q*4+2] = fmaf(a1v, wv.z, g1[q*4+2]);
          g1[q*4+3] = fmaf(a1v, wv.w, g1[q*4+3]);
        }
      }
    }
    if (slot0 < count) {
      size_t o = ((size_t)e*NPTS + slot0)*DD;
#pragma unroll
      for (int i = 0; i < 8; ++i) QC[o + c8 + i] = g0[i];
    }
    if (slot1 < count) {
      size_t o = ((size_t)e*NPTS + slot1)*DD;
#pragma unroll
      for (int i = 0; i < 8; ++i) QC[o + c8 + i] = g1[i];
    }
  }
}

// ---------- kernel 4: fused scores + wave-distributed top-16 + softmax ----------
// K chunk staged as Ks4[dim-quad][key] (float4): lane-contiguous LDS reads,
// conflict-free (R4 post-mortem: row-major [128][132] was ~8-way on every read).
// NOTE: q-loop unroll capped at 4 — full unroll blew past 256 VGPR (R2 post-mortem).
__global__ __launch_bounds__(256) void k_scores(
    const float* __restrict__ QC, const float* __restrict__ Khat,
    const int* __restrict__ cnt,
    float* __restrict__ attnW, int* __restrict__ attnI)
{
  int e = blockIdx.y;
  int count = cnt[e];
  int sbase = blockIdx.x * 16;
  if (sbase >= count) return;
  __shared__ float4 Ks4[32][128];   // [dim-quad][key within chunk]
  __shared__ float Qs[16][128];
  int tid = threadIdx.x;
  int w = tid >> 6, lane = tid & 63;

  for (int idx = tid; idx < 16*32; idx += 256) {
    int s = idx >> 5, c4 = (idx & 31) * 4;
    int slot = sbase + s;
    float4 v = make_float4(0.f, 0.f, 0.f, 0.f);
    if (slot < count) v = *(const float4*)(QC + ((size_t)e*NPTS + slot)*DD + c4);
    Qs[s][c4+0] = v.x; Qs[s][c4+1] = v.y; Qs[s][c4+2] = v.z; Qs[s][c4+3] = v.w;
  }

  float lv = NEG_INF;
  int   li = 0x7fffffff;
  const float4* K4 = (const float4*)Khat + (size_t)e*32*NM;

  for (int ch = 0; ch < NM/128; ++ch) {
    __syncthreads();
    for (int idx = tid; idx < 32*128; idx += 256) {
      int q = idx >> 7, kk = idx & 127;
      Ks4[q][kk] = K4[(size_t)q*NM + ch*128 + kk];
    }
    __syncthreads();

    float acc0[4], acc1[4];
#pragma unroll
    for (int j = 0; j < 4; ++j) { acc0[j] = 0.f; acc1[j] = 0.f; }
#pragma unroll 4
    for (int q = 0; q < 32; ++q) {
      float4 ka = Ks4[q][lane];
      float4 kb = Ks4[q][64 + lane];
#pragma unroll
      for (int j = 0; j < 4; ++j) {
        float4 qv = *(const float4*)&Qs[w*4 + j][q*4];
        acc0[j] = fmaf(ka.x, qv.x, acc0[j]); acc0[j] = fmaf(ka.y, qv.y, acc0[j]);
        acc0[j] = fmaf(ka.z, qv.z, acc0[j]); acc0[j] = fmaf(ka.w, qv.w, acc0[j]);
        acc1[j] = fmaf(kb.x, qv.x, acc1[j]); acc1[j] = fmaf(kb.y, qv.y, acc1[j]);
        acc1[j] = fmaf(kb.z, qv.z, acc1[j]); acc1[j] = fmaf(kb.w, qv.w, acc1[j]);
      }
    }

#pragma unroll
    for (int j = 0; j < 4; ++j) {
      int slot = sbase + w*4 + j;
      if (slot >= count) continue;
#pragma unroll
      for (int h = 0; h < 2; ++h) {
        float v = h ? acc1[j] : acc0[j];
        int key = ch*128 + h*64 + lane;
        float Tv = __shfl(lv, j*16 + 15);
        int   Ti = __shfl(li, j*16 + 15);
        unsigned long long mb = __ballot(rank_gt(v, key, Tv, Ti));
        while (mb) {
          int b = __ffsll((unsigned long long)mb) - 1;
          mb &= mb - 1;
          float cv = __shfl(v, b);
          int   ck = ch*128 + h*64 + b;
          Tv = __shfl(lv, j*16 + 15);
          Ti = __shfl(li, j*16 + 15);
          if (!rank_gt(cv, ck, Tv, Ti)) continue;
          float pv = __shfl_up(lv, 1);
          int   pi = __shfl_up(li, 1);
          int p = lane & 15;
          bool abv_me   = rank_gt(lv, li, cv, ck);
          bool abv_prev = (p == 0) || rank_gt(pv, pi, cv, ck);
          float nv = abv_me ? lv : (abv_prev ? cv : pv);
          int   ni = abv_me ? li : (abv_prev ? ck : pi);
          if ((lane >> 4) == j) { lv = nv; li = ni; }
        }
      }
    }
  }

  const float inv_scale = 0.08838834764831845f;  // 1/sqrt(128)
#pragma unroll
  for (int j = 0; j < 4; ++j) {
    int slot = sbase + w*4 + j;
    if (slot >= count) continue;
    float m = __shfl(lv, j*16 + 0);
    float ev = expf((lv - m) * inv_scale);
    float s = ev;
    s += __shfl_xor(s, 1); s += __shfl_xor(s, 2);
    s += __shfl_xor(s, 4); s += __shfl_xor(s, 8);
    if ((lane >> 4) == j) {
      size_t off = ((size_t)e*NPTS + slot)*NTK + (lane & 15);
      attnW[off] = ev / s;
      attnI[off] = li;
    }
  }
}

// ---------- kernel 5: adapter MLP + LN + attention combine (wave=slot) ----------
// 4 slots/block, 1 wave per slot; lane = (key<<2)|colgroup. Weight staging in
// 5 big rounds (was 16); final key-reduce via LDS (was 128 shfl_xor/lane —
// R4 post-mortem: 1.4e8 LDS-pipe conflict cycles).
__global__ __launch_bounds__(256) void k_adapter(
    const float* __restrict__ Vhat, const float* __restrict__ pf,
    const float* __restrict__ A1, const float* __restrict__ a1,
    const float* __restrict__ A2, const float* __restrict__ a2,
    const float* __restrict__ alng, const float* __restrict__ alnb,
    const float* __restrict__ attnW, const int* __restrict__ attnI,
    const float* __restrict__ featsC, const float* __restrict__ slotW,
    const int* __restrict__ plist, const int* __restrict__ cnt,
    float* __restrict__ outC)
{
  int e = blockIdx.y;
  int count = cnt[e];
  int s0 = blockIdx.x * 4;
  if (s0 >= count) return;
  __shared__ float ainV[64][132];   // 4 slots x 16 keys of Vhat rows; reused as reduce buf
  __shared__ float pfS[4][68];      // per-slot param feats
  __shared__ float hid[64][68];
  __shared__ float Wt[4352];
  __shared__ float attwS[4][16];
  __shared__ float alnS[132], albS[132];
  __shared__ int   rtiS[64];
  __shared__ float wslS[4];
  __shared__ int   ptlS[4];
  int tid = threadIdx.x;
  if (tid < 64) {
    int sl = tid >> 4, key = tid & 15;
    int slot = s0 + sl;
    if (slot < count) {
      size_t o = ((size_t)e*NPTS + slot)*NTK + key;
      rtiS[tid] = attnI[o];
      attwS[sl][key] = attnW[o];
    } else { rtiS[tid] = 0; attwS[sl][key] = 0.f; }
  } else if (tid < 68) {
    int sl = tid - 64;
    int slot = s0 + sl;
    wslS[sl] = (slot < count) ? slotW[e*NPTS + slot] : 0.f;
    ptlS[sl] = (slot < count) ? plist[e*NPTS + slot] : 0;
  } else if (tid >= 128 && tid < 192) {
    int c2 = (tid - 128) * 2;
    alnS[c2]   = alng[e*DD + c2];
    alnS[c2+1] = alng[e*DD + c2+1];
    albS[c2]   = alnb[e*DD + c2];
    albS[c2+1] = alnb[e*DD + c2+1];
  }
  __syncthreads();
  for (int idx = tid; idx < 64*32; idx += 256) {
    int r = idx >> 5, c4 = (idx & 31) * 4;
    *(float4*)&ainV[r][c4] = *(const float4*)(Vhat + ((size_t)e*NM + rtiS[r])*DD + c4);
  }
  if (tid < 64) {
    int sl = tid >> 4, c4 = (tid & 15) * 4;
    *(float4*)&pfS[sl][c4] = *(const float4*)(pf + (size_t)ptlS[sl]*64 + c4);
  }

  int lane = tid & 63;
  int wv = tid >> 6;        // slot within block
  int key = lane >> 2;
  int cg  = lane & 3;
  int r   = wv*16 + key;

  // ---- L1: 192 -> 64, relu. acc cols = cg*16..+16. 3 rounds of 64 k-rows ----
  float acc[16];
  const float* a1e = a1 + e*64;
#pragma unroll
  for (int i = 0; i < 16; ++i) acc[i] = a1e[cg*16 + i];
  const float* A1e = A1 + (size_t)e*192*64;
  for (int kc = 0; kc < 3; ++kc) {
    __syncthreads();
    for (int idx = tid; idx < 64*16; idx += 256) {
      int kk = idx >> 4, c4 = (idx & 15) * 4;
      *(float4*)&Wt[kk*68 + c4] = *(const float4*)(A1e + (size_t)(kc*64+kk)*64 + c4);
    }
    __syncthreads();
#pragma unroll 4
    for (int kk = 0; kk < 64; ++kk) {
      float s = (kc < 2) ? ainV[r][kc*64+kk] : pfS[wv][kk];
      const float* wr = &Wt[kk*68 + cg*16];
#pragma unroll
      for (int q = 0; q < 4; ++q) {
        float4 wv4 = *(const float4*)(wr + q*4);
        acc[q*4+0] = fmaf(s, wv4.x, acc[q*4+0]);
        acc[q*4+1] = fmaf(s, wv4.y, acc[q*4+1]);
        acc[q*4+2] = fmaf(s, wv4.z, acc[q*4+2]);
        acc[q*4+3] = fmaf(s, wv4.w, acc[q*4+3]);
      }
    }
  }
#pragma unroll
  for (int q = 0; q < 4; ++q) {
    float4 hv;
    hv.x = fmaxf(acc[q*4+0], 0.f); hv.y = fmaxf(acc[q*4+1], 0.f);
    hv.z = fmaxf(acc[q*4+2], 0.f); hv.w = fmaxf(acc[q*4+3], 0.f);
    *(float4*)&hid[r][cg*16 + q*4] = hv;
  }

  // ---- L2: 64 -> 128 (+bias), 2 rounds of 32 k-rows; LN via shuffles ----
  float adA[16], adB[16];
  const float* a2e = a2 + e*DD;
  int cA = cg*16, cB = 64 + cg*16;
#pragma unroll
  for (int i = 0; i < 16; ++i) { adA[i] = a2e[cA+i]; adB[i] = a2e[cB+i]; }
  const float* A2e = A2 + (size_t)e*64*DD;
  for (int kc = 0; kc < 2; ++kc) {
    __syncthreads();
    for (int idx = tid; idx < 32*32; idx += 256) {
      int kk = idx >> 5, c4 = (idx & 31) * 4;
      *(float4*)&Wt[kk*132 + c4] = *(const float4*)(A2e + (size_t)(kc*32+kk)*DD + c4);
    }
    __syncthreads();
#pragma unroll 4
    for (int kk = 0; kk < 32; ++kk) {
      float s = hid[r][kc*32+kk];
      const float* wrA = &Wt[kk*132 + cA];
      const float* wrB = &Wt[kk*132 + cB];
#pragma unroll
      for (int q = 0; q < 4; ++q) {
        float4 wa = *(const float4*)(wrA + q*4);
        float4 wb = *(const float4*)(wrB + q*4);
        adA[q*4+0] = fmaf(s, wa.x, adA[q*4+0]);
        adA[q*4+1] = fmaf(s, wa.y, adA[q*4+1]);
        adA[q*4+2] = fmaf(s, wa.z, adA[q*4+2]);
        adA[q*4+3] = fmaf(s, wa.w, adA[q*4+3]);
        adB[q*4+0] = fmaf(s, wb.x, adB[q*4+0]);
        adB[q*4+1] = fmaf(s, wb.y, adB[q*4+1]);
        adB[q*4+2] = fmaf(s, wb.z, adB[q*4+2]);
        adB[q*4+3] = fmaf(s, wb.w, adB[q*4+3]);
      }
    }
  }
  // LN stats over 128 (own 32 + 4 cg-lanes)
  float sm = 0.f, sq = 0.f;
#pragma unroll
  for (int i = 0; i < 16; ++i) {
    sm += adA[i] + adB[i];
    sq += adA[i]*adA[i] + adB[i]*adB[i];
  }
  sm += __shfl_xor(sm, 1); sq += __shfl_xor(sq, 1);
  sm += __shfl_xor(sm, 2); sq += __shfl_xor(sq, 2);
  float mu = sm * (1.f/128.f);
  float var = sq * (1.f/128.f) - mu*mu;
  float rs = rsqrtf(var + 1e-5f);

  // w * (Vt + LN(ad)*g + b) -> back into ainV (same lane's cols: no hazard)
  float w = attwS[wv][key];
#pragma unroll
  for (int i = 0; i < 16; ++i) {
    adA[i] = w * (ainV[r][cA+i] + (adA[i]-mu)*rs*alnS[cA+i] + albS[cA+i]);
    adB[i] = w * (ainV[r][cB+i] + (adB[i]-mu)*rs*alnS[cB+i] + albS[cB+i]);
  }
#pragma unroll
  for (int q = 0; q < 4; ++q) {
    *(float4*)&ainV[r][cA + q*4] = make_float4(adA[q*4+0], adA[q*4+1], adA[q*4+2], adA[q*4+3]);
    *(float4*)&ainV[r][cB + q*4] = make_float4(adB[q*4+0], adB[q*4+1], adB[q*4+2], adB[q*4+3]);
  }
  __syncthreads();

  // key-reduce in LDS: 512 col-tasks, each sums 16 rows
  for (int t = tid; t < 4*128; t += 256) {
    int sl = t >> 7, c = t & 127;
    int slot = s0 + sl;
    float ssum = 0.f;
#pragma unroll
    for (int k = 0; k < 16; ++k) ssum += ainV[sl*16 + k][c];
    if (slot < count) {
      size_t o = ((size_t)e*NPTS + slot)*DD + c;
      outC[o] = wslS[sl] * (ssum + featsC[o]);
    }
  }
}

// ---------- kernel 6: gather pairs + final MLP + sigmoid ----------
#define FR 32
__device__ __forceinline__ void mlp_layer_f(
    const float (*X)[260], float (*Y)[260], float (*Wt)[260],
    const float* __restrict__ W, const float* __restrict__ bias,
    int K, int tid)
{
  int rg = tid >> 4;
  int cg = tid & 15;
  int r0 = rg * 2;
  int c16 = cg * 16;
  float acc0[16], acc1[16];
#pragma unroll
  for (int i = 0; i < 16; ++i) { acc0[i] = 0.f; acc1[i] = 0.f; }
  int nkc = K >> 3;
  for (int kc = 0; kc < nkc; ++kc) {
    __syncthreads();
    for (int idx = tid; idx < 512; idx += 256) {
      int rr = idx >> 6, c4 = (idx & 63) * 4;
      *(float4*)&Wt[rr][c4] = *(const float4*)(W + (size_t)(kc*8 + rr)*NHM + c4);
    }
    __syncthreads();
#pragma unroll
    for (int kk = 0; kk < 8; ++kk) {
      float a0 = X[r0][kc*8 + kk];
      float a1 = X[r0+1][kc*8 + kk];
#pragma unroll
      for (int q = 0; q < 4; ++q) {
        float4 wv = *(const float4*)&Wt[kk][c16 + q*4];
        acc0[q*4+0] = fmaf(a0, wv.x, acc0[q*4+0]);
        acc0[q*4+1] = fmaf(a0, wv.y, acc0[q*4+1]);
        acc0[q*4+2] = fmaf(a0, wv.z, acc0[q*4+2]);
        acc0[q*4+3] = fmaf(a0, wv.w, acc0[q*4+3]);
        acc1[q*4+0] = fmaf(a1, wv.x, acc1[q*4+0]);
        acc1[q*4+1] = fmaf(a1, wv.y, acc1[q*4+1]);
        acc1[q*4+2] = fmaf(a1, wv.z, acc1[q*4+2]);
        acc1[q*4+3] = fmaf(a1, wv.w, acc1[q*4+3]);
      }
    }
  }
  float4 b0 = *(const float4*)(bias + c16);
  float4 b1 = *(const float4*)(bias + c16 + 4);
  float4 b2 = *(const float4*)(bias + c16 + 8);
  float4 b3 = *(const float4*)(bias + c16 + 12);
  float bb[16] = {b0.x,b0.y,b0.z,b0.w, b1.x,b1.y,b1.z,b1.w,
                  b2.x,b2.y,b2.z,b2.w, b3.x,b3.y,b3.z,b3.w};
  __syncthreads();
#pragma unroll
  for (int i = 0; i < 16; ++i) {
    Y[r0][c16+i]   = fmaxf(acc0[i] + bb[i], 0.f);
    Y[r0+1][c16+i] = fmaxf(acc1[i] + bb[i], 0.f);
  }
}

__global__ __launch_bounds__(256) void k_final(
    const float* __restrict__ outC, const int* __restrict__ pairE, const int* __restrict__ pairS,
    const float* __restrict__ M1, const float* __restrict__ c1,
    const float* __restrict__ M2, const float* __restrict__ c2,
    const float* __restrict__ M3, const float* __restrict__ c3,
    const float* __restrict__ M4, const float* __restrict__ c4,
    float* __restrict__ out)
{
  int base = blockIdx.x * FR;
  __shared__ float A[FR][260];
  __shared__ float B[FR][260];
  __shared__ float Wt[8][260];
  __shared__ int prE[FR*2];
  __shared__ int prS[FR*2];
  int tid = threadIdx.x;
  if (tid < FR*2) {
    prE[tid] = pairE[(size_t)base*2 + tid];
    prS[tid] = pairS[(size_t)base*2 + tid];
  }
  __syncthreads();
  for (int idx = tid; idx < FR*32; idx += 256) {
    int rr = idx >> 5, c4 = (idx & 31) * 4;
    float4 a = *(const float4*)(outC + ((size_t)prE[rr*2+0]*NPTS + prS[rr*2+0])*DD + c4);
    float4 b = *(const float4*)(outC + ((size_t)prE[rr*2+1]*NPTS + prS[rr*2+1])*DD + c4);
    A[rr][c4+0] = a.x + b.x; A[rr][c4+1] = a.y + b.y;
    A[rr][c4+2] = a.z + b.z; A[rr][c4+3] = a.w + b.w;
  }

  mlp_layer_f(A, B, Wt, M1, c1, 128, tid);
  mlp_layer_f(B, A, Wt, M2, c2, 256, tid);
  mlp_layer_f(A, B, Wt, M3, c3, 256, tid);

  __syncthreads();
  {
    int rg = tid >> 4, cg = tid & 15;
    int r0 = rg * 2, c16 = cg * 16;
    float p0 = 0.f, p1 = 0.f;
#pragma unroll
    for (int q = 0; q < 4; ++q) {
      float4 mv = *(const float4*)(M4 + c16 + q*4);
      p0 = fmaf(B[r0][c16+q*4+0], mv.x, p0); p0 = fmaf(B[r0][c16+q*4+1], mv.y, p0);
      p0 = fmaf(B[r0][c16+q*4+2], mv.z, p0); p0 = fmaf(B[r0][c16+q*4+3], mv.w, p0);
      p1 = fmaf(B[r0+1][c16+q*4+0], mv.x, p1); p1 = fmaf(B[r0+1][c16+q*4+1], mv.y, p1);
      p1 = fmaf(B[r0+1][c16+q*4+2], mv.z, p1); p1 = fmaf(B[r0+1][c16+q*4+3], mv.w, p1);
    }
#pragma unroll
    for (int m = 1; m < 16; m <<= 1) {
      p0 += __shfl_xor(p0, m);
      p1 += __shfl_xor(p1, m);
    }
    if (cg == 0) {
      float z0 = p0 + c4[0];
      float z1 = p1 + c4[0];
      out[base + r0]     = 1.f / (1.f + expf(-z0));
      out[base + r0 + 1] = 1.f / (1.f + expf(-z1));
    }
  }
}

// ---------- launcher ----------
extern "C" void kernel_launch(void* const* d_in, const int* in_sizes, int n_in,
                              void* d_out, int out_size, void* d_ws, size_t ws_size,
                              hipStream_t stream)
{
  const float* x    = (const float*)d_in[0];
  const float* lines= (const float*)d_in[1];
  const float* Wm1  = (const float*)d_in[2];
  const float* bm1  = (const float*)d_in[3];
  const float* Wm2  = (const float*)d_in[4];
  const float* bm2  = (const float*)d_in[5];
  const float* We1  = (const float*)d_in[6];
  const float* be1  = (const float*)d_in[7];
  const float* We2  = (const float*)d_in[8];
  const float* be2  = (const float*)d_in[9];
  const float* We3  = (const float*)d_in[10];
  const float* be3  = (const float*)d_in[11];
  const float* ln_g = (const float*)d_in[12];
  const float* ln_b = (const float*)d_in[13];
  const float* Wq   = (const float*)d_in[14];
  const float* Wk   = (const float*)d_in[15];
  const float* Wv   = (const float*)d_in[16];
  const float* A1   = (const float*)d_in[17];
  const float* a1   = (const float*)d_in[18];
  const float* A2   = (const float*)d_in[19];
  const float* a2   = (const float*)d_in[20];
  const float* alng = (const float*)d_in[21];
  const float* alnb = (const float*)d_in[22];
  const float* mem_k= (const float*)d_in[23];
  const float* mem_v= (const float*)d_in[24];
  const float* M1   = (const float*)d_in[25];
  const float* c1   = (const float*)d_in[26];
  const float* M2   = (const float*)d_in[27];
  const float* c2   = (const float*)d_in[28];
  const float* M3   = (const float*)d_in[29];
  const float* c3   = (const float*)d_in[30];
  const float* M4   = (const float*)d_in[31];
  const float* c4   = (const float*)d_in[32];
  float* out = (float*)d_out;

  char* wp = (char*)d_ws;
  auto alloc = [&](size_t bytes) -> void* {
    void* p = (void*)wp;
    wp += (bytes + 255) & ~(size_t)255;
    return p;
  };
  float* pf     = (float*)alloc((size_t)NPTS*64*4);
  float* pe     = (float*)alloc((size_t)NPTS*64*4);
  float* Khat   = (float*)alloc((size_t)NE*NM*DD*4);   // transposed-f4 layout [e][32][NM]
  float* Vhat   = (float*)alloc((size_t)NE*NM*DD*4);
  float* featsC = (float*)alloc((size_t)NE*NPTS*DD*4);
  float* QoutC  = (float*)alloc((size_t)NE*NPTS*DD*4);  // QC then reused as outC
  float* attnWb = (float*)alloc((size_t)NE*NPTS*NTK*4);
  float* slotW  = (float*)alloc((size_t)NE*NPTS*4);
  int*   attnIb = (int*)alloc((size_t)NE*NPTS*NTK*4);
  int*   plist  = (int*)alloc((size_t)NE*NPTS*4);
  int*   pairE  = (int*)alloc((size_t)NPTS*2*4);
  int*   pairS  = (int*)alloc((size_t)NPTS*2*4);
  int*   cnt    = (int*)alloc(64);

  hipMemsetAsync(cnt, 0, 64, stream);
  k_preproc<<<NPTS/256, 256, 0, stream>>>(x, lines, Wm1, bm1, Wm2, bm2,
                                          pf, pe, slotW, plist, pairE, pairS, cnt);
  k_kv<<<dim3(NM/32, NE, 2), 256, 0, stream>>>(mem_k, mem_v, Wk, Wv, Khat, Vhat);
  k_expert<<<dim3(NPTS/32, NE), 256, 0, stream>>>(pe, We1, be1, We2, be2, We3, be3,
                                                  ln_g, ln_b, Wq, plist, cnt, featsC, QoutC);
  k_scores<<<dim3(NPTS/16, NE), 256, 0, stream>>>(QoutC, Khat, cnt, attnWb, attnIb);
  k_adapter<<<dim3(NPTS/4, NE), 256, 0, stream>>>(Vhat, pf, A1, a1, A2, a2, alng, alnb,
                                                  attnWb, attnIb, featsC, slotW, plist, cnt,
                                                  QoutC);
  k_final<<<NPTS/FR, 256, 0, stream>>>(QoutC, pairE, pairS, M1, c1, M2, c2, M3, c3, M4, c4, out);
}

// Round 6
// 2172.977 us; speedup vs baseline: 4.9733x; 1.0805x over previous
//
#include <hip/hip_runtime.h>
#include <hip/hip_bf16.h>
#include <math.h>

#define NPTS 16384
#define NE 4
#define NM 2048
#define DD 128    // D3
#define DP 64     // D1
#define NHE 256
#define NHM 256
#define NRES 64
#define NTK 16
#define NEG_INF -3.402823466e38f

// ---------- helpers ----------
__device__ __forceinline__ bool rank_gt(float av, int ai, float bv, int bi) {
  // "ranks higher in top-k": larger value, ties broken by lower index (jax top_k)
  return (av > bv) || (av == bv && ai < bi);
}

// ---------- kernel 1: per-point preproc ----------
__global__ __launch_bounds__(256) void k_preproc(
    const float* __restrict__ x, const float* __restrict__ lines,
    const float* __restrict__ Wm1, const float* __restrict__ bm1,
    const float* __restrict__ Wm2, const float* __restrict__ bm2,
    float* __restrict__ pf, float* __restrict__ pe,
    float* __restrict__ slotW, int* __restrict__ plist,
    int* __restrict__ pairE, int* __restrict__ pairS, int* __restrict__ cnt)
{
  int n = blockIdx.x * 256 + threadIdx.x;
  if (n >= NPTS) return;
  float c0 = x[n*5+0], c1 = x[n*5+1], c2 = x[n*5+2];

  // ---- gating MLP ----
  float l0 = bm2[0], l1 = bm2[1], l2 = bm2[2], l3 = bm2[3];
#pragma unroll 4
  for (int j = 0; j < 64; ++j) {
    float h = fmaf(c0, Wm1[j], fmaf(c1, Wm1[64+j], fmaf(c2, Wm1[128+j], bm1[j])));
    h = fmaxf(h, 0.f);
    l0 = fmaf(h, Wm2[j*4+0], l0);
    l1 = fmaf(h, Wm2[j*4+1], l1);
    l2 = fmaf(h, Wm2[j*4+2], l2);
    l3 = fmaf(h, Wm2[j*4+3], l3);
  }
  float lg[4] = {l0, l1, l2, l3};
  float mx = fmaxf(fmaxf(l0, l1), fmaxf(l2, l3));
  float pr[4]; float ssum = 0.f;
#pragma unroll
  for (int k = 0; k < 4; ++k) { pr[k] = expf(lg[k] - mx); ssum += pr[k]; }
#pragma unroll
  for (int k = 0; k < 4; ++k) pr[k] /= ssum;
  int i0 = 0;
#pragma unroll
  for (int k = 1; k < 4; ++k) if (pr[k] > pr[i0]) i0 = k;
  int i1 = (i0 == 0) ? 1 : 0;
#pragma unroll
  for (int k = 0; k < 4; ++k) if (k != i0 && pr[k] > pr[i1]) i1 = k;
  float g0 = pr[i0], g1 = pr[i1], gs = g0 + g1;
  g0 /= gs; g1 /= gs;
  int s0 = atomicAdd(&cnt[i0], 1);
  int s1 = atomicAdd(&cnt[i1], 1);
  plist[i0*NPTS + s0] = n; slotW[i0*NPTS + s0] = g0;
  plist[i1*NPTS + s1] = n; slotW[i1*NPTS + s1] = g1;
  pairE[n*2+0] = i0; pairE[n*2+1] = i1;
  pairS[n*2+0] = s0; pairS[n*2+1] = s1;

  // ---- positional encoding (accurate sinf/cosf: args up to 512*pi) ----
  pe[(size_t)n*64 + 0] = c0;
  pe[(size_t)n*64 + 1] = c1;
  pe[(size_t)n*64 + 2] = c2;
  float cc[3] = {c0, c1, c2};
#pragma unroll
  for (int i = 0; i < 10; ++i) {
    float sc = 3.14159274101257324f * (float)(1 << i);
#pragma unroll
    for (int j = 0; j < 3; ++j) {
      float a = sc * cc[j];
      pe[(size_t)n*64 + 3 + (i*3+j)*2 + 0] = sinf(a);
      pe[(size_t)n*64 + 3 + (i*3+j)*2 + 1] = cosf(a);
    }
  }
  pe[(size_t)n*64 + 63] = 0.f;

  // ---- param feats: product of 2 line interpolations ----
  float pfv[64];
#pragma unroll
  for (int d = 0; d < 64; ++d) pfv[d] = 1.f;
  for (int i = 0; i < 2; ++i) {
    float p = x[n*5 + 3 + i] * 63.0f;
    float f = floorf(p);
    float wfr = p - f;
    int j0 = (int)f;
    int j1 = (int)fminf(f + 1.0f, 63.0f);
    const float* L = lines + (size_t)i * 64 * 64;
#pragma unroll
    for (int d = 0; d < 64; ++d) {
      float a = L[d*64 + j0];
      float b = L[d*64 + j1];
      pfv[d] *= a + wfr * (b - a);
    }
  }
#pragma unroll
  for (int d = 0; d < 64; ++d) pf[(size_t)n*64 + d] = pfv[d];
}

// ---------- kernel 2: K/V projection ----------
// K is written TRANSPOSED at float4 granularity: Khat4[e][q][key] = float4 of
// dims 4q..4q+3 of key's row. This makes k_scores' per-lane K reads
// lane-contiguous in LDS (conflict-free b128). V stays row-major (adapter gathers rows).
__global__ __launch_bounds__(256) void k_kv(
    const float* __restrict__ mem_k, const float* __restrict__ mem_v,
    const float* __restrict__ Wk, const float* __restrict__ Wv,
    float* __restrict__ Khat, float* __restrict__ Vhat)
{
  int e = blockIdx.y;
  int which = blockIdx.z;
  const float* src = which ? mem_v : mem_k;
  const float* W   = which ? Wv : Wk;
  int r0 = blockIdx.x * 32;
  __shared__ float sm[32][130];
  int tid = threadIdx.x;
  for (int idx = tid; idx < 32*32; idx += 256) {
    int r = idx >> 5, c4 = (idx & 31) * 4;
    float4 v = *(const float4*)(src + ((size_t)e*NM + r0 + r)*DD + c4);
    sm[r][c4+0] = v.x; sm[r][c4+1] = v.y; sm[r][c4+2] = v.z; sm[r][c4+3] = v.w;
  }
  __syncthreads();
  int r = tid >> 3, cb = (tid & 7) * 16;
  float acc[16];
#pragma unroll
  for (int i = 0; i < 16; ++i) acc[i] = 0.f;
  const float* We = W + (size_t)e*DD*DD;
#pragma unroll 4
  for (int k = 0; k < 128; ++k) {
    float s = sm[r][k];
    const float4* w4 = (const float4*)(We + (size_t)k*DD + cb);
#pragma unroll
    for (int q = 0; q < 4; ++q) {
      float4 wv = w4[q];
      acc[q*4+0] = fmaf(s, wv.x, acc[q*4+0]);
      acc[q*4+1] = fmaf(s, wv.y, acc[q*4+1]);
      acc[q*4+2] = fmaf(s, wv.z, acc[q*4+2]);
      acc[q*4+3] = fmaf(s, wv.w, acc[q*4+3]);
    }
  }
  if (which) {
    float* drow = Vhat + ((size_t)e*NM + r0 + r)*DD + cb;
#pragma unroll
    for (int i = 0; i < 16; ++i) drow[i] = acc[i];
  } else {
    float4* K4 = (float4*)Khat + (size_t)e*32*NM;
    int q0 = (tid & 7) * 4;
    int key = r0 + r;
#pragma unroll
    for (int j = 0; j < 4; ++j) {
      K4[(size_t)(q0+j)*NM + key] = make_float4(acc[j*4+0], acc[j*4+1], acc[j*4+2], acc[j*4+3]);
    }
  }
}

// ---------- kernel 3: routed expert SIREN MLP + LN + Q-proj (LDS-staged weights) ----------
__global__ __launch_bounds__(256) void k_expert(
    const float* __restrict__ pe,
    const float* __restrict__ We1, const float* __restrict__ be1,
    const float* __restrict__ We2, const float* __restrict__ be2,
    const float* __restrict__ We3, const float* __restrict__ be3,
    const float* __restrict__ ln_g, const float* __restrict__ ln_b,
    const float* __restrict__ Wq,
    const int* __restrict__ plist, const int* __restrict__ cnt,
    float* __restrict__ featsC, float* __restrict__ QC)
{
  int e = blockIdx.y;
  int count = cnt[e];
  int base = blockIdx.x * 32;
  if (base >= count) return;
  __shared__ float A[32][260];
  __shared__ float B[32][260];
  __shared__ float Wt[2176];
  __shared__ int pts[32];
  int tid = threadIdx.x;
  if (tid < 32) {
    int slot = base + tid;
    pts[tid] = (slot < count) ? plist[e*NPTS + slot] : 0;
  }
  __syncthreads();
  // pe rows into A[r][0..63]
  for (int idx = tid; idx < 32*16; idx += 256) {
    int rr = idx >> 4, c4 = (idx & 15) * 4;
    *(float4*)&A[rr][c4] = *(const float4*)(pe + (size_t)pts[rr]*64 + c4);
  }
  int rg = tid >> 4, cg = tid & 15;
  int r0 = rg*2, r1 = r0+1, c16 = cg*16, c8 = cg*8;
  int slot0 = base + r0, slot1 = base + r1;

  float acc0[16], acc1[16];

  // ---- L1: 63 -> 256, sin(30x): A[.][0..62] -> B ----
  {
    const float* be = be1 + e*NHE;
#pragma unroll
    for (int i = 0; i < 16; ++i) { acc0[i] = be[c16+i]; acc1[i] = acc0[i]; }
    const float* W = We1 + (size_t)e*63*NHE;
    for (int kc = 0; kc < 8; ++kc) {
      int kbase = kc*8;
      int rows = (kc == 7) ? 7 : 8;
      __syncthreads();
      for (int idx = tid; idx < rows*64; idx += 256) {
        int kk = idx >> 6, c4 = (idx & 63) * 4;
        *(float4*)&Wt[kk*260 + c4] = *(const float4*)(W + (size_t)(kbase+kk)*NHE + c4);
      }
      __syncthreads();
      for (int kk = 0; kk < rows; ++kk) {
        float a0 = A[r0][kbase+kk], a1v = A[r1][kbase+kk];
        const float* wr = &Wt[kk*260 + c16];
#pragma unroll
        for (int q = 0; q < 4; ++q) {
          float4 wv = *(const float4*)(wr + q*4);
          acc0[q*4+0] = fmaf(a0, wv.x, acc0[q*4+0]);
          acc0[q*4+1] = fmaf(a0, wv.y, acc0[q*4+1]);
          acc0[q*4+2] = fmaf(a0, wv.z, acc0[q*4+2]);
          acc0[q*4+3] = fmaf(a0, wv.w, acc0[q*4+3]);
          acc1[q*4+0] = fmaf(a1v, wv.x, acc1[q*4+0]);
          acc1[q*4+1] = fmaf(a1v, wv.y, acc1[q*4+1]);
          acc1[q*4+2] = fmaf(a1v, wv.z, acc1[q*4+2]);
          acc1[q*4+3] = fmaf(a1v, wv.w, acc1[q*4+3]);
        }
      }
    }
#pragma unroll
    for (int i = 0; i < 16; ++i) {
      B[r0][c16+i] = sinf(30.0f*acc0[i]);
      B[r1][c16+i] = sinf(30.0f*acc1[i]);
    }
  }

  // ---- L2: 256 -> 256, sin(30x): B -> A ----
  {
    const float* be = be2 + e*NHE;
#pragma unroll
    for (int i = 0; i < 16; ++i) { acc0[i] = be[c16+i]; acc1[i] = acc0[i]; }
    const float* W = We2 + (size_t)e*NHE*NHE;
    for (int kc = 0; kc < 32; ++kc) {
      __syncthreads();
      for (int idx = tid; idx < 512; idx += 256) {
        int kk = idx >> 6, c4 = (idx & 63) * 4;
        *(float4*)&Wt[kk*260 + c4] = *(const float4*)(W + (size_t)(kc*8+kk)*NHE + c4);
      }
      __syncthreads();
#pragma unroll
      for (int kk = 0; kk < 8; ++kk) {
        float a0 = B[r0][kc*8+kk], a1v = B[r1][kc*8+kk];
        const float* wr = &Wt[kk*260 + c16];
#pragma unroll
        for (int q = 0; q < 4; ++q) {
          float4 wv = *(const float4*)(wr + q*4);
          acc0[q*4+0] = fmaf(a0, wv.x, acc0[q*4+0]);
          acc0[q*4+1] = fmaf(a0, wv.y, acc0[q*4+1]);
          acc0[q*4+2] = fmaf(a0, wv.z, acc0[q*4+2]);
          acc0[q*4+3] = fmaf(a0, wv.w, acc0[q*4+3]);
          acc1[q*4+0] = fmaf(a1v, wv.x, acc1[q*4+0]);
          acc1[q*4+1] = fmaf(a1v, wv.y, acc1[q*4+1]);
          acc1[q*4+2] = fmaf(a1v, wv.z, acc1[q*4+2]);
          acc1[q*4+3] = fmaf(a1v, wv.w, acc1[q*4+3]);
        }
      }
    }
#pragma unroll
    for (int i = 0; i < 16; ++i) {
      A[r0][c16+i] = sinf(30.0f*acc0[i]);
      A[r1][c16+i] = sinf(30.0f*acc1[i]);
    }
  }

  // ---- L3: 256 -> 128 linear: A -> feats (regs) ----
  float f0[8], f1[8];
  {
    const float* be = be3 + e*DD;
#pragma unroll
    for (int i = 0; i < 8; ++i) { f0[i] = be[c8+i]; f1[i] = f0[i]; }
    const float* W = We3 + (size_t)e*NHE*DD;
    for (int kc = 0; kc < 16; ++kc) {
      __syncthreads();
      for (int idx = tid; idx < 512; idx += 256) {
        int kk = idx >> 5, c4 = (idx & 31) * 4;
        *(float4*)&Wt[kk*132 + c4] = *(const float4*)(W + (size_t)(kc*16+kk)*DD + c4);
      }
      __syncthreads();
#pragma unroll
      for (int kk = 0; kk < 16; ++kk) {
        float a0 = A[r0][kc*16+kk], a1v = A[r1][kc*16+kk];
        const float* wr = &Wt[kk*132 + c8];
#pragma unroll
        for (int q = 0; q < 2; ++q) {
          float4 wv = *(const float4*)(wr + q*4);
          f0[q*4+0] = fmaf(a0, wv.x, f0[q*4+0]);
          f0[q*4+1] = fmaf(a0, wv.y, f0[q*4+1]);
          f0[q*4+2] = fmaf(a0, wv.z, f0[q*4+2]);
          f0[q*4+3] = fmaf(a0, wv.w, f0[q*4+3]);
          f1[q*4+0] = fmaf(a1v, wv.x, f1[q*4+0]);
          f1[q*4+1] = fmaf(a1v, wv.y, f1[q*4+1]);
          f1[q*4+2] = fmaf(a1v, wv.z, f1[q*4+2]);
          f1[q*4+3] = fmaf(a1v, wv.w, f1[q*4+3]);
        }
      }
    }
  }

  // ---- LN (register + cg-shuffle) -> q into B[r][128..255]; feats to global ----
  {
    float sm0=0.f, sq0=0.f, sm1=0.f, sq1=0.f;
#pragma unroll
    for (int i = 0; i < 8; ++i) {
      sm0 += f0[i]; sq0 += f0[i]*f0[i];
      sm1 += f1[i]; sq1 += f1[i]*f1[i];
    }
#pragma unroll
    for (int m = 1; m < 16; m <<= 1) {
      sm0 += __shfl_xor(sm0, m); sq0 += __shfl_xor(sq0, m);
      sm1 += __shfl_xor(sm1, m); sq1 += __shfl_xor(sq1, m);
    }
    float mu0 = sm0*(1.f/128.f), mu1 = sm1*(1.f/128.f);
    float rs0 = rsqrtf(sq0*(1.f/128.f) - mu0*mu0 + 1e-5f);
    float rs1 = rsqrtf(sq1*(1.f/128.f) - mu1*mu1 + 1e-5f);
#pragma unroll
    for (int i = 0; i < 8; ++i) {
      float g = ln_g[c8+i], b = ln_b[c8+i];
      B[r0][128+c8+i] = (f0[i]-mu0)*rs0*g + b;
      B[r1][128+c8+i] = (f1[i]-mu1)*rs1*g + b;
    }
    if (slot0 < count) {
      size_t o = ((size_t)e*NPTS + slot0)*DD;
#pragma unroll
      for (int i = 0; i < 8; ++i) featsC[o + c8 + i] = f0[i];
    }
    if (slot1 < count) {
      size_t o = ((size_t)e*NPTS + slot1)*DD;
#pragma unroll
      for (int i = 0; i < 8; ++i) featsC[o + c8 + i] = f1[i];
    }
  }

  // ---- Wq: q(128) -> Q(128): B[.][128..255] -> QC ----
  {
    float g0[8], g1[8];
#pragma unroll
    for (int i = 0; i < 8; ++i) { g0[i] = 0.f; g1[i] = 0.f; }
    const float* W = Wq + (size_t)e*DD*DD;
    for (int kc = 0; kc < 8; ++kc) {
      __syncthreads();
      for (int idx = tid; idx < 512; idx += 256) {
        int kk = idx >> 5, c4 = (idx & 31) * 4;
        *(float4*)&Wt[kk*132 + c4] = *(const float4*)(W + (size_t)(kc*16+kk)*DD + c4);
      }
      __syncthreads();
#pragma unroll
      for (int kk = 0; kk < 16; ++kk) {
        float a0 = B[r0][128+kc*16+kk], a1v = B[r1][128+kc*16+kk];
        const float* wr = &Wt[kk*132 + c8];
#pragma unroll
        for (int q = 0; q < 2; ++q) {
          float4 wv = *(const float4*)(wr + q*4);
          g0[q*4+0] = fmaf(a0, wv.x, g0[q*4+0]);
          g0[q*4+1] = fmaf(a0, wv.y, g0[q*4+1]);
          g0[q*4+2] = fmaf(a0, wv.z, g0[q*4+2]);
          g0[q*4+3] = fmaf(a0, wv.w, g0[q*4+3]);
          g1[q*4+0] = fmaf(a1v, wv.x, g1[q*4+0]);
          g1[q*4+1] = fmaf(a1v, wv.y, g1[q*4+1]);
          g1[q*4+2] = fmaf(a1v, wv.z, g1[q*4+2]);
          g1[q*4+3] = fmaf(a1v, wv.w, g1[q*4+3]);
        }
      }
    }
    if (slot0 < count) {
      size_t o = ((size_t)e*NPTS + slot0)*DD;
#pragma unroll
      for (int i = 0; i < 8; ++i) QC[o + c8 + i] = g0[i];
    }
    if (slot1 < count) {
      size_t o = ((size_t)e*NPTS + slot1)*DD;
#pragma unroll
      for (int i = 0; i < 8; ++i) QC[o + c8 + i] = g1[i];
    }
  }
}

// ---------- kernel 4: fused scores + wave-distributed top-16 + softmax ----------
// 64-key chunks: Ks4[32][64] (32KB) + Qs[16][128] (8KB) = 40KB LDS ->
// 4 blocks/CU = 4 waves/SIMD (R5 post-mortem: 72KB -> 2 waves/SIMD was
// latency-bound at 37% VALUBusy despite zero bank conflicts).
// Each lane owns 1 key/chunk; 4 slot-accumulators; K reads lane-contiguous.
__global__ __launch_bounds__(256) void k_scores(
    const float* __restrict__ QC, const float* __restrict__ Khat,
    const int* __restrict__ cnt,
    float* __restrict__ attnW, int* __restrict__ attnI)
{
  int e = blockIdx.y;
  int count = cnt[e];
  int sbase = blockIdx.x * 16;
  if (sbase >= count) return;
  __shared__ float4 Ks4[32][64];   // [dim-quad][key within chunk] = 32 KB
  __shared__ float Qs[16][128];    // 8 KB
  int tid = threadIdx.x;
  int w = tid >> 6, lane = tid & 63;

  for (int idx = tid; idx < 16*32; idx += 256) {
    int s = idx >> 5, c4 = (idx & 31) * 4;
    int slot = sbase + s;
    float4 v = make_float4(0.f, 0.f, 0.f, 0.f);
    if (slot < count) v = *(const float4*)(QC + ((size_t)e*NPTS + slot)*DD + c4);
    Qs[s][c4+0] = v.x; Qs[s][c4+1] = v.y; Qs[s][c4+2] = v.z; Qs[s][c4+3] = v.w;
  }

  float lv = NEG_INF;
  int   li = 0x7fffffff;
  const float4* K4 = (const float4*)Khat + (size_t)e*32*NM;

  for (int ch = 0; ch < NM/64; ++ch) {
    __syncthreads();
    for (int idx = tid; idx < 32*64; idx += 256) {
      int q = idx >> 6, kk = idx & 63;
      Ks4[q][kk] = K4[(size_t)q*NM + ch*64 + kk];
    }
    __syncthreads();

    float acc[4];
#pragma unroll
    for (int j = 0; j < 4; ++j) acc[j] = 0.f;
#pragma unroll 4
    for (int q = 0; q < 32; ++q) {
      float4 ka = Ks4[q][lane];
#pragma unroll
      for (int j = 0; j < 4; ++j) {
        float4 qv = *(const float4*)&Qs[w*4 + j][q*4];
        acc[j] = fmaf(ka.x, qv.x, acc[j]); acc[j] = fmaf(ka.y, qv.y, acc[j]);
        acc[j] = fmaf(ka.z, qv.z, acc[j]); acc[j] = fmaf(ka.w, qv.w, acc[j]);
      }
    }

    // threshold-gated distributed inserts (1 key/lane)
#pragma unroll
    for (int j = 0; j < 4; ++j) {
      int slot = sbase + w*4 + j;
      if (slot >= count) continue;   // wave-uniform
      float v = acc[j];
      int key = ch*64 + lane;
      float Tv = __shfl(lv, j*16 + 15);
      int   Ti = __shfl(li, j*16 + 15);
      unsigned long long mb = __ballot(rank_gt(v, key, Tv, Ti));
      while (mb) {
        int b = __ffsll((unsigned long long)mb) - 1;
        mb &= mb - 1;
        float cv = __shfl(v, b);
        int   ck = ch*64 + b;
        Tv = __shfl(lv, j*16 + 15);
        Ti = __shfl(li, j*16 + 15);
        if (!rank_gt(cv, ck, Tv, Ti)) continue;  // stale candidate (uniform branch)
        float pv = __shfl_up(lv, 1);
        int   pi = __shfl_up(li, 1);
        int p = lane & 15;
        bool abv_me   = rank_gt(lv, li, cv, ck);
        bool abv_prev = (p == 0) || rank_gt(pv, pi, cv, ck);
        float nv = abv_me ? lv : (abv_prev ? cv : pv);
        int   ni = abv_me ? li : (abv_prev ? ck : pi);
        if ((lane >> 4) == j) { lv = nv; li = ni; }
      }
    }
  }

  const float inv_scale = 0.08838834764831845f;  // 1/sqrt(128)
#pragma unroll
  for (int j = 0; j < 4; ++j) {
    int slot = sbase + w*4 + j;
    if (slot >= count) continue;
    float m = __shfl(lv, j*16 + 0);
    float ev = expf((lv - m) * inv_scale);
    float s = ev;
    s += __shfl_xor(s, 1); s += __shfl_xor(s, 2);
    s += __shfl_xor(s, 4); s += __shfl_xor(s, 8);
    if ((lane >> 4) == j) {
      size_t off = ((size_t)e*NPTS + slot)*NTK + (lane & 15);
      attnW[off] = ev / s;
      attnI[off] = li;
    }
  }
}

// ---------- kernel 5: adapter MLP + LN + attention combine (wave=slot) ----------
// 4 slots/block, 1 wave per slot; lane = (key<<2)|colgroup. Weight staging in
// 5 big rounds; final key-reduce via LDS (R4 post-mortem: shfl chain was
// 1.4e8 LDS-pipe conflict cycles).
__global__ __launch_bounds__(256) void k_adapter(
    const float* __restrict__ Vhat, const float* __restrict__ pf,
    const float* __restrict__ A1, const float* __restrict__ a1,
    const float* __restrict__ A2, const float* __restrict__ a2,
    const float* __restrict__ alng, const float* __restrict__ alnb,
    const float* __restrict__ attnW, const int* __restrict__ attnI,
    const float* __restrict__ featsC, const float* __restrict__ slotW,
    const int* __restrict__ plist, const int* __restrict__ cnt,
    float* __restrict__ outC)
{
  int e = blockIdx.y;
  int count = cnt[e];
  int s0 = blockIdx.x * 4;
  if (s0 >= count) return;
  __shared__ float ainV[64][132];   // 4 slots x 16 keys of Vhat rows; reused as reduce buf
  __shared__ float pfS[4][68];      // per-slot param feats
  __shared__ float hid[64][68];
  __shared__ float Wt[4352];
  __shared__ float attwS[4][16];
  __shared__ float alnS[132], albS[132];
  __shared__ int   rtiS[64];
  __shared__ float wslS[4];
  __shared__ int   ptlS[4];
  int tid = threadIdx.x;
  if (tid < 64) {
    int sl = tid >> 4, key = tid & 15;
    int slot = s0 + sl;
    if (slot < count) {
      size_t o = ((size_t)e*NPTS + slot)*NTK + key;
      rtiS[tid] = attnI[o];
      attwS[sl][key] = attnW[o];
    } else { rtiS[tid] = 0; attwS[sl][key] = 0.f; }
  } else if (tid < 68) {
    int sl = tid - 64;
    int slot = s0 + sl;
    wslS[sl] = (slot < count) ? slotW[e*NPTS + slot] : 0.f;
    ptlS[sl] = (slot < count) ? plist[e*NPTS + slot] : 0;
  } else if (tid >= 128 && tid < 192) {
    int c2 = (tid - 128) * 2;
    alnS[c2]   = alng[e*DD + c2];
    alnS[c2+1] = alng[e*DD + c2+1];
    albS[c2]   = alnb[e*DD + c2];
    albS[c2+1] = alnb[e*DD + c2+1];
  }
  __syncthreads();
  for (int idx = tid; idx < 64*32; idx += 256) {
    int r = idx >> 5, c4 = (idx & 31) * 4;
    *(float4*)&ainV[r][c4] = *(const float4*)(Vhat + ((size_t)e*NM + rtiS[r])*DD + c4);
  }
  if (tid < 64) {
    int sl = tid >> 4, c4 = (tid & 15) * 4;
    *(float4*)&pfS[sl][c4] = *(const float4*)(pf + (size_t)ptlS[sl]*64 + c4);
  }

  int lane = tid & 63;
  int wv = tid >> 6;        // slot within block
  int key = lane >> 2;
  int cg  = lane & 3;
  int r   = wv*16 + key;

  // ---- L1: 192 -> 64, relu. acc cols = cg*16..+16. 3 rounds of 64 k-rows ----
  float acc[16];
  const float* a1e = a1 + e*64;
#pragma unroll
  for (int i = 0; i < 16; ++i) acc[i] = a1e[cg*16 + i];
  const float* A1e = A1 + (size_t)e*192*64;
  for (int kc = 0; kc < 3; ++kc) {
    __syncthreads();
    for (int idx = tid; idx < 64*16; idx += 256) {
      int kk = idx >> 4, c4 = (idx & 15) * 4;
      *(float4*)&Wt[kk*68 + c4] = *(const float4*)(A1e + (size_t)(kc*64+kk)*64 + c4);
    }
    __syncthreads();
#pragma unroll 4
    for (int kk = 0; kk < 64; ++kk) {
      float s = (kc < 2) ? ainV[r][kc*64+kk] : pfS[wv][kk];
      const float* wr = &Wt[kk*68 + cg*16];
#pragma unroll
      for (int q = 0; q < 4; ++q) {
        float4 wv4 = *(const float4*)(wr + q*4);
        acc[q*4+0] = fmaf(s, wv4.x, acc[q*4+0]);
        acc[q*4+1] = fmaf(s, wv4.y, acc[q*4+1]);
        acc[q*4+2] = fmaf(s, wv4.z, acc[q*4+2]);
        acc[q*4+3] = fmaf(s, wv4.w, acc[q*4+3]);
      }
    }
  }
#pragma unroll
  for (int q = 0; q < 4; ++q) {
    float4 hv;
    hv.x = fmaxf(acc[q*4+0], 0.f); hv.y = fmaxf(acc[q*4+1], 0.f);
    hv.z = fmaxf(acc[q*4+2], 0.f); hv.w = fmaxf(acc[q*4+3], 0.f);
    *(float4*)&hid[r][cg*16 + q*4] = hv;
  }

  // ---- L2: 64 -> 128 (+bias), 2 rounds of 32 k-rows; LN via shuffles ----
  float adA[16], adB[16];
  const float* a2e = a2 + e*DD;
  int cA = cg*16, cB = 64 + cg*16;
#pragma unroll
  for (int i = 0; i < 16; ++i) { adA[i] = a2e[cA+i]; adB[i] = a2e[cB+i]; }
  const float* A2e = A2 + (size_t)e*64*DD;
  for (int kc = 0; kc < 2; ++kc) {
    __syncthreads();
    for (int idx = tid; idx < 32*32; idx += 256) {
      int kk = idx >> 5, c4 = (idx & 31) * 4;
      *(float4*)&Wt[kk*132 + c4] = *(const float4*)(A2e + (size_t)(kc*32+kk)*DD + c4);
    }
    __syncthreads();
#pragma unroll 4
    for (int kk = 0; kk < 32; ++kk) {
      float s = hid[r][kc*32+kk];
      const float* wrA = &Wt[kk*132 + cA];
      const float* wrB = &Wt[kk*132 + cB];
#pragma unroll
      for (int q = 0; q < 4; ++q) {
        float4 wa = *(const float4*)(wrA + q*4);
        float4 wb = *(const float4*)(wrB + q*4);
        adA[q*4+0] = fmaf(s, wa.x, adA[q*4+0]);
        adA[q*4+1] = fmaf(s, wa.y, adA[q*4+1]);
        adA[q*4+2] = fmaf(s, wa.z, adA[q*4+2]);
        adA[q*4+3] = fmaf(s, wa.w, adA[q*4+3]);
        adB[q*4+0] = fmaf(s, wb.x, adB[q*4+0]);
        adB[q*4+1] = fmaf(s, wb.y, adB[q*4+1]);
        adB[q*4+2] = fmaf(s, wb.z, adB[q*4+2]);
        adB[q*4+3] = fmaf(s, wb.w, adB[q*4+3]);
      }
    }
  }
  // LN stats over 128 (own 32 + 4 cg-lanes)
  float sm = 0.f, sq = 0.f;
#pragma unroll
  for (int i = 0; i < 16; ++i) {
    sm += adA[i] + adB[i];
    sq += adA[i]*adA[i] + adB[i]*adB[i];
  }
  sm += __shfl_xor(sm, 1); sq += __shfl_xor(sq, 1);
  sm += __shfl_xor(sm, 2); sq += __shfl_xor(sq, 2);
  float mu = sm * (1.f/128.f);
  float var = sq * (1.f/128.f) - mu*mu;
  float rs = rsqrtf(var + 1e-5f);

  // w * (Vt + LN(ad)*g + b) -> back into ainV (same lane's cols: no hazard)
  float w = attwS[wv][key];
#pragma unroll
  for (int i = 0; i < 16; ++i) {
    adA[i] = w * (ainV[r][cA+i] + (adA[i]-mu)*rs*alnS[cA+i] + albS[cA+i]);
    adB[i] = w * (ainV[r][cB+i] + (adB[i]-mu)*rs*alnS[cB+i] + albS[cB+i]);
  }
#pragma unroll
  for (int q = 0; q < 4; ++q) {
    *(float4*)&ainV[r][cA + q*4] = make_float4(adA[q*4+0], adA[q*4+1], adA[q*4+2], adA[q*4+3]);
    *(float4*)&ainV[r][cB + q*4] = make_float4(adB[q*4+0], adB[q*4+1], adB[q*4+2], adB[q*4+3]);
  }
  __syncthreads();

  // key-reduce in LDS: 512 col-tasks, each sums 16 rows
  for (int t = tid; t < 4*128; t += 256) {
    int sl = t >> 7, c = t & 127;
    int slot = s0 + sl;
    float ssum = 0.f;
#pragma unroll
    for (int k = 0; k < 16; ++k) ssum += ainV[sl*16 + k][c];
    if (slot < count) {
      size_t o = ((size_t)e*NPTS + slot)*DD + c;
      outC[o] = wslS[sl] * (ssum + featsC[o]);
    }
  }
}

// ---------- kernel 6: gather pairs + final MLP + sigmoid ----------
#define FR 32
__device__ __forceinline__ void mlp_layer_f(
    const float (*X)[260], float (*Y)[260], float (*Wt)[260],
    const float* __restrict__ W, const float* __restrict__ bias,
    int K, int tid)
{
  int rg = tid >> 4;
  int cg = tid & 15;
  int r0 = rg * 2;
  int c16 = cg * 16;
  float acc0[16], acc1[16];
#pragma unroll
  for (int i = 0; i < 16; ++i) { acc0[i] = 0.f; acc1[i] = 0.f; }
  int nkc = K >> 3;
  for (int kc = 0; kc < nkc; ++kc) {
    __syncthreads();
    for (int idx = tid; idx < 512; idx += 256) {
      int rr = idx >> 6, c4 = (idx & 63) * 4;
      *(float4*)&Wt[rr][c4] = *(const float4*)(W + (size_t)(kc*8 + rr)*NHM + c4);
    }
    __syncthreads();
#pragma unroll
    for (int kk = 0; kk < 8; ++kk) {
      float a0 = X[r0][kc*8 + kk];
      float a1 = X[r0+1][kc*8 + kk];
#pragma unroll
      for (int q = 0; q < 4; ++q) {
        float4 wv = *(const float4*)&Wt[kk][c16 + q*4];
        acc0[q*4+0] = fmaf(a0, wv.x, acc0[q*4+0]);
        acc0[q*4+1] = fmaf(a0, wv.y, acc0[q*4+1]);
        acc0[q*4+2] = fmaf(a0, wv.z, acc0[q*4+2]);
        acc0[q*4+3] = fmaf(a0, wv.w, acc0[q*4+3]);
        acc1[q*4+0] = fmaf(a1, wv.x, acc1[q*4+0]);
        acc1[q*4+1] = fmaf(a1, wv.y, acc1[q*4+1]);
        acc1[q*4+2] = fmaf(a1, wv.z, acc1[q*4+2]);
        acc1[q*4+3] = fmaf(a1, wv.w, acc1[q*4+3]);
      }
    }
  }
  float4 b0 = *(const float4*)(bias + c16);
  float4 b1 = *(const float4*)(bias + c16 + 4);
  float4 b2 = *(const float4*)(bias + c16 + 8);
  float4 b3 = *(const float4*)(bias + c16 + 12);
  float bb[16] = {b0.x,b0.y,b0.z,b0.w, b1.x,b1.y,b1.z,b1.w,
                  b2.x,b2.y,b2.z,b2.w, b3.x,b3.y,b3.z,b3.w};
  __syncthreads();
#pragma unroll
  for (int i = 0; i < 16; ++i) {
    Y[r0][c16+i]   = fmaxf(acc0[i] + bb[i], 0.f);
    Y[r0+1][c16+i] = fmaxf(acc1[i] + bb[i], 0.f);
  }
}

__global__ __launch_bounds__(256) void k_final(
    const float* __restrict__ outC, const int* __restrict__ pairE, const int* __restrict__ pairS,
    const float* __restrict__ M1, const float* __restrict__ c1,
    const float* __restrict__ M2, const float* __restrict__ c2,
    const float* __restrict__ M3, const float* __restrict__ c3,
    const float* __restrict__ M4, const float* __restrict__ c4,
    float* __restrict__ out)
{
  int base = blockIdx.x * FR;
  __shared__ float A[FR][260];
  __shared__ float B[FR][260];
  __shared__ float Wt[8][260];
  __shared__ int prE[FR*2];
  __shared__ int prS[FR*2];
  int tid = threadIdx.x;
  if (tid < FR*2) {
    prE[tid] = pairE[(size_t)base*2 + tid];
    prS[tid] = pairS[(size_t)base*2 + tid];
  }
  __syncthreads();
  for (int idx = tid; idx < FR*32; idx += 256) {
    int rr = idx >> 5, c4 = (idx & 31) * 4;
    float4 a = *(const float4*)(outC + ((size_t)prE[rr*2+0]*NPTS + prS[rr*2+0])*DD + c4);
    float4 b = *(const float4*)(outC + ((size_t)prE[rr*2+1]*NPTS + prS[rr*2+1])*DD + c4);
    A[rr][c4+0] = a.x + b.x; A[rr][c4+1] = a.y + b.y;
    A[rr][c4+2] = a.z + b.z; A[rr][c4+3] = a.w + b.w;
  }

  mlp_layer_f(A, B, Wt, M1, c1, 128, tid);
  mlp_layer_f(B, A, Wt, M2, c2, 256, tid);
  mlp_layer_f(A, B, Wt, M3, c3, 256, tid);

  __syncthreads();
  {
    int rg = tid >> 4, cg = tid & 15;
    int r0 = rg * 2, c16 = cg * 16;
    float p0 = 0.f, p1 = 0.f;
#pragma unroll
    for (int q = 0; q < 4; ++q) {
      float4 mv = *(const float4*)(M4 + c16 + q*4);
      p0 = fmaf(B[r0][c16+q*4+0], mv.x, p0); p0 = fmaf(B[r0][c16+q*4+1], mv.y, p0);
      p0 = fmaf(B[r0][c16+q*4+2], mv.z, p0); p0 = fmaf(B[r0][c16+q*4+3], mv.w, p0);
      p1 = fmaf(B[r0+1][c16+q*4+0], mv.x, p1); p1 = fmaf(B[r0+1][c16+q*4+1], mv.y, p1);
      p1 = fmaf(B[r0+1][c16+q*4+2], mv.z, p1); p1 = fmaf(B[r0+1][c16+q*4+3], mv.w, p1);
    }
#pragma unroll
    for (int m = 1; m < 16; m <<= 1) {
      p0 += __shfl_xor(p0, m);
      p1 += __shfl_xor(p1, m);
    }
    if (cg == 0) {
      float z0 = p0 + c4[0];
      float z1 = p1 + c4[0];
      out[base + r0]     = 1.f / (1.f + expf(-z0));
      out[base + r0 + 1] = 1.f / (1.f + expf(-z1));
    }
  }
}

// ---------- launcher ----------
extern "C" void kernel_launch(void* const* d_in, const int* in_sizes, int n_in,
                              void* d_out, int out_size, void* d_ws, size_t ws_size,
                              hipStream_t stream)
{
  const float* x    = (const float*)d_in[0];
  const float* lines= (const float*)d_in[1];
  const float* Wm1  = (const float*)d_in[2];
  const float* bm1  = (const float*)d_in[3];
  const float* Wm2  = (const float*)d_in[4];
  const float* bm2  = (const float*)d_in[5];
  const float* We1  = (const float*)d_in[6];
  const float* be1  = (const float*)d_in[7];
  const float* We2  = (const float*)d_in[8];
  const float* be2  = (const float*)d_in[9];
  const float* We3  = (const float*)d_in[10];
  const float* be3  = (const float*)d_in[11];
  const float* ln_g = (const float*)d_in[12];
  const float* ln_b = (const float*)d_in[13];
  const float* Wq   = (const float*)d_in[14];
  const float* Wk   = (const float*)d_in[15];
  const float* Wv   = (const float*)d_in[16];
  const float* A1   = (const float*)d_in[17];
  const float* a1   = (const float*)d_in[18];
  const float* A2   = (const float*)d_in[19];
  const float* a2   = (const float*)d_in[20];
  const float* alng = (const float*)d_in[21];
  const float* alnb = (const float*)d_in[22];
  const float* mem_k= (const float*)d_in[23];
  const float* mem_v= (const float*)d_in[24];
  const float* M1   = (const float*)d_in[25];
  const float* c1   = (const float*)d_in[26];
  const float* M2   = (const float*)d_in[27];
  const float* c2   = (const float*)d_in[28];
  const float* M3   = (const float*)d_in[29];
  const float* c3   = (const float*)d_in[30];
  const float* M4   = (const float*)d_in[31];
  const float* c4   = (const float*)d_in[32];
  float* out = (float*)d_out;

  char* wp = (char*)d_ws;
  auto alloc = [&](size_t bytes) -> void* {
    void* p = (void*)wp;
    wp += (bytes + 255) & ~(size_t)255;
    return p;
  };
  float* pf     = (float*)alloc((size_t)NPTS*64*4);
  float* pe     = (float*)alloc((size_t)NPTS*64*4);
  float* Khat   = (float*)alloc((size_t)NE*NM*DD*4);   // transposed-f4 layout [e][32][NM]
  float* Vhat   = (float*)alloc((size_t)NE*NM*DD*4);
  float* featsC = (float*)alloc((size_t)NE*NPTS*DD*4);
  float* QoutC  = (float*)alloc((size_t)NE*NPTS*DD*4);  // QC then reused as outC
  float* attnWb = (float*)alloc((size_t)NE*NPTS*NTK*4);
  float* slotW  = (float*)alloc((size_t)NE*NPTS*4);
  int*   attnIb = (int*)alloc((size_t)NE*NPTS*NTK*4);
  int*   plist  = (int*)alloc((size_t)NE*NPTS*4);
  int*   pairE  = (int*)alloc((size_t)NPTS*2*4);
  int*   pairS  = (int*)alloc((size_t)NPTS*2*4);
  int*   cnt    = (int*)alloc(64);

  hipMemsetAsync(cnt, 0, 64, stream);
  k_preproc<<<NPTS/256, 256, 0, stream>>>(x, lines, Wm1, bm1, Wm2, bm2,
                                          pf, pe, slotW, plist, pairE, pairS, cnt);
  k_kv<<<dim3(NM/32, NE, 2), 256, 0, stream>>>(mem_k, mem_v, Wk, Wv, Khat, Vhat);
  k_expert<<<dim3(NPTS/32, NE), 256, 0, stream>>>(pe, We1, be1, We2, be2, We3, be3,
                                                  ln_g, ln_b, Wq, plist, cnt, featsC, QoutC);
  k_scores<<<dim3(NPTS/16, NE), 256, 0, stream>>>(QoutC, Khat, cnt, attnWb, attnIb);
  k_adapter<<<dim3(NPTS/4, NE), 256, 0, stream>>>(Vhat, pf, A1, a1, A2, a2, alng, alnb,
                                                  attnWb, attnIb, featsC, slotW, plist, cnt,
                                                  QoutC);
  k_final<<<NPTS/FR, 256, 0, stream>>>(QoutC, pairE, pairS, M1, c1, M2, c2, M3, c3, M4, c4, out);
}

// Round 7
// 1857.306 us; speedup vs baseline: 5.8185x; 1.1700x over previous
//
#include <hip/hip_runtime.h>
#include <hip/hip_bf16.h>
#include <math.h>

#define NPTS 16384
#define NE 4
#define NM 2048
#define DD 128    // D3
#define DP 64     // D1
#define NHE 256
#define NHM 256
#define NRES 64
#define NTK 16
#define NEG_INF -3.402823466e38f

typedef unsigned short u16;
typedef __attribute__((ext_vector_type(8))) short short8;
typedef __attribute__((ext_vector_type(4))) float f32x4;

// ---------- helpers ----------
__device__ __forceinline__ bool rank_gt(float av, int ai, float bv, int bi) {
  // "ranks higher in top-k": larger value, ties broken by lower index (jax top_k)
  return (av > bv) || (av == bv && ai < bi);
}

__device__ __forceinline__ u16 f2bf(float x) {   // RNE float -> bf16 bits
  union { float f; unsigned u; } v; v.f = x;
  unsigned r = v.u + 0x7fffu + ((v.u >> 16) & 1u);
  return (u16)(r >> 16);
}
__device__ __forceinline__ float bf2f(u16 b) {
  union { float f; unsigned u; } v; v.u = ((unsigned)b) << 16;
  return v.f;
}

// ---------- kernel 1: per-point preproc ----------
__global__ __launch_bounds__(256) void k_preproc(
    const float* __restrict__ x, const float* __restrict__ lines,
    const float* __restrict__ Wm1, const float* __restrict__ bm1,
    const float* __restrict__ Wm2, const float* __restrict__ bm2,
    float* __restrict__ pf, float* __restrict__ pe,
    float* __restrict__ slotW, int* __restrict__ plist,
    int* __restrict__ pairE, int* __restrict__ pairS, int* __restrict__ cnt)
{
  int n = blockIdx.x * 256 + threadIdx.x;
  if (n >= NPTS) return;
  float c0 = x[n*5+0], c1 = x[n*5+1], c2 = x[n*5+2];

  // ---- gating MLP ----
  float l0 = bm2[0], l1 = bm2[1], l2 = bm2[2], l3 = bm2[3];
#pragma unroll 4
  for (int j = 0; j < 64; ++j) {
    float h = fmaf(c0, Wm1[j], fmaf(c1, Wm1[64+j], fmaf(c2, Wm1[128+j], bm1[j])));
    h = fmaxf(h, 0.f);
    l0 = fmaf(h, Wm2[j*4+0], l0);
    l1 = fmaf(h, Wm2[j*4+1], l1);
    l2 = fmaf(h, Wm2[j*4+2], l2);
    l3 = fmaf(h, Wm2[j*4+3], l3);
  }
  float lg[4] = {l0, l1, l2, l3};
  float mx = fmaxf(fmaxf(l0, l1), fmaxf(l2, l3));
  float pr[4]; float ssum = 0.f;
#pragma unroll
  for (int k = 0; k < 4; ++k) { pr[k] = expf(lg[k] - mx); ssum += pr[k]; }
#pragma unroll
  for (int k = 0; k < 4; ++k) pr[k] /= ssum;
  int i0 = 0;
#pragma unroll
  for (int k = 1; k < 4; ++k) if (pr[k] > pr[i0]) i0 = k;
  int i1 = (i0 == 0) ? 1 : 0;
#pragma unroll
  for (int k = 0; k < 4; ++k) if (k != i0 && pr[k] > pr[i1]) i1 = k;
  float g0 = pr[i0], g1 = pr[i1], gs = g0 + g1;
  g0 /= gs; g1 /= gs;
  int s0 = atomicAdd(&cnt[i0], 1);
  int s1 = atomicAdd(&cnt[i1], 1);
  plist[i0*NPTS + s0] = n; slotW[i0*NPTS + s0] = g0;
  plist[i1*NPTS + s1] = n; slotW[i1*NPTS + s1] = g1;
  pairE[n*2+0] = i0; pairE[n*2+1] = i1;
  pairS[n*2+0] = s0; pairS[n*2+1] = s1;

  // ---- positional encoding (accurate sinf/cosf: args up to 512*pi) ----
  pe[(size_t)n*64 + 0] = c0;
  pe[(size_t)n*64 + 1] = c1;
  pe[(size_t)n*64 + 2] = c2;
  float cc[3] = {c0, c1, c2};
#pragma unroll
  for (int i = 0; i < 10; ++i) {
    float sc = 3.14159274101257324f * (float)(1 << i);
#pragma unroll
    for (int j = 0; j < 3; ++j) {
      float a = sc * cc[j];
      pe[(size_t)n*64 + 3 + (i*3+j)*2 + 0] = sinf(a);
      pe[(size_t)n*64 + 3 + (i*3+j)*2 + 1] = cosf(a);
    }
  }
  pe[(size_t)n*64 + 63] = 0.f;

  // ---- param feats: product of 2 line interpolations ----
  float pfv[64];
#pragma unroll
  for (int d = 0; d < 64; ++d) pfv[d] = 1.f;
  for (int i = 0; i < 2; ++i) {
    float p = x[n*5 + 3 + i] * 63.0f;
    float f = floorf(p);
    float wfr = p - f;
    int j0 = (int)f;
    int j1 = (int)fminf(f + 1.0f, 63.0f);
    const float* L = lines + (size_t)i * 64 * 64;
#pragma unroll
    for (int d = 0; d < 64; ++d) {
      float a = L[d*64 + j0];
      float b = L[d*64 + j1];
      pfv[d] *= a + wfr * (b - a);
    }
  }
#pragma unroll
  for (int d = 0; d < 64; ++d) pf[(size_t)n*64 + d] = pfv[d];
}

// ---------- kernel 2: K/V projection ----------
// K is written as bf16 hi/lo MFMA A-fragments:
//   Khf[((e*128 + T)*4 + kt)*512 + lane*8 + j], lane = khalf*16 + (key&15),
//   element = K[T*16 + (key&15)][kt*32 + khalf*8 + j].
// hi = bf16(x), lo = bf16(x - hi): 3-term MFMA gives ~fp32-accurate scores.
// V stays fp32 row-major (adapter gathers rows).
__global__ __launch_bounds__(256) void k_kv(
    const float* __restrict__ mem_k, const float* __restrict__ mem_v,
    const float* __restrict__ Wk, const float* __restrict__ Wv,
    u16* __restrict__ Khf, u16* __restrict__ Klf, float* __restrict__ Vhat)
{
  int e = blockIdx.y;
  int which = blockIdx.z;
  const float* src = which ? mem_v : mem_k;
  const float* W   = which ? Wv : Wk;
  int r0 = blockIdx.x * 32;
  __shared__ float sm[32][130];
  int tid = threadIdx.x;
  for (int idx = tid; idx < 32*32; idx += 256) {
    int r = idx >> 5, c4 = (idx & 31) * 4;
    float4 v = *(const float4*)(src + ((size_t)e*NM + r0 + r)*DD + c4);
    sm[r][c4+0] = v.x; sm[r][c4+1] = v.y; sm[r][c4+2] = v.z; sm[r][c4+3] = v.w;
  }
  __syncthreads();
  int r = tid >> 3, cb = (tid & 7) * 16;
  float acc[16];
#pragma unroll
  for (int i = 0; i < 16; ++i) acc[i] = 0.f;
  const float* We = W + (size_t)e*DD*DD;
#pragma unroll 4
  for (int k = 0; k < 128; ++k) {
    float s = sm[r][k];
    const float4* w4 = (const float4*)(We + (size_t)k*DD + cb);
#pragma unroll
    for (int q = 0; q < 4; ++q) {
      float4 wv = w4[q];
      acc[q*4+0] = fmaf(s, wv.x, acc[q*4+0]);
      acc[q*4+1] = fmaf(s, wv.y, acc[q*4+1]);
      acc[q*4+2] = fmaf(s, wv.z, acc[q*4+2]);
      acc[q*4+3] = fmaf(s, wv.w, acc[q*4+3]);
    }
  }
  if (which) {
    float* drow = Vhat + ((size_t)e*NM + r0 + r)*DD + cb;
#pragma unroll
    for (int i = 0; i < 16; ++i) drow[i] = acc[i];
  } else {
    int key = r0 + r;
    int T = key >> 4;
    int kr = key & 15;
#pragma unroll
    for (int b = 0; b < 2; ++b) {
      int k_off = cb + b*8;
      int kt = k_off >> 5;
      int lhi = (k_off >> 3) & 3;
      int lane_ = lhi*16 + kr;
      size_t dst = (((size_t)e*128 + T)*4 + kt)*512 + (size_t)lane_*8;
      unsigned ph[4], pl[4];
#pragma unroll
      for (int p = 0; p < 4; ++p) {
        float x0 = acc[b*8 + p*2 + 0];
        float x1 = acc[b*8 + p*2 + 1];
        u16 h0 = f2bf(x0), h1 = f2bf(x1);
        u16 l0v = f2bf(x0 - bf2f(h0)), l1v = f2bf(x1 - bf2f(h1));
        ph[p] = (unsigned)h0 | ((unsigned)h1 << 16);
        pl[p] = (unsigned)l0v | ((unsigned)l1v << 16);
      }
      *(uint4*)(Khf + dst) = make_uint4(ph[0], ph[1], ph[2], ph[3]);
      *(uint4*)(Klf + dst) = make_uint4(pl[0], pl[1], pl[2], pl[3]);
    }
  }
}

// ---------- kernel 3: routed expert SIREN MLP + LN + Q-proj (LDS-staged weights) ----------
__global__ __launch_bounds__(256) void k_expert(
    const float* __restrict__ pe,
    const float* __restrict__ We1, const float* __restrict__ be1,
    const float* __restrict__ We2, const float* __restrict__ be2,
    const float* __restrict__ We3, const float* __restrict__ be3,
    const float* __restrict__ ln_g, const float* __restrict__ ln_b,
    const float* __restrict__ Wq,
    const int* __restrict__ plist, const int* __restrict__ cnt,
    float* __restrict__ featsC, float* __restrict__ QC)
{
  int e = blockIdx.y;
  int count = cnt[e];
  int base = blockIdx.x * 32;
  if (base >= count) return;
  __shared__ float A[32][260];
  __shared__ float B[32][260];
  __shared__ float Wt[2176];
  __shared__ int pts[32];
  int tid = threadIdx.x;
  if (tid < 32) {
    int slot = base + tid;
    pts[tid] = (slot < count) ? plist[e*NPTS + slot] : 0;
  }
  __syncthreads();
  // pe rows into A[r][0..63]
  for (int idx = tid; idx < 32*16; idx += 256) {
    int rr = idx >> 4, c4 = (idx & 15) * 4;
    *(float4*)&A[rr][c4] = *(const float4*)(pe + (size_t)pts[rr]*64 + c4);
  }
  int rg = tid >> 4, cg = tid & 15;
  int r0 = rg*2, r1 = r0+1, c16 = cg*16, c8 = cg*8;
  int slot0 = base + r0, slot1 = base + r1;

  float acc0[16], acc1[16];

  // ---- L1: 63 -> 256, sin(30x): A[.][0..62] -> B ----
  {
    const float* be = be1 + e*NHE;
#pragma unroll
    for (int i = 0; i < 16; ++i) { acc0[i] = be[c16+i]; acc1[i] = acc0[i]; }
    const float* W = We1 + (size_t)e*63*NHE;
    for (int kc = 0; kc < 8; ++kc) {
      int kbase = kc*8;
      int rows = (kc == 7) ? 7 : 8;
      __syncthreads();
      for (int idx = tid; idx < rows*64; idx += 256) {
        int kk = idx >> 6, c4 = (idx & 63) * 4;
        *(float4*)&Wt[kk*260 + c4] = *(const float4*)(W + (size_t)(kbase+kk)*NHE + c4);
      }
      __syncthreads();
      for (int kk = 0; kk < rows; ++kk) {
        float a0 = A[r0][kbase+kk], a1v = A[r1][kbase+kk];
        const float* wr = &Wt[kk*260 + c16];
#pragma unroll
        for (int q = 0; q < 4; ++q) {
          float4 wv = *(const float4*)(wr + q*4);
          acc0[q*4+0] = fmaf(a0, wv.x, acc0[q*4+0]);
          acc0[q*4+1] = fmaf(a0, wv.y, acc0[q*4+1]);
          acc0[q*4+2] = fmaf(a0, wv.z, acc0[q*4+2]);
          acc0[q*4+3] = fmaf(a0, wv.w, acc0[q*4+3]);
          acc1[q*4+0] = fmaf(a1v, wv.x, acc1[q*4+0]);
          acc1[q*4+1] = fmaf(a1v, wv.y, acc1[q*4+1]);
          acc1[q*4+2] = fmaf(a1v, wv.z, acc1[q*4+2]);
          acc1[q*4+3] = fmaf(a1v, wv.w, acc1[q*4+3]);
        }
      }
    }
#pragma unroll
    for (int i = 0; i < 16; ++i) {
      B[r0][c16+i] = sinf(30.0f*acc0[i]);
      B[r1][c16+i] = sinf(30.0f*acc1[i]);
    }
  }

  // ---- L2: 256 -> 256, sin(30x): B -> A ----
  {
    const float* be = be2 + e*NHE;
#pragma unroll
    for (int i = 0; i < 16; ++i) { acc0[i] = be[c16+i]; acc1[i] = acc0[i]; }
    const float* W = We2 + (size_t)e*NHE*NHE;
    for (int kc = 0; kc < 32; ++kc) {
      __syncthreads();
      for (int idx = tid; idx < 512; idx += 256) {
        int kk = idx >> 6, c4 = (idx & 63) * 4;
        *(float4*)&Wt[kk*260 + c4] = *(const float4*)(W + (size_t)(kc*8+kk)*NHE + c4);
      }
      __syncthreads();
#pragma unroll
      for (int kk = 0; kk < 8; ++kk) {
        float a0 = B[r0][kc*8+kk], a1v = B[r1][kc*8+kk];
        const float* wr = &Wt[kk*260 + c16];
#pragma unroll
        for (int q = 0; q < 4; ++q) {
          float4 wv = *(const float4*)(wr + q*4);
          acc0[q*4+0] = fmaf(a0, wv.x, acc0[q*4+0]);
          acc0[q*4+1] = fmaf(a0, wv.y, acc0[q*4+1]);
          acc0[q*4+2] = fmaf(a0, wv.z, acc0[q*4+2]);
          acc0[q*4+3] = fmaf(a0, wv.w, acc0[q*4+3]);
          acc1[q*4+0] = fmaf(a1v, wv.x, acc1[q*4+0]);
          acc1[q*4+1] = fmaf(a1v, wv.y, acc1[q*4+1]);
          acc1[q*4+2] = fmaf(a1v, wv.z, acc1[q*4+2]);
          acc1[q*4+3] = fmaf(a1v, wv.w, acc1[q*4+3]);
        }
      }
    }
#pragma unroll
    for (int i = 0; i < 16; ++i) {
      A[r0][c16+i] = sinf(30.0f*acc0[i]);
      A[r1][c16+i] = sinf(30.0f*acc1[i]);
    }
  }

  // ---- L3: 256 -> 128 linear: A -> feats (regs) ----
  float f0[8], f1[8];
  {
    const float* be = be3 + e*DD;
#pragma unroll
    for (int i = 0; i < 8; ++i) { f0[i] = be[c8+i]; f1[i] = f0[i]; }
    const float* W = We3 + (size_t)e*NHE*DD;
    for (int kc = 0; kc < 16; ++kc) {
      __syncthreads();
      for (int idx = tid; idx < 512; idx += 256) {
        int kk = idx >> 5, c4 = (idx & 31) * 4;
        *(float4*)&Wt[kk*132 + c4] = *(const float4*)(W + (size_t)(kc*16+kk)*DD + c4);
      }
      __syncthreads();
#pragma unroll
      for (int kk = 0; kk < 16; ++kk) {
        float a0 = A[r0][kc*16+kk], a1v = A[r1][kc*16+kk];
        const float* wr = &Wt[kk*132 + c8];
#pragma unroll
        for (int q = 0; q < 2; ++q) {
          float4 wv = *(const float4*)(wr + q*4);
          f0[q*4+0] = fmaf(a0, wv.x, f0[q*4+0]);
          f0[q*4+1] = fmaf(a0, wv.y, f0[q*4+1]);
          f0[q*4+2] = fmaf(a0, wv.z, f0[q*4+2]);
          f0[q*4+3] = fmaf(a0, wv.w, f0[q*4+3]);
          f1[q*4+0] = fmaf(a1v, wv.x, f1[q*4+0]);
          f1[q*4+1] = fmaf(a1v, wv.y, f1[q*4+1]);
          f1[q*4+2] = fmaf(a1v, wv.z, f1[q*4+2]);
          f1[q*4+3] = fmaf(a1v, wv.w, f1[q*4+3]);
        }
      }
    }
  }

  // ---- LN (register + cg-shuffle) -> q into B[r][128..255]; feats to global ----
  {
    float sm0=0.f, sq0=0.f, sm1=0.f, sq1=0.f;
#pragma unroll
    for (int i = 0; i < 8; ++i) {
      sm0 += f0[i]; sq0 += f0[i]*f0[i];
      sm1 += f1[i]; sq1 += f1[i]*f1[i];
    }
#pragma unroll
    for (int m = 1; m < 16; m <<= 1) {
      sm0 += __shfl_xor(sm0, m); sq0 += __shfl_xor(sq0, m);
      sm1 += __shfl_xor(sm1, m); sq1 += __shfl_xor(sq1, m);
    }
    float mu0 = sm0*(1.f/128.f), mu1 = sm1*(1.f/128.f);
    float rs0 = rsqrtf(sq0*(1.f/128.f) - mu0*mu0 + 1e-5f);
    float rs1 = rsqrtf(sq1*(1.f/128.f) - mu1*mu1 + 1e-5f);
#pragma unroll
    for (int i = 0; i < 8; ++i) {
      float g = ln_g[c8+i], b = ln_b[c8+i];
      B[r0][128+c8+i] = (f0[i]-mu0)*rs0*g + b;
      B[r1][128+c8+i] = (f1[i]-mu1)*rs1*g + b;
    }
    if (slot0 < count) {
      size_t o = ((size_t)e*NPTS + slot0)*DD;
#pragma unroll
      for (int i = 0; i < 8; ++i) featsC[o + c8 + i] = f0[i];
    }
    if (slot1 < count) {
      size_t o = ((size_t)e*NPTS + slot1)*DD;
#pragma unroll
      for (int i = 0; i < 8; ++i) featsC[o + c8 + i] = f1[i];
    }
  }

  // ---- Wq: q(128) -> Q(128): B[.][128..255] -> QC ----
  {
    float g0[8], g1[8];
#pragma unroll
    for (int i = 0; i < 8; ++i) { g0[i] = 0.f; g1[i] = 0.f; }
    const float* W = Wq + (size_t)e*DD*DD;
    for (int kc = 0; kc < 8; ++kc) {
      __syncthreads();
      for (int idx = tid; idx < 512; idx += 256) {
        int kk = idx >> 5, c4 = (idx & 31) * 4;
        *(float4*)&Wt[kk*132 + c4] = *(const float4*)(W + (size_t)(kc*16+kk)*DD + c4);
      }
      __syncthreads();
#pragma unroll
      for (int kk = 0; kk < 16; ++kk) {
        float a0 = B[r0][128+kc*16+kk], a1v = B[r1][128+kc*16+kk];
        const float* wr = &Wt[kk*132 + c8];
#pragma unroll
        for (int q = 0; q < 2; ++q) {
          float4 wv = *(const float4*)(wr + q*4);
          g0[q*4+0] = fmaf(a0, wv.x, g0[q*4+0]);
          g0[q*4+1] = fmaf(a0, wv.y, g0[q*4+1]);
          g0[q*4+2] = fmaf(a0, wv.z, g0[q*4+2]);
          g0[q*4+3] = fmaf(a0, wv.w, g0[q*4+3]);
          g1[q*4+0] = fmaf(a1v, wv.x, g1[q*4+0]);
          g1[q*4+1] = fmaf(a1v, wv.y, g1[q*4+1]);
          g1[q*4+2] = fmaf(a1v, wv.z, g1[q*4+2]);
          g1[q*4+3] = fmaf(a1v, wv.w, g1[q*4+3]);
        }
      }
    }
    if (slot0 < count) {
      size_t o = ((size_t)e*NPTS + slot0)*DD;
#pragma unroll
      for (int i = 0; i < 8; ++i) QC[o + c8 + i] = g0[i];
    }
    if (slot1 < count) {
      size_t o = ((size_t)e*NPTS + slot1)*DD;
#pragma unroll
      for (int i = 0; i < 8; ++i) QC[o + c8 + i] = g1[i];
    }
  }
}

// ---------- kernel 4: MFMA scores + wave-distributed top-16 + softmax ----------
// D[key][slot] = K·Q^T via mfma_f32_16x16x32_bf16, 3-term hi/lo split for
// ~fp32 accuracy (dropped lo·lo ~2^-16 relative). Per 64-key chunk: wave w
// computes key-tile w (16 keys) x 16 slots = 12 MFMAs + 16 LDS b128 reads
// (vs 512 FMA + 160 LDS reads in R6's VALU version). Scores go through a
// padded LDS slab so the R5-proven ballot top-16 machinery stays unchanged.
// C/D layout: col=lane&15, row=(lane>>4)*4+i [m89]. A/B: lane holds 8
// contiguous k at row/col = lane&15, k-half = lane>>4.
__global__ __launch_bounds__(256) void k_scores(
    const float* __restrict__ QC, const u16* __restrict__ Khf, const u16* __restrict__ Klf,
    const int* __restrict__ cnt,
    float* __restrict__ attnW, int* __restrict__ attnI)
{
  int e = blockIdx.y;
  int count = cnt[e];
  int sbase = blockIdx.x * 16;
  if (sbase >= count) return;
  __shared__ u16 KhS[16*512];    // [t][kt][lane][8]  16 KB
  __shared__ u16 KlS[16*512];    // 16 KB
  __shared__ u16 QhS[4*512];     // [kt][lane][8]  4 KB
  __shared__ u16 QlS[4*512];     // 4 KB
  __shared__ float Ssc[64][17];  // padded: insert-phase column reads conflict-free
  int tid = threadIdx.x;
  int w = tid >> 6, lane = tid & 63;

  // ---- build Q B-fragments (hi/lo): thread = (kt=w, lane) ----
  {
    int srow = lane & 15, khalf = lane >> 4;
    int slot = sbase + srow;
    float q[8];
    if (slot < count) {
      const float* Qr = QC + ((size_t)e*NPTS + slot)*DD + w*32 + khalf*8;
#pragma unroll
      for (int i = 0; i < 8; ++i) q[i] = Qr[i];
    } else {
#pragma unroll
      for (int i = 0; i < 8; ++i) q[i] = 0.f;
    }
    int dst = w*512 + lane*8;
#pragma unroll
    for (int i = 0; i < 8; ++i) {
      u16 h = f2bf(q[i]);
      QhS[dst + i] = h;
      QlS[dst + i] = f2bf(q[i] - bf2f(h));
    }
  }
  // (visibility of QhS/QlS covered by first chunk's barrier)

  float lv = NEG_INF;
  int   li = 0x7fffffff;
  const u16* KhB = Khf + (size_t)e*128*4*512;
  const u16* KlB = Klf + (size_t)e*128*4*512;

  for (int ch = 0; ch < NM/64; ++ch) {
    // stage 16 KB hi + 16 KB lo (contiguous: 4 key-tiles x 4 kt x 1 KB)
    {
      const uint4* srcH = (const uint4*)(KhB + (size_t)ch*8192);
      const uint4* srcL = (const uint4*)(KlB + (size_t)ch*8192);
      uint4* dH = (uint4*)KhS; uint4* dL = (uint4*)KlS;
#pragma unroll
      for (int i = 0; i < 4; ++i) {
        dH[tid + i*256] = srcH[tid + i*256];
        dL[tid + i*256] = srcL[tid + i*256];
      }
    }
    __syncthreads();

    // MFMA: wave w -> key-tile w, all 16 slots
    {
      f32x4 acc = {0.f, 0.f, 0.f, 0.f};
#pragma unroll
      for (int kt = 0; kt < 4; ++kt) {
        int ko = (w*4 + kt)*512 + lane*8;
        int qo = kt*512 + lane*8;
        short8 ah = *(const short8*)&KhS[ko];
        short8 al = *(const short8*)&KlS[ko];
        short8 bh = *(const short8*)&QhS[qo];
        short8 bl = *(const short8*)&QlS[qo];
        acc = __builtin_amdgcn_mfma_f32_16x16x32_bf16(ah, bh, acc, 0, 0, 0);
        acc = __builtin_amdgcn_mfma_f32_16x16x32_bf16(ah, bl, acc, 0, 0, 0);
        acc = __builtin_amdgcn_mfma_f32_16x16x32_bf16(al, bh, acc, 0, 0, 0);
      }
      int col = lane & 15, rbase = (lane >> 4) * 4;
#pragma unroll
      for (int i = 0; i < 4; ++i)
        Ssc[w*16 + rbase + i][col] = acc[i];
    }
    __syncthreads();

    // threshold-gated distributed inserts (lane = key in chunk)
#pragma unroll
    for (int j = 0; j < 4; ++j) {
      int slot = sbase + w*4 + j;
      if (slot >= count) continue;   // wave-uniform
      float v = Ssc[lane][w*4 + j];
      int key = ch*64 + lane;
      float Tv = __shfl(lv, j*16 + 15);
      int   Ti = __shfl(li, j*16 + 15);
      unsigned long long mb = __ballot(rank_gt(v, key, Tv, Ti));
      while (mb) {
        int b = __ffsll((unsigned long long)mb) - 1;
        mb &= mb - 1;
        float cv = __shfl(v, b);
        int   ck = ch*64 + b;
        Tv = __shfl(lv, j*16 + 15);
        Ti = __shfl(li, j*16 + 15);
        if (!rank_gt(cv, ck, Tv, Ti)) continue;  // stale candidate (uniform branch)
        float pv = __shfl_up(lv, 1);
        int   pi = __shfl_up(li, 1);
        int p = lane & 15;
        bool abv_me   = rank_gt(lv, li, cv, ck);
        bool abv_prev = (p == 0) || rank_gt(pv, pi, cv, ck);
        float nv = abv_me ? lv : (abv_prev ? cv : pv);
        int   ni = abv_me ? li : (abv_prev ? ck : pi);
        if ((lane >> 4) == j) { lv = nv; li = ni; }
      }
    }
  }

  const float inv_scale = 0.08838834764831845f;  // 1/sqrt(128)
#pragma unroll
  for (int j = 0; j < 4; ++j) {
    int slot = sbase + w*4 + j;
    if (slot >= count) continue;
    float m = __shfl(lv, j*16 + 0);
    float ev = expf((lv - m) * inv_scale);
    float s = ev;
    s += __shfl_xor(s, 1); s += __shfl_xor(s, 2);
    s += __shfl_xor(s, 4); s += __shfl_xor(s, 8);
    if ((lane >> 4) == j) {
      size_t off = ((size_t)e*NPTS + slot)*NTK + (lane & 15);
      attnW[off] = ev / s;
      attnI[off] = li;
    }
  }
}

// ---------- kernel 5: adapter MLP + LN + attention combine (wave=slot) ----------
__global__ __launch_bounds__(256) void k_adapter(
    const float* __restrict__ Vhat, const float* __restrict__ pf,
    const float* __restrict__ A1, const float* __restrict__ a1,
    const float* __restrict__ A2, const float* __restrict__ a2,
    const float* __restrict__ alng, const float* __restrict__ alnb,
    const float* __restrict__ attnW, const int* __restrict__ attnI,
    const float* __restrict__ featsC, const float* __restrict__ slotW,
    const int* __restrict__ plist, const int* __restrict__ cnt,
    float* __restrict__ outC)
{
  int e = blockIdx.y;
  int count = cnt[e];
  int s0 = blockIdx.x * 4;
  if (s0 >= count) return;
  __shared__ float ainV[64][132];   // 4 slots x 16 keys of Vhat rows; reused as reduce buf
  __shared__ float pfS[4][68];      // per-slot param feats
  __shared__ float hid[64][68];
  __shared__ float Wt[4352];
  __shared__ float attwS[4][16];
  __shared__ float alnS[132], albS[132];
  __shared__ int   rtiS[64];
  __shared__ float wslS[4];
  __shared__ int   ptlS[4];
  int tid = threadIdx.x;
  if (tid < 64) {
    int sl = tid >> 4, key = tid & 15;
    int slot = s0 + sl;
    if (slot < count) {
      size_t o = ((size_t)e*NPTS + slot)*NTK + key;
      rtiS[tid] = attnI[o];
      attwS[sl][key] = attnW[o];
    } else { rtiS[tid] = 0; attwS[sl][key] = 0.f; }
  } else if (tid < 68) {
    int sl = tid - 64;
    int slot = s0 + sl;
    wslS[sl] = (slot < count) ? slotW[e*NPTS + slot] : 0.f;
    ptlS[sl] = (slot < count) ? plist[e*NPTS + slot] : 0;
  } else if (tid >= 128 && tid < 192) {
    int c2 = (tid - 128) * 2;
    alnS[c2]   = alng[e*DD + c2];
    alnS[c2+1] = alng[e*DD + c2+1];
    albS[c2]   = alnb[e*DD + c2];
    albS[c2+1] = alnb[e*DD + c2+1];
  }
  __syncthreads();
  for (int idx = tid; idx < 64*32; idx += 256) {
    int r = idx >> 5, c4 = (idx & 31) * 4;
    *(float4*)&ainV[r][c4] = *(const float4*)(Vhat + ((size_t)e*NM + rtiS[r])*DD + c4);
  }
  if (tid < 64) {
    int sl = tid >> 4, c4 = (tid & 15) * 4;
    *(float4*)&pfS[sl][c4] = *(const float4*)(pf + (size_t)ptlS[sl]*64 + c4);
  }

  int lane = tid & 63;
  int wv = tid >> 6;        // slot within block
  int key = lane >> 2;
  int cg  = lane & 3;
  int r   = wv*16 + key;

  // ---- L1: 192 -> 64, relu. acc cols = cg*16..+16. 3 rounds of 64 k-rows ----
  float acc[16];
  const float* a1e = a1 + e*64;
#pragma unroll
  for (int i = 0; i < 16; ++i) acc[i] = a1e[cg*16 + i];
  const float* A1e = A1 + (size_t)e*192*64;
  for (int kc = 0; kc < 3; ++kc) {
    __syncthreads();
    for (int idx = tid; idx < 64*16; idx += 256) {
      int kk = idx >> 4, c4 = (idx & 15) * 4;
      *(float4*)&Wt[kk*68 + c4] = *(const float4*)(A1e + (size_t)(kc*64+kk)*64 + c4);
    }
    __syncthreads();
#pragma unroll 4
    for (int kk = 0; kk < 64; ++kk) {
      float s = (kc < 2) ? ainV[r][kc*64+kk] : pfS[wv][kk];
      const float* wr = &Wt[kk*68 + cg*16];
#pragma unroll
      for (int q = 0; q < 4; ++q) {
        float4 wv4 = *(const float4*)(wr + q*4);
        acc[q*4+0] = fmaf(s, wv4.x, acc[q*4+0]);
        acc[q*4+1] = fmaf(s, wv4.y, acc[q*4+1]);
        acc[q*4+2] = fmaf(s, wv4.z, acc[q*4+2]);
        acc[q*4+3] = fmaf(s, wv4.w, acc[q*4+3]);
      }
    }
  }
#pragma unroll
  for (int q = 0; q < 4; ++q) {
    float4 hv;
    hv.x = fmaxf(acc[q*4+0], 0.f); hv.y = fmaxf(acc[q*4+1], 0.f);
    hv.z = fmaxf(acc[q*4+2], 0.f); hv.w = fmaxf(acc[q*4+3], 0.f);
    *(float4*)&hid[r][cg*16 + q*4] = hv;
  }

  // ---- L2: 64 -> 128 (+bias), 2 rounds of 32 k-rows; LN via shuffles ----
  float adA[16], adB[16];
  const float* a2e = a2 + e*DD;
  int cA = cg*16, cB = 64 + cg*16;
#pragma unroll
  for (int i = 0; i < 16; ++i) { adA[i] = a2e[cA+i]; adB[i] = a2e[cB+i]; }
  const float* A2e = A2 + (size_t)e*64*DD;
  for (int kc = 0; kc < 2; ++kc) {
    __syncthreads();
    for (int idx = tid; idx < 32*32; idx += 256) {
      int kk = idx >> 5, c4 = (idx & 31) * 4;
      *(float4*)&Wt[kk*132 + c4] = *(const float4*)(A2e + (size_t)(kc*32+kk)*DD + c4);
    }
    __syncthreads();
#pragma unroll 4
    for (int kk = 0; kk < 32; ++kk) {
      float s = hid[r][kc*32+kk];
      const float* wrA = &Wt[kk*132 + cA];
      const float* wrB = &Wt[kk*132 + cB];
#pragma unroll
      for (int q = 0; q < 4; ++q) {
        float4 wa = *(const float4*)(wrA + q*4);
        float4 wb = *(const float4*)(wrB + q*4);
        adA[q*4+0] = fmaf(s, wa.x, adA[q*4+0]);
        adA[q*4+1] = fmaf(s, wa.y, adA[q*4+1]);
        adA[q*4+2] = fmaf(s, wa.z, adA[q*4+2]);
        adA[q*4+3] = fmaf(s, wa.w, adA[q*4+3]);
        adB[q*4+0] = fmaf(s, wb.x, adB[q*4+0]);
        adB[q*4+1] = fmaf(s, wb.y, adB[q*4+1]);
        adB[q*4+2] = fmaf(s, wb.z, adB[q*4+2]);
        adB[q*4+3] = fmaf(s, wb.w, adB[q*4+3]);
      }
    }
  }
  // LN stats over 128 (own 32 + 4 cg-lanes)
  float sm = 0.f, sq = 0.f;
#pragma unroll
  for (int i = 0; i < 16; ++i) {
    sm += adA[i] + adB[i];
    sq += adA[i]*adA[i] + adB[i]*adB[i];
  }
  sm += __shfl_xor(sm, 1); sq += __shfl_xor(sq, 1);
  sm += __shfl_xor(sm, 2); sq += __shfl_xor(sq, 2);
  float mu = sm * (1.f/128.f);
  float var = sq * (1.f/128.f) - mu*mu;
  float rs = rsqrtf(var + 1e-5f);

  // w * (Vt + LN(ad)*g + b) -> back into ainV (same lane's cols: no hazard)
  float w = attwS[wv][key];
#pragma unroll
  for (int i = 0; i < 16; ++i) {
    adA[i] = w * (ainV[r][cA+i] + (adA[i]-mu)*rs*alnS[cA+i] + albS[cA+i]);
    adB[i] = w * (ainV[r][cB+i] + (adB[i]-mu)*rs*alnS[cB+i] + albS[cB+i]);
  }
#pragma unroll
  for (int q = 0; q < 4; ++q) {
    *(float4*)&ainV[r][cA + q*4] = make_float4(adA[q*4+0], adA[q*4+1], adA[q*4+2], adA[q*4+3]);
    *(float4*)&ainV[r][cB + q*4] = make_float4(adB[q*4+0], adB[q*4+1], adB[q*4+2], adB[q*4+3]);
  }
  __syncthreads();

  // key-reduce in LDS: 512 col-tasks, each sums 16 rows
  for (int t = tid; t < 4*128; t += 256) {
    int sl = t >> 7, c = t & 127;
    int slot = s0 + sl;
    float ssum = 0.f;
#pragma unroll
    for (int k = 0; k < 16; ++k) ssum += ainV[sl*16 + k][c];
    if (slot < count) {
      size_t o = ((size_t)e*NPTS + slot)*DD + c;
      outC[o] = wslS[sl] * (ssum + featsC[o]);
    }
  }
}

// ---------- kernel 6: gather pairs + final MLP + sigmoid ----------
#define FR 32
__device__ __forceinline__ void mlp_layer_f(
    const float (*X)[260], float (*Y)[260], float (*Wt)[260],
    const float* __restrict__ W, const float* __restrict__ bias,
    int K, int tid)
{
  int rg = tid >> 4;
  int cg = tid & 15;
  int r0 = rg * 2;
  int c16 = cg * 16;
  float acc0[16], acc1[16];
#pragma unroll
  for (int i = 0; i < 16; ++i) { acc0[i] = 0.f; acc1[i] = 0.f; }
  int nkc = K >> 3;
  for (int kc = 0; kc < nkc; ++kc) {
    __syncthreads();
    for (int idx = tid; idx < 512; idx += 256) {
      int rr = idx >> 6, c4 = (idx & 63) * 4;
      *(float4*)&Wt[rr][c4] = *(const float4*)(W + (size_t)(kc*8 + rr)*NHM + c4);
    }
    __syncthreads();
#pragma unroll
    for (int kk = 0; kk < 8; ++kk) {
      float a0 = X[r0][kc*8 + kk];
      float a1 = X[r0+1][kc*8 + kk];
#pragma unroll
      for (int q = 0; q < 4; ++q) {
        float4 wv = *(const float4*)&Wt[kk][c16 + q*4];
        acc0[q*4+0] = fmaf(a0, wv.x, acc0[q*4+0]);
        acc0[q*4+1] = fmaf(a0, wv.y, acc0[q*4+1]);
        acc0[q*4+2] = fmaf(a0, wv.z, acc0[q*4+2]);
        acc0[q*4+3] = fmaf(a0, wv.w, acc0[q*4+3]);
        acc1[q*4+0] = fmaf(a1, wv.x, acc1[q*4+0]);
        acc1[q*4+1] = fmaf(a1, wv.y, acc1[q*4+1]);
        acc1[q*4+2] = fmaf(a1, wv.z, acc1[q*4+2]);
        acc1[q*4+3] = fmaf(a1, wv.w, acc1[q*4+3]);
      }
    }
  }
  float4 b0 = *(const float4*)(bias + c16);
  float4 b1 = *(const float4*)(bias + c16 + 4);
  float4 b2 = *(const float4*)(bias + c16 + 8);
  float4 b3 = *(const float4*)(bias + c16 + 12);
  float bb[16] = {b0.x,b0.y,b0.z,b0.w, b1.x,b1.y,b1.z,b1.w,
                  b2.x,b2.y,b2.z,b2.w, b3.x,b3.y,b3.z,b3.w};
  __syncthreads();
#pragma unroll
  for (int i = 0; i < 16; ++i) {
    Y[r0][c16+i]   = fmaxf(acc0[i] + bb[i], 0.f);
    Y[r0+1][c16+i] = fmaxf(acc1[i] + bb[i], 0.f);
  }
}

__global__ __launch_bounds__(256) void k_final(
    const float* __restrict__ outC, const int* __restrict__ pairE, const int* __restrict__ pairS,
    const float* __restrict__ M1, const float* __restrict__ c1,
    const float* __restrict__ M2, const float* __restrict__ c2,
    const float* __restrict__ M3, const float* __restrict__ c3,
    const float* __restrict__ M4, const float* __restrict__ c4,
    float* __restrict__ out)
{
  int base = blockIdx.x * FR;
  __shared__ float A[FR][260];
  __shared__ float B[FR][260];
  __shared__ float Wt[8][260];
  __shared__ int prE[FR*2];
  __shared__ int prS[FR*2];
  int tid = threadIdx.x;
  if (tid < FR*2) {
    prE[tid] = pairE[(size_t)base*2 + tid];
    prS[tid] = pairS[(size_t)base*2 + tid];
  }
  __syncthreads();
  for (int idx = tid; idx < FR*32; idx += 256) {
    int rr = idx >> 5, c4 = (idx & 31) * 4;
    float4 a = *(const float4*)(outC + ((size_t)prE[rr*2+0]*NPTS + prS[rr*2+0])*DD + c4);
    float4 b = *(const float4*)(outC + ((size_t)prE[rr*2+1]*NPTS + prS[rr*2+1])*DD + c4);
    A[rr][c4+0] = a.x + b.x; A[rr][c4+1] = a.y + b.y;
    A[rr][c4+2] = a.z + b.z; A[rr][c4+3] = a.w + b.w;
  }

  mlp_layer_f(A, B, Wt, M1, c1, 128, tid);
  mlp_layer_f(B, A, Wt, M2, c2, 256, tid);
  mlp_layer_f(A, B, Wt, M3, c3, 256, tid);

  __syncthreads();
  {
    int rg = tid >> 4, cg = tid & 15;
    int r0 = rg * 2, c16 = cg * 16;
    float p0 = 0.f, p1 = 0.f;
#pragma unroll
    for (int q = 0; q < 4; ++q) {
      float4 mv = *(const float4*)(M4 + c16 + q*4);
      p0 = fmaf(B[r0][c16+q*4+0], mv.x, p0); p0 = fmaf(B[r0][c16+q*4+1], mv.y, p0);
      p0 = fmaf(B[r0][c16+q*4+2], mv.z, p0); p0 = fmaf(B[r0][c16+q*4+3], mv.w, p0);
      p1 = fmaf(B[r0+1][c16+q*4+0], mv.x, p1); p1 = fmaf(B[r0+1][c16+q*4+1], mv.y, p1);
      p1 = fmaf(B[r0+1][c16+q*4+2], mv.z, p1); p1 = fmaf(B[r0+1][c16+q*4+3], mv.w, p1);
    }
#pragma unroll
    for (int m = 1; m < 16; m <<= 1) {
      p0 += __shfl_xor(p0, m);
      p1 += __shfl_xor(p1, m);
    }
    if (cg == 0) {
      float z0 = p0 + c4[0];
      float z1 = p1 + c4[0];
      out[base + r0]     = 1.f / (1.f + expf(-z0));
      out[base + r0 + 1] = 1.f / (1.f + expf(-z1));
    }
  }
}

// ---------- launcher ----------
extern "C" void kernel_launch(void* const* d_in, const int* in_sizes, int n_in,
                              void* d_out, int out_size, void* d_ws, size_t ws_size,
                              hipStream_t stream)
{
  const float* x    = (const float*)d_in[0];
  const float* lines= (const float*)d_in[1];
  const float* Wm1  = (const float*)d_in[2];
  const float* bm1  = (const float*)d_in[3];
  const float* Wm2  = (const float*)d_in[4];
  const float* bm2  = (const float*)d_in[5];
  const float* We1  = (const float*)d_in[6];
  const float* be1  = (const float*)d_in[7];
  const float* We2  = (const float*)d_in[8];
  const float* be2  = (const float*)d_in[9];
  const float* We3  = (const float*)d_in[10];
  const float* be3  = (const float*)d_in[11];
  const float* ln_g = (const float*)d_in[12];
  const float* ln_b = (const float*)d_in[13];
  const float* Wq   = (const float*)d_in[14];
  const float* Wk   = (const float*)d_in[15];
  const float* Wv   = (const float*)d_in[16];
  const float* A1   = (const float*)d_in[17];
  const float* a1   = (const float*)d_in[18];
  const float* A2   = (const float*)d_in[19];
  const float* a2   = (const float*)d_in[20];
  const float* alng = (const float*)d_in[21];
  const float* alnb = (const float*)d_in[22];
  const float* mem_k= (const float*)d_in[23];
  const float* mem_v= (const float*)d_in[24];
  const float* M1   = (const float*)d_in[25];
  const float* c1   = (const float*)d_in[26];
  const float* M2   = (const float*)d_in[27];
  const float* c2   = (const float*)d_in[28];
  const float* M3   = (const float*)d_in[29];
  const float* c3   = (const float*)d_in[30];
  const float* M4   = (const float*)d_in[31];
  const float* c4   = (const float*)d_in[32];
  float* out = (float*)d_out;

  char* wp = (char*)d_ws;
  auto alloc = [&](size_t bytes) -> void* {
    void* p = (void*)wp;
    wp += (bytes + 255) & ~(size_t)255;
    return p;
  };
  float* pf     = (float*)alloc((size_t)NPTS*64*4);
  float* pe     = (float*)alloc((size_t)NPTS*64*4);
  u16*   Khf    = (u16*)alloc((size_t)NE*128*4*512*2);   // bf16-hi MFMA A-fragments
  u16*   Klf    = (u16*)alloc((size_t)NE*128*4*512*2);   // bf16-lo
  float* Vhat   = (float*)alloc((size_t)NE*NM*DD*4);
  float* featsC = (float*)alloc((size_t)NE*NPTS*DD*4);
  float* QoutC  = (float*)alloc((size_t)NE*NPTS*DD*4);  // QC then reused as outC
  float* attnWb = (float*)alloc((size_t)NE*NPTS*NTK*4);
  float* slotW  = (float*)alloc((size_t)NE*NPTS*4);
  int*   attnIb = (int*)alloc((size_t)NE*NPTS*NTK*4);
  int*   plist  = (int*)alloc((size_t)NE*NPTS*4);
  int*   pairE  = (int*)alloc((size_t)NPTS*2*4);
  int*   pairS  = (int*)alloc((size_t)NPTS*2*4);
  int*   cnt    = (int*)alloc(64);

  hipMemsetAsync(cnt, 0, 64, stream);
  k_preproc<<<NPTS/256, 256, 0, stream>>>(x, lines, Wm1, bm1, Wm2, bm2,
                                          pf, pe, slotW, plist, pairE, pairS, cnt);
  k_kv<<<dim3(NM/32, NE, 2), 256, 0, stream>>>(mem_k, mem_v, Wk, Wv, Khf, Klf, Vhat);
  k_expert<<<dim3(NPTS/32, NE), 256, 0, stream>>>(pe, We1, be1, We2, be2, We3, be3,
                                                  ln_g, ln_b, Wq, plist, cnt, featsC, QoutC);
  k_scores<<<dim3(NPTS/16, NE), 256, 0, stream>>>(QoutC, Khf, Klf, cnt, attnWb, attnIb);
  k_adapter<<<dim3(NPTS/4, NE), 256, 0, stream>>>(Vhat, pf, A1, a1, A2, a2, alng, alnb,
                                                  attnWb, attnIb, featsC, slotW, plist, cnt,
                                                  QoutC);
  k_final<<<NPTS/FR, 256, 0, stream>>>(QoutC, pairE, pairS, M1, c1, M2, c2, M3, c3, M4, c4, out);
}

// Round 8
// 1567.214 us; speedup vs baseline: 6.8955x; 1.1851x over previous
//
#include <hip/hip_runtime.h>
#include <hip/hip_bf16.h>
#include <math.h>

#define NPTS 16384
#define NE 4
#define NM 2048
#define DD 128    // D3
#define DP 64     // D1
#define NHE 256
#define NHM 256
#define NRES 64
#define NTK 16
#define NEG_INF -3.402823466e38f

typedef unsigned short u16;
typedef __attribute__((ext_vector_type(8))) short short8;
typedef __attribute__((ext_vector_type(4))) float f32x4;

// ---------- helpers ----------
__device__ __forceinline__ bool rank_gt(float av, int ai, float bv, int bi) {
  // "ranks higher in top-k": larger value, ties broken by lower index (jax top_k)
  return (av > bv) || (av == bv && ai < bi);
}

__device__ __forceinline__ u16 f2bf(float x) {   // RNE float -> bf16 bits
  union { float f; unsigned u; } v; v.f = x;
  unsigned r = v.u + 0x7fffu + ((v.u >> 16) & 1u);
  return (u16)(r >> 16);
}
__device__ __forceinline__ float bf2f(u16 b) {
  union { float f; unsigned u; } v; v.u = ((unsigned)b) << 16;
  return v.f;
}

// ---------- kernel 1: per-point preproc ----------
__global__ __launch_bounds__(256) void k_preproc(
    const float* __restrict__ x, const float* __restrict__ lines,
    const float* __restrict__ Wm1, const float* __restrict__ bm1,
    const float* __restrict__ Wm2, const float* __restrict__ bm2,
    float* __restrict__ pf, float* __restrict__ pe,
    float* __restrict__ slotW, int* __restrict__ plist,
    int* __restrict__ pairE, int* __restrict__ pairS, int* __restrict__ cnt)
{
  int n = blockIdx.x * 256 + threadIdx.x;
  if (n >= NPTS) return;
  float c0 = x[n*5+0], c1 = x[n*5+1], c2 = x[n*5+2];

  // ---- gating MLP ----
  float l0 = bm2[0], l1 = bm2[1], l2 = bm2[2], l3 = bm2[3];
#pragma unroll 4
  for (int j = 0; j < 64; ++j) {
    float h = fmaf(c0, Wm1[j], fmaf(c1, Wm1[64+j], fmaf(c2, Wm1[128+j], bm1[j])));
    h = fmaxf(h, 0.f);
    l0 = fmaf(h, Wm2[j*4+0], l0);
    l1 = fmaf(h, Wm2[j*4+1], l1);
    l2 = fmaf(h, Wm2[j*4+2], l2);
    l3 = fmaf(h, Wm2[j*4+3], l3);
  }
  float lg[4] = {l0, l1, l2, l3};
  float mx = fmaxf(fmaxf(l0, l1), fmaxf(l2, l3));
  float pr[4]; float ssum = 0.f;
#pragma unroll
  for (int k = 0; k < 4; ++k) { pr[k] = expf(lg[k] - mx); ssum += pr[k]; }
#pragma unroll
  for (int k = 0; k < 4; ++k) pr[k] /= ssum;
  int i0 = 0;
#pragma unroll
  for (int k = 1; k < 4; ++k) if (pr[k] > pr[i0]) i0 = k;
  int i1 = (i0 == 0) ? 1 : 0;
#pragma unroll
  for (int k = 0; k < 4; ++k) if (k != i0 && pr[k] > pr[i1]) i1 = k;
  float g0 = pr[i0], g1 = pr[i1], gs = g0 + g1;
  g0 /= gs; g1 /= gs;
  int s0 = atomicAdd(&cnt[i0], 1);
  int s1 = atomicAdd(&cnt[i1], 1);
  plist[i0*NPTS + s0] = n; slotW[i0*NPTS + s0] = g0;
  plist[i1*NPTS + s1] = n; slotW[i1*NPTS + s1] = g1;
  pairE[n*2+0] = i0; pairE[n*2+1] = i1;
  pairS[n*2+0] = s0; pairS[n*2+1] = s1;

  // ---- positional encoding (accurate sinf/cosf: args up to 512*pi) ----
  pe[(size_t)n*64 + 0] = c0;
  pe[(size_t)n*64 + 1] = c1;
  pe[(size_t)n*64 + 2] = c2;
  float cc[3] = {c0, c1, c2};
#pragma unroll
  for (int i = 0; i < 10; ++i) {
    float sc = 3.14159274101257324f * (float)(1 << i);
#pragma unroll
    for (int j = 0; j < 3; ++j) {
      float a = sc * cc[j];
      pe[(size_t)n*64 + 3 + (i*3+j)*2 + 0] = sinf(a);
      pe[(size_t)n*64 + 3 + (i*3+j)*2 + 1] = cosf(a);
    }
  }
  pe[(size_t)n*64 + 63] = 0.f;

  // ---- param feats: product of 2 line interpolations ----
  float pfv[64];
#pragma unroll
  for (int d = 0; d < 64; ++d) pfv[d] = 1.f;
  for (int i = 0; i < 2; ++i) {
    float p = x[n*5 + 3 + i] * 63.0f;
    float f = floorf(p);
    float wfr = p - f;
    int j0 = (int)f;
    int j1 = (int)fminf(f + 1.0f, 63.0f);
    const float* L = lines + (size_t)i * 64 * 64;
#pragma unroll
    for (int d = 0; d < 64; ++d) {
      float a = L[d*64 + j0];
      float b = L[d*64 + j1];
      pfv[d] *= a + wfr * (b - a);
    }
  }
#pragma unroll
  for (int d = 0; d < 64; ++d) pf[(size_t)n*64 + d] = pfv[d];
}

// ---------- kernel 2: K/V projection ----------
// K is written as bf16 hi/lo MFMA A-fragments (layout verified on HW in R7).
// V stays fp32 row-major (adapter gathers rows).
__global__ __launch_bounds__(256) void k_kv(
    const float* __restrict__ mem_k, const float* __restrict__ mem_v,
    const float* __restrict__ Wk, const float* __restrict__ Wv,
    u16* __restrict__ Khf, u16* __restrict__ Klf, float* __restrict__ Vhat)
{
  int e = blockIdx.y;
  int which = blockIdx.z;
  const float* src = which ? mem_v : mem_k;
  const float* W   = which ? Wv : Wk;
  int r0 = blockIdx.x * 32;
  __shared__ float sm[32][130];
  int tid = threadIdx.x;
  for (int idx = tid; idx < 32*32; idx += 256) {
    int r = idx >> 5, c4 = (idx & 31) * 4;
    float4 v = *(const float4*)(src + ((size_t)e*NM + r0 + r)*DD + c4);
    sm[r][c4+0] = v.x; sm[r][c4+1] = v.y; sm[r][c4+2] = v.z; sm[r][c4+3] = v.w;
  }
  __syncthreads();
  int r = tid >> 3, cb = (tid & 7) * 16;
  float acc[16];
#pragma unroll
  for (int i = 0; i < 16; ++i) acc[i] = 0.f;
  const float* We = W + (size_t)e*DD*DD;
#pragma unroll 4
  for (int k = 0; k < 128; ++k) {
    float s = sm[r][k];
    const float4* w4 = (const float4*)(We + (size_t)k*DD + cb);
#pragma unroll
    for (int q = 0; q < 4; ++q) {
      float4 wv = w4[q];
      acc[q*4+0] = fmaf(s, wv.x, acc[q*4+0]);
      acc[q*4+1] = fmaf(s, wv.y, acc[q*4+1]);
      acc[q*4+2] = fmaf(s, wv.z, acc[q*4+2]);
      acc[q*4+3] = fmaf(s, wv.w, acc[q*4+3]);
    }
  }
  if (which) {
    float* drow = Vhat + ((size_t)e*NM + r0 + r)*DD + cb;
#pragma unroll
    for (int i = 0; i < 16; ++i) drow[i] = acc[i];
  } else {
    int key = r0 + r;
    int T = key >> 4;
    int kr = key & 15;
#pragma unroll
    for (int b = 0; b < 2; ++b) {
      int k_off = cb + b*8;
      int kt = k_off >> 5;
      int lhi = (k_off >> 3) & 3;
      int lane_ = lhi*16 + kr;
      size_t dst = (((size_t)e*128 + T)*4 + kt)*512 + (size_t)lane_*8;
      unsigned ph[4], pl[4];
#pragma unroll
      for (int p = 0; p < 4; ++p) {
        float x0 = acc[b*8 + p*2 + 0];
        float x1 = acc[b*8 + p*2 + 1];
        u16 h0 = f2bf(x0), h1 = f2bf(x1);
        u16 l0v = f2bf(x0 - bf2f(h0)), l1v = f2bf(x1 - bf2f(h1));
        ph[p] = (unsigned)h0 | ((unsigned)h1 << 16);
        pl[p] = (unsigned)l0v | ((unsigned)l1v << 16);
      }
      *(uint4*)(Khf + dst) = make_uint4(ph[0], ph[1], ph[2], ph[3]);
      *(uint4*)(Klf + dst) = make_uint4(pl[0], pl[1], pl[2], pl[3]);
    }
  }
}

// ---------- kernel 2b: pack A1/A2 adapter weights into bf16 hi/lo B-fragments ----------
// B-frag layout (HW-verified via k_scores Q-frags): lane = khalf*16 + col,
// 8 contiguous k elems: B[ks*32 + khalf*8 + j][ct*16 + col].
// A1: [192][64] -> 24 frags (6 ks x 4 ct). A2: [64][128] -> 16 frags (2 ks x 8 ct).
__global__ __launch_bounds__(256) void k_pack(
    const float* __restrict__ A1, const float* __restrict__ A2,
    u16* __restrict__ A1h, u16* __restrict__ A1l,
    u16* __restrict__ A2h, u16* __restrict__ A2l)
{
  int e = blockIdx.x;
  int tid = threadIdx.x;
  for (int idx = tid; idx < 40*64; idx += 256) {
    int frag = idx >> 6, lane = idx & 63;
    int col = lane & 15, khalf = lane >> 4;
    unsigned ph[4], pl[4];
    if (frag < 24) {
      int ks = frag >> 2;
      int ct = frag & 3;
      const float* src = A1 + (size_t)e*192*64;
#pragma unroll
      for (int p = 0; p < 4; ++p) {
        float x0 = src[(size_t)(ks*32 + khalf*8 + 2*p + 0)*64 + ct*16 + col];
        float x1 = src[(size_t)(ks*32 + khalf*8 + 2*p + 1)*64 + ct*16 + col];
        u16 h0 = f2bf(x0), h1 = f2bf(x1);
        u16 l0 = f2bf(x0 - bf2f(h0)), l1 = f2bf(x1 - bf2f(h1));
        ph[p] = (unsigned)h0 | ((unsigned)h1 << 16);
        pl[p] = (unsigned)l0 | ((unsigned)l1 << 16);
      }
      size_t dst = ((size_t)e*24 + frag)*512 + (size_t)lane*8;
      *(uint4*)(A1h + dst) = make_uint4(ph[0], ph[1], ph[2], ph[3]);
      *(uint4*)(A1l + dst) = make_uint4(pl[0], pl[1], pl[2], pl[3]);
    } else {
      int f2 = frag - 24;
      int ks = f2 >> 3;
      int ct = f2 & 7;
      const float* src = A2 + (size_t)e*64*DD;
#pragma unroll
      for (int p = 0; p < 4; ++p) {
        float x0 = src[(size_t)(ks*32 + khalf*8 + 2*p + 0)*DD + ct*16 + col];
        float x1 = src[(size_t)(ks*32 + khalf*8 + 2*p + 1)*DD + ct*16 + col];
        u16 h0 = f2bf(x0), h1 = f2bf(x1);
        u16 l0 = f2bf(x0 - bf2f(h0)), l1 = f2bf(x1 - bf2f(h1));
        ph[p] = (unsigned)h0 | ((unsigned)h1 << 16);
        pl[p] = (unsigned)l0 | ((unsigned)l1 << 16);
      }
      size_t dst = ((size_t)e*16 + f2)*512 + (size_t)lane*8;
      *(uint4*)(A2h + dst) = make_uint4(ph[0], ph[1], ph[2], ph[3]);
      *(uint4*)(A2l + dst) = make_uint4(pl[0], pl[1], pl[2], pl[3]);
    }
  }
}

// ---------- kernel 3: routed expert SIREN MLP + LN + Q-proj (LDS-staged weights) ----------
__global__ __launch_bounds__(256) void k_expert(
    const float* __restrict__ pe,
    const float* __restrict__ We1, const float* __restrict__ be1,
    const float* __restrict__ We2, const float* __restrict__ be2,
    const float* __restrict__ We3, const float* __restrict__ be3,
    const float* __restrict__ ln_g, const float* __restrict__ ln_b,
    const float* __restrict__ Wq,
    const int* __restrict__ plist, const int* __restrict__ cnt,
    float* __restrict__ featsC, float* __restrict__ QC)
{
  int e = blockIdx.y;
  int count = cnt[e];
  int base = blockIdx.x * 32;
  if (base >= count) return;
  __shared__ float A[32][260];
  __shared__ float B[32][260];
  __shared__ float Wt[2176];
  __shared__ int pts[32];
  int tid = threadIdx.x;
  if (tid < 32) {
    int slot = base + tid;
    pts[tid] = (slot < count) ? plist[e*NPTS + slot] : 0;
  }
  __syncthreads();
  // pe rows into A[r][0..63]
  for (int idx = tid; idx < 32*16; idx += 256) {
    int rr = idx >> 4, c4 = (idx & 15) * 4;
    *(float4*)&A[rr][c4] = *(const float4*)(pe + (size_t)pts[rr]*64 + c4);
  }
  int rg = tid >> 4, cg = tid & 15;
  int r0 = rg*2, r1 = r0+1, c16 = cg*16, c8 = cg*8;
  int slot0 = base + r0, slot1 = base + r1;

  float acc0[16], acc1[16];

  // ---- L1: 63 -> 256, sin(30x): A[.][0..62] -> B ----
  {
    const float* be = be1 + e*NHE;
#pragma unroll
    for (int i = 0; i < 16; ++i) { acc0[i] = be[c16+i]; acc1[i] = acc0[i]; }
    const float* W = We1 + (size_t)e*63*NHE;
    for (int kc = 0; kc < 8; ++kc) {
      int kbase = kc*8;
      int rows = (kc == 7) ? 7 : 8;
      __syncthreads();
      for (int idx = tid; idx < rows*64; idx += 256) {
        int kk = idx >> 6, c4 = (idx & 63) * 4;
        *(float4*)&Wt[kk*260 + c4] = *(const float4*)(W + (size_t)(kbase+kk)*NHE + c4);
      }
      __syncthreads();
      for (int kk = 0; kk < rows; ++kk) {
        float a0 = A[r0][kbase+kk], a1v = A[r1][kbase+kk];
        const float* wr = &Wt[kk*260 + c16];
#pragma unroll
        for (int q = 0; q < 4; ++q) {
          float4 wv = *(const float4*)(wr + q*4);
          acc0[q*4+0] = fmaf(a0, wv.x, acc0[q*4+0]);
          acc0[q*4+1] = fmaf(a0, wv.y, acc0[q*4+1]);
          acc0[q*4+2] = fmaf(a0, wv.z, acc0[q*4+2]);
          acc0[q*4+3] = fmaf(a0, wv.w, acc0[q*4+3]);
          acc1[q*4+0] = fmaf(a1v, wv.x, acc1[q*4+0]);
          acc1[q*4+1] = fmaf(a1v, wv.y, acc1[q*4+1]);
          acc1[q*4+2] = fmaf(a1v, wv.z, acc1[q*4+2]);
          acc1[q*4+3] = fmaf(a1v, wv.w, acc1[q*4+3]);
        }
      }
    }
#pragma unroll
    for (int i = 0; i < 16; ++i) {
      B[r0][c16+i] = sinf(30.0f*acc0[i]);
      B[r1][c16+i] = sinf(30.0f*acc1[i]);
    }
  }

  // ---- L2: 256 -> 256, sin(30x): B -> A ----
  {
    const float* be = be2 + e*NHE;
#pragma unroll
    for (int i = 0; i < 16; ++i) { acc0[i] = be[c16+i]; acc1[i] = acc0[i]; }
    const float* W = We2 + (size_t)e*NHE*NHE;
    for (int kc = 0; kc < 32; ++kc) {
      __syncthreads();
      for (int idx = tid; idx < 512; idx += 256) {
        int kk = idx >> 6, c4 = (idx & 63) * 4;
        *(float4*)&Wt[kk*260 + c4] = *(const float4*)(W + (size_t)(kc*8+kk)*NHE + c4);
      }
      __syncthreads();
#pragma unroll
      for (int kk = 0; kk < 8; ++kk) {
        float a0 = B[r0][kc*8+kk], a1v = B[r1][kc*8+kk];
        const float* wr = &Wt[kk*260 + c16];
#pragma unroll
        for (int q = 0; q < 4; ++q) {
          float4 wv = *(const float4*)(wr + q*4);
          acc0[q*4+0] = fmaf(a0, wv.x, acc0[q*4+0]);
          acc0[q*4+1] = fmaf(a0, wv.y, acc0[q*4+1]);
          acc0[q*4+2] = fmaf(a0, wv.z, acc0[q*4+2]);
          acc0[q*4+3] = fmaf(a0, wv.w, acc0[q*4+3]);
          acc1[q*4+0] = fmaf(a1v, wv.x, acc1[q*4+0]);
          acc1[q*4+1] = fmaf(a1v, wv.y, acc1[q*4+1]);
          acc1[q*4+2] = fmaf(a1v, wv.z, acc1[q*4+2]);
          acc1[q*4+3] = fmaf(a1v, wv.w, acc1[q*4+3]);
        }
      }
    }
#pragma unroll
    for (int i = 0; i < 16; ++i) {
      A[r0][c16+i] = sinf(30.0f*acc0[i]);
      A[r1][c16+i] = sinf(30.0f*acc1[i]);
    }
  }

  // ---- L3: 256 -> 128 linear: A -> feats (regs) ----
  float f0[8], f1[8];
  {
    const float* be = be3 + e*DD;
#pragma unroll
    for (int i = 0; i < 8; ++i) { f0[i] = be[c8+i]; f1[i] = f0[i]; }
    const float* W = We3 + (size_t)e*NHE*DD;
    for (int kc = 0; kc < 16; ++kc) {
      __syncthreads();
      for (int idx = tid; idx < 512; idx += 256) {
        int kk = idx >> 5, c4 = (idx & 31) * 4;
        *(float4*)&Wt[kk*132 + c4] = *(const float4*)(W + (size_t)(kc*16+kk)*DD + c4);
      }
      __syncthreads();
#pragma unroll
      for (int kk = 0; kk < 16; ++kk) {
        float a0 = A[r0][kc*16+kk], a1v = A[r1][kc*16+kk];
        const float* wr = &Wt[kk*132 + c8];
#pragma unroll
        for (int q = 0; q < 2; ++q) {
          float4 wv = *(const float4*)(wr + q*4);
          f0[q*4+0] = fmaf(a0, wv.x, f0[q*4+0]);
          f0[q*4+1] = fmaf(a0, wv.y, f0[q*4+1]);
          f0[q*4+2] = fmaf(a0, wv.z, f0[q*4+2]);
          f0[q*4+3] = fmaf(a0, wv.w, f0[q*4+3]);
          f1[q*4+0] = fmaf(a1v, wv.x, f1[q*4+0]);
          f1[q*4+1] = fmaf(a1v, wv.y, f1[q*4+1]);
          f1[q*4+2] = fmaf(a1v, wv.z, f1[q*4+2]);
          f1[q*4+3] = fmaf(a1v, wv.w, f1[q*4+3]);
        }
      }
    }
  }

  // ---- LN (register + cg-shuffle) -> q into B[r][128..255]; feats to global ----
  {
    float sm0=0.f, sq0=0.f, sm1=0.f, sq1=0.f;
#pragma unroll
    for (int i = 0; i < 8; ++i) {
      sm0 += f0[i]; sq0 += f0[i]*f0[i];
      sm1 += f1[i]; sq1 += f1[i]*f1[i];
    }
#pragma unroll
    for (int m = 1; m < 16; m <<= 1) {
      sm0 += __shfl_xor(sm0, m); sq0 += __shfl_xor(sq0, m);
      sm1 += __shfl_xor(sm1, m); sq1 += __shfl_xor(sq1, m);
    }
    float mu0 = sm0*(1.f/128.f), mu1 = sm1*(1.f/128.f);
    float rs0 = rsqrtf(sq0*(1.f/128.f) - mu0*mu0 + 1e-5f);
    float rs1 = rsqrtf(sq1*(1.f/128.f) - mu1*mu1 + 1e-5f);
#pragma unroll
    for (int i = 0; i < 8; ++i) {
      float g = ln_g[c8+i], b = ln_b[c8+i];
      B[r0][128+c8+i] = (f0[i]-mu0)*rs0*g + b;
      B[r1][128+c8+i] = (f1[i]-mu1)*rs1*g + b;
    }
    if (slot0 < count) {
      size_t o = ((size_t)e*NPTS + slot0)*DD;
#pragma unroll
      for (int i = 0; i < 8; ++i) featsC[o + c8 + i] = f0[i];
    }
    if (slot1 < count) {
      size_t o = ((size_t)e*NPTS + slot1)*DD;
#pragma unroll
      for (int i = 0; i < 8; ++i) featsC[o + c8 + i] = f1[i];
    }
  }

  // ---- Wq: q(128) -> Q(128): B[.][128..255] -> QC ----
  {
    float g0[8], g1[8];
#pragma unroll
    for (int i = 0; i < 8; ++i) { g0[i] = 0.f; g1[i] = 0.f; }
    const float* W = Wq + (size_t)e*DD*DD;
    for (int kc = 0; kc < 8; ++kc) {
      __syncthreads();
      for (int idx = tid; idx < 512; idx += 256) {
        int kk = idx >> 5, c4 = (idx & 31) * 4;
        *(float4*)&Wt[kk*132 + c4] = *(const float4*)(W + (size_t)(kc*16+kk)*DD + c4);
      }
      __syncthreads();
#pragma unroll
      for (int kk = 0; kk < 16; ++kk) {
        float a0 = B[r0][128+kc*16+kk], a1v = B[r1][128+kc*16+kk];
        const float* wr = &Wt[kk*132 + c8];
#pragma unroll
        for (int q = 0; q < 2; ++q) {
          float4 wv = *(const float4*)(wr + q*4);
          g0[q*4+0] = fmaf(a0, wv.x, g0[q*4+0]);
          g0[q*4+1] = fmaf(a0, wv.y, g0[q*4+1]);
          g0[q*4+2] = fmaf(a0, wv.z, g0[q*4+2]);
          g0[q*4+3] = fmaf(a0, wv.w, g0[q*4+3]);
          g1[q*4+0] = fmaf(a1v, wv.x, g1[q*4+0]);
          g1[q*4+1] = fmaf(a1v, wv.y, g1[q*4+1]);
          g1[q*4+2] = fmaf(a1v, wv.z, g1[q*4+2]);
          g1[q*4+3] = fmaf(a1v, wv.w, g1[q*4+3]);
        }
      }
    }
    if (slot0 < count) {
      size_t o = ((size_t)e*NPTS + slot0)*DD;
#pragma unroll
      for (int i = 0; i < 8; ++i) QC[o + c8 + i] = g0[i];
    }
    if (slot1 < count) {
      size_t o = ((size_t)e*NPTS + slot1)*DD;
#pragma unroll
      for (int i = 0; i < 8; ++i) QC[o + c8 + i] = g1[i];
    }
  }
}

// ---------- kernel 4: MFMA scores + wave-distributed top-16 + softmax ----------
__global__ __launch_bounds__(256) void k_scores(
    const float* __restrict__ QC, const u16* __restrict__ Khf, const u16* __restrict__ Klf,
    const int* __restrict__ cnt,
    float* __restrict__ attnW, int* __restrict__ attnI)
{
  int e = blockIdx.y;
  int count = cnt[e];
  int sbase = blockIdx.x * 16;
  if (sbase >= count) return;
  __shared__ u16 KhS[16*512];    // [t][kt][lane][8]  16 KB
  __shared__ u16 KlS[16*512];    // 16 KB
  __shared__ u16 QhS[4*512];     // [kt][lane][8]  4 KB
  __shared__ u16 QlS[4*512];     // 4 KB
  __shared__ float Ssc[64][17];  // padded: insert-phase column reads conflict-free
  int tid = threadIdx.x;
  int w = tid >> 6, lane = tid & 63;

  // ---- build Q B-fragments (hi/lo): thread = (kt=w, lane) ----
  {
    int srow = lane & 15, khalf = lane >> 4;
    int slot = sbase + srow;
    float q[8];
    if (slot < count) {
      const float* Qr = QC + ((size_t)e*NPTS + slot)*DD + w*32 + khalf*8;
#pragma unroll
      for (int i = 0; i < 8; ++i) q[i] = Qr[i];
    } else {
#pragma unroll
      for (int i = 0; i < 8; ++i) q[i] = 0.f;
    }
    int dst = w*512 + lane*8;
#pragma unroll
    for (int i = 0; i < 8; ++i) {
      u16 h = f2bf(q[i]);
      QhS[dst + i] = h;
      QlS[dst + i] = f2bf(q[i] - bf2f(h));
    }
  }
  // (visibility of QhS/QlS covered by first chunk's barrier)

  float lv = NEG_INF;
  int   li = 0x7fffffff;
  const u16* KhB = Khf + (size_t)e*128*4*512;
  const u16* KlB = Klf + (size_t)e*128*4*512;

  for (int ch = 0; ch < NM/64; ++ch) {
    // stage 16 KB hi + 16 KB lo (contiguous: 4 key-tiles x 4 kt x 1 KB)
    {
      const uint4* srcH = (const uint4*)(KhB + (size_t)ch*8192);
      const uint4* srcL = (const uint4*)(KlB + (size_t)ch*8192);
      uint4* dH = (uint4*)KhS; uint4* dL = (uint4*)KlS;
#pragma unroll
      for (int i = 0; i < 4; ++i) {
        dH[tid + i*256] = srcH[tid + i*256];
        dL[tid + i*256] = srcL[tid + i*256];
      }
    }
    __syncthreads();

    // MFMA: wave w -> key-tile w, all 16 slots
    {
      f32x4 acc = {0.f, 0.f, 0.f, 0.f};
#pragma unroll
      for (int kt = 0; kt < 4; ++kt) {
        int ko = (w*4 + kt)*512 + lane*8;
        int qo = kt*512 + lane*8;
        short8 ah = *(const short8*)&KhS[ko];
        short8 al = *(const short8*)&KlS[ko];
        short8 bh = *(const short8*)&QhS[qo];
        short8 bl = *(const short8*)&QlS[qo];
        acc = __builtin_amdgcn_mfma_f32_16x16x32_bf16(ah, bh, acc, 0, 0, 0);
        acc = __builtin_amdgcn_mfma_f32_16x16x32_bf16(ah, bl, acc, 0, 0, 0);
        acc = __builtin_amdgcn_mfma_f32_16x16x32_bf16(al, bh, acc, 0, 0, 0);
      }
      int col = lane & 15, rbase = (lane >> 4) * 4;
#pragma unroll
      for (int i = 0; i < 4; ++i)
        Ssc[w*16 + rbase + i][col] = acc[i];
    }
    __syncthreads();

    // threshold-gated distributed inserts (lane = key in chunk)
#pragma unroll
    for (int j = 0; j < 4; ++j) {
      int slot = sbase + w*4 + j;
      if (slot >= count) continue;   // wave-uniform
      float v = Ssc[lane][w*4 + j];
      int key = ch*64 + lane;
      float Tv = __shfl(lv, j*16 + 15);
      int   Ti = __shfl(li, j*16 + 15);
      unsigned long long mb = __ballot(rank_gt(v, key, Tv, Ti));
      while (mb) {
        int b = __ffsll((unsigned long long)mb) - 1;
        mb &= mb - 1;
        float cv = __shfl(v, b);
        int   ck = ch*64 + b;
        Tv = __shfl(lv, j*16 + 15);
        Ti = __shfl(li, j*16 + 15);
        if (!rank_gt(cv, ck, Tv, Ti)) continue;  // stale candidate (uniform branch)
        float pv = __shfl_up(lv, 1);
        int   pi = __shfl_up(li, 1);
        int p = lane & 15;
        bool abv_me   = rank_gt(lv, li, cv, ck);
        bool abv_prev = (p == 0) || rank_gt(pv, pi, cv, ck);
        float nv = abv_me ? lv : (abv_prev ? cv : pv);
        int   ni = abv_me ? li : (abv_prev ? ck : pi);
        if ((lane >> 4) == j) { lv = nv; li = ni; }
      }
    }
  }

  const float inv_scale = 0.08838834764831845f;  // 1/sqrt(128)
#pragma unroll
  for (int j = 0; j < 4; ++j) {
    int slot = sbase + w*4 + j;
    if (slot >= count) continue;
    float m = __shfl(lv, j*16 + 0);
    float ev = expf((lv - m) * inv_scale);
    float s = ev;
    s += __shfl_xor(s, 1); s += __shfl_xor(s, 2);
    s += __shfl_xor(s, 4); s += __shfl_xor(s, 8);
    if ((lane >> 4) == j) {
      size_t off = ((size_t)e*NPTS + slot)*NTK + (lane & 15);
      attnW[off] = ev / s;
      attnI[off] = li;
    }
  }
}

// ---------- kernel 5: MFMA adapter MLP + LN + attention combine ----------
// Wave w owns slot w's 16 keys (row-tile). L1: 64 rows x 64 cols, K=192 ->
// 6 ks x 4 ct x 3-term = 72 MFMA/wave. L2: K=64, 128 cols -> 48 MFMA/wave.
// A-fragments built in-register from LDS (ainV/pfS/hid); B-fragments (weights)
// pre-packed by k_pack, read from global (L2-resident, ~80 KB/block).
// hid write/read is same-wave (DS ops in-order) -> no barrier. LN stats via
// 16-lane-group shfl_xor; key-reduce via shfl_xor(16,32).
// R7 post-mortem: VALU version was LDS-issue-bound (1536 LDS instr/thread);
// this has ~60 LDS instr/thread + 120 MFMA/wave. LDS 52.7 KB -> 3 blocks/CU.
__global__ __launch_bounds__(256) void k_adapter(
    const float* __restrict__ Vhat, const float* __restrict__ pf,
    const u16* __restrict__ A1h, const u16* __restrict__ A1l,
    const u16* __restrict__ A2h, const u16* __restrict__ A2l,
    const float* __restrict__ a1, const float* __restrict__ a2,
    const float* __restrict__ alng, const float* __restrict__ alnb,
    const float* __restrict__ attnW, const int* __restrict__ attnI,
    const float* __restrict__ featsC, const float* __restrict__ slotW,
    const int* __restrict__ plist, const int* __restrict__ cnt,
    float* __restrict__ outC)
{
  int e = blockIdx.y;
  int count = cnt[e];
  int s0 = blockIdx.x * 4;
  if (s0 >= count) return;
  __shared__ float ainV[64][132];   // 4 slots x 16 keys of Vhat rows (33.8 KB)
  __shared__ float hid[64][68];     // hidden, C-layout -> A-layout transpose (17.4 KB)
  __shared__ float pfS[4][68];
  __shared__ float attwS[4][16];
  __shared__ float alnS[128], albS[128];
  __shared__ int   rtiS[64];
  __shared__ float wslS[4];
  __shared__ int   ptlS[4];
  int tid = threadIdx.x;
  if (tid < 64) {
    int sl = tid >> 4, key = tid & 15;
    int slot = s0 + sl;
    if (slot < count) {
      size_t o = ((size_t)e*NPTS + slot)*NTK + key;
      rtiS[tid] = attnI[o];
      attwS[sl][key] = attnW[o];
    } else { rtiS[tid] = 0; attwS[sl][key] = 0.f; }
  } else if (tid < 68) {
    int sl = tid - 64;
    int slot = s0 + sl;
    wslS[sl] = (slot < count) ? slotW[e*NPTS + slot] : 0.f;
    ptlS[sl] = (slot < count) ? plist[e*NPTS + slot] : 0;
  } else if (tid >= 128 && tid < 192) {
    int c2 = (tid - 128) * 2;
    alnS[c2]   = alng[e*DD + c2];
    alnS[c2+1] = alng[e*DD + c2+1];
    albS[c2]   = alnb[e*DD + c2];
    albS[c2+1] = alnb[e*DD + c2+1];
  }
  __syncthreads();
  for (int idx = tid; idx < 64*32; idx += 256) {
    int r = idx >> 5, c4 = (idx & 31) * 4;
    *(float4*)&ainV[r][c4] = *(const float4*)(Vhat + ((size_t)e*NM + rtiS[r])*DD + c4);
  }
  if (tid < 64) {
    int sl = tid >> 4, c4 = (tid & 15) * 4;
    *(float4*)&pfS[sl][c4] = *(const float4*)(pf + (size_t)ptlS[sl]*64 + c4);
  }
  __syncthreads();

  int w = tid >> 6, lane = tid & 63;
  int rloc = lane & 15;       // A-frag row-in-tile / C col-in-tile
  int khalf = lane >> 4;      // A-frag k-half / C row-group

  // ---- L1 MFMA: hidden = relu(ain @ A1 + a1) ----
  f32x4 acc1[4];
#pragma unroll
  for (int ct = 0; ct < 4; ++ct) acc1[ct] = (f32x4){0.f, 0.f, 0.f, 0.f};
  for (int ks = 0; ks < 6; ++ks) {
    short8 ah, al;
    {
      const float* src = (ks < 4) ? &ainV[w*16 + rloc][ks*32 + khalf*8]
                                  : &pfS[w][(ks-4)*32 + khalf*8];
      float4 u0 = *(const float4*)(src);
      float4 u1 = *(const float4*)(src + 4);
      float xv[8] = {u0.x, u0.y, u0.z, u0.w, u1.x, u1.y, u1.z, u1.w};
      union { unsigned u[4]; short8 s; } H, L;
#pragma unroll
      for (int p = 0; p < 4; ++p) {
        u16 h0 = f2bf(xv[2*p]),  h1 = f2bf(xv[2*p+1]);
        u16 l0 = f2bf(xv[2*p] - bf2f(h0)), l1 = f2bf(xv[2*p+1] - bf2f(h1));
        H.u[p] = (unsigned)h0 | ((unsigned)h1 << 16);
        L.u[p] = (unsigned)l0 | ((unsigned)l1 << 16);
      }
      ah = H.s; al = L.s;
    }
    const u16* bh0 = A1h + ((size_t)e*24 + ks*4)*512 + (size_t)lane*8;
    const u16* bl0 = A1l + ((size_t)e*24 + ks*4)*512 + (size_t)lane*8;
#pragma unroll
    for (int ct = 0; ct < 4; ++ct) {
      short8 bh = *(const short8*)(bh0 + ct*512);
      short8 bl = *(const short8*)(bl0 + ct*512);
      acc1[ct] = __builtin_amdgcn_mfma_f32_16x16x32_bf16(ah, bh, acc1[ct], 0, 0, 0);
      acc1[ct] = __builtin_amdgcn_mfma_f32_16x16x32_bf16(ah, bl, acc1[ct], 0, 0, 0);
      acc1[ct] = __builtin_amdgcn_mfma_f32_16x16x32_bf16(al, bh, acc1[ct], 0, 0, 0);
    }
  }
  // bias + relu -> hid (C layout: row = khalf*4+i, col = ct*16+rloc); same-wave
#pragma unroll
  for (int ct = 0; ct < 4; ++ct) {
    float b = a1[e*64 + ct*16 + rloc];
#pragma unroll
    for (int i = 0; i < 4; ++i)
      hid[w*16 + khalf*4 + i][ct*16 + rloc] = fmaxf(acc1[ct][i] + b, 0.f);
  }

  // ---- L2 MFMA: ad = hidden @ A2 + a2 ----
  f32x4 acc2[8];
#pragma unroll
  for (int ct = 0; ct < 8; ++ct) acc2[ct] = (f32x4){0.f, 0.f, 0.f, 0.f};
  for (int ks = 0; ks < 2; ++ks) {
    short8 ah, al;
    {
      const float* src = &hid[w*16 + rloc][ks*32 + khalf*8];
      float4 u0 = *(const float4*)(src);
      float4 u1 = *(const float4*)(src + 4);
      float xv[8] = {u0.x, u0.y, u0.z, u0.w, u1.x, u1.y, u1.z, u1.w};
      union { unsigned u[4]; short8 s; } H, L;
#pragma unroll
      for (int p = 0; p < 4; ++p) {
        u16 h0 = f2bf(xv[2*p]),  h1 = f2bf(xv[2*p+1]);
        u16 l0 = f2bf(xv[2*p] - bf2f(h0)), l1 = f2bf(xv[2*p+1] - bf2f(h1));
        H.u[p] = (unsigned)h0 | ((unsigned)h1 << 16);
        L.u[p] = (unsigned)l0 | ((unsigned)l1 << 16);
      }
      ah = H.s; al = L.s;
    }
    const u16* bh0 = A2h + ((size_t)e*16 + ks*8)*512 + (size_t)lane*8;
    const u16* bl0 = A2l + ((size_t)e*16 + ks*8)*512 + (size_t)lane*8;
#pragma unroll
    for (int ct = 0; ct < 8; ++ct) {
      short8 bh = *(const short8*)(bh0 + ct*512);
      short8 bl = *(const short8*)(bl0 + ct*512);
      acc2[ct] = __builtin_amdgcn_mfma_f32_16x16x32_bf16(ah, bh, acc2[ct], 0, 0, 0);
      acc2[ct] = __builtin_amdgcn_mfma_f32_16x16x32_bf16(ah, bl, acc2[ct], 0, 0, 0);
      acc2[ct] = __builtin_amdgcn_mfma_f32_16x16x32_bf16(al, bh, acc2[ct], 0, 0, 0);
    }
  }

  // ---- bias; LN stats per row (16-lane-group shfl reduce over cols) ----
  float ad[8][4];
#pragma unroll
  for (int ct = 0; ct < 8; ++ct) {
    float b = a2[e*DD + ct*16 + rloc];
#pragma unroll
    for (int i = 0; i < 4; ++i) ad[ct][i] = acc2[ct][i] + b;
  }
  float mu[4], rsv[4];
#pragma unroll
  for (int i = 0; i < 4; ++i) {
    float sm = 0.f, sq = 0.f;
#pragma unroll
    for (int ct = 0; ct < 8; ++ct) { sm += ad[ct][i]; sq += ad[ct][i]*ad[ct][i]; }
    sm += __shfl_xor(sm, 1); sq += __shfl_xor(sq, 1);
    sm += __shfl_xor(sm, 2); sq += __shfl_xor(sq, 2);
    sm += __shfl_xor(sm, 4); sq += __shfl_xor(sq, 4);
    sm += __shfl_xor(sm, 8); sq += __shfl_xor(sq, 8);
    mu[i] = sm * (1.f/128.f);
    float var = sq * (1.f/128.f) - mu[i]*mu[i];
    rsv[i] = rsqrtf(var + 1e-5f);
  }
  float aw[4];
#pragma unroll
  for (int i = 0; i < 4; ++i) aw[i] = attwS[w][khalf*4 + i];

  // ---- Va = Vt + LN(ad)*g + b, attn-weighted partial sum over own 4 rows ----
  float outv[8];
#pragma unroll
  for (int ct = 0; ct < 8; ++ct) {
    int cg = ct*16 + rloc;
    float g = alnS[cg], bb = albS[cg];
    float s = 0.f;
#pragma unroll
    for (int i = 0; i < 4; ++i) {
      float vt = ainV[w*16 + khalf*4 + i][cg];
      s += aw[i] * (vt + (ad[ct][i] - mu[i]) * rsv[i] * g + bb);
    }
    outv[ct] = s;
  }
  // reduce across the 4 row-groups
#pragma unroll
  for (int ct = 0; ct < 8; ++ct) {
    outv[ct] += __shfl_xor(outv[ct], 16);
    outv[ct] += __shfl_xor(outv[ct], 32);
  }
  int slot = s0 + w;
  if (khalf == 0 && slot < count) {
    size_t o = ((size_t)e*NPTS + slot)*DD;
    float wg = wslS[w];
#pragma unroll
    for (int ct = 0; ct < 8; ++ct) {
      int cg = ct*16 + rloc;
      outC[o + cg] = wg * (outv[ct] + featsC[o + cg]);
    }
  }
}

// ---------- kernel 6: gather pairs + final MLP + sigmoid ----------
#define FR 32
__device__ __forceinline__ void mlp_layer_f(
    const float (*X)[260], float (*Y)[260], float (*Wt)[260],
    const float* __restrict__ W, const float* __restrict__ bias,
    int K, int tid)
{
  int rg = tid >> 4;
  int cg = tid & 15;
  int r0 = rg * 2;
  int c16 = cg * 16;
  float acc0[16], acc1[16];
#pragma unroll
  for (int i = 0; i < 16; ++i) { acc0[i] = 0.f; acc1[i] = 0.f; }
  int nkc = K >> 3;
  for (int kc = 0; kc < nkc; ++kc) {
    __syncthreads();
    for (int idx = tid; idx < 512; idx += 256) {
      int rr = idx >> 6, c4 = (idx & 63) * 4;
      *(float4*)&Wt[rr][c4] = *(const float4*)(W + (size_t)(kc*8 + rr)*NHM + c4);
    }
    __syncthreads();
#pragma unroll
    for (int kk = 0; kk < 8; ++kk) {
      float a0 = X[r0][kc*8 + kk];
      float a1 = X[r0+1][kc*8 + kk];
#pragma unroll
      for (int q = 0; q < 4; ++q) {
        float4 wv = *(const float4*)&Wt[kk][c16 + q*4];
        acc0[q*4+0] = fmaf(a0, wv.x, acc0[q*4+0]);
        acc0[q*4+1] = fmaf(a0, wv.y, acc0[q*4+1]);
        acc0[q*4+2] = fmaf(a0, wv.z, acc0[q*4+2]);
        acc0[q*4+3] = fmaf(a0, wv.w, acc0[q*4+3]);
        acc1[q*4+0] = fmaf(a1, wv.x, acc1[q*4+0]);
        acc1[q*4+1] = fmaf(a1, wv.y, acc1[q*4+1]);
        acc1[q*4+2] = fmaf(a1, wv.z, acc1[q*4+2]);
        acc1[q*4+3] = fmaf(a1, wv.w, acc1[q*4+3]);
      }
    }
  }
  float4 b0 = *(const float4*)(bias + c16);
  float4 b1 = *(const float4*)(bias + c16 + 4);
  float4 b2 = *(const float4*)(bias + c16 + 8);
  float4 b3 = *(const float4*)(bias + c16 + 12);
  float bb[16] = {b0.x,b0.y,b0.z,b0.w, b1.x,b1.y,b1.z,b1.w,
                  b2.x,b2.y,b2.z,b2.w, b3.x,b3.y,b3.z,b3.w};
  __syncthreads();
#pragma unroll
  for (int i = 0; i < 16; ++i) {
    Y[r0][c16+i]   = fmaxf(acc0[i] + bb[i], 0.f);
    Y[r0+1][c16+i] = fmaxf(acc1[i] + bb[i], 0.f);
  }
}

__global__ __launch_bounds__(256) void k_final(
    const float* __restrict__ outC, const int* __restrict__ pairE, const int* __restrict__ pairS,
    const float* __restrict__ M1, const float* __restrict__ c1,
    const float* __restrict__ M2, const float* __restrict__ c2,
    const float* __restrict__ M3, const float* __restrict__ c3,
    const float* __restrict__ M4, const float* __restrict__ c4,
    float* __restrict__ out)
{
  int base = blockIdx.x * FR;
  __shared__ float A[FR][260];
  __shared__ float B[FR][260];
  __shared__ float Wt[8][260];
  __shared__ int prE[FR*2];
  __shared__ int prS[FR*2];
  int tid = threadIdx.x;
  if (tid < FR*2) {
    prE[tid] = pairE[(size_t)base*2 + tid];
    prS[tid] = pairS[(size_t)base*2 + tid];
  }
  __syncthreads();
  for (int idx = tid; idx < FR*32; idx += 256) {
    int rr = idx >> 5, c4 = (idx & 31) * 4;
    float4 a = *(const float4*)(outC + ((size_t)prE[rr*2+0]*NPTS + prS[rr*2+0])*DD + c4);
    float4 b = *(const float4*)(outC + ((size_t)prE[rr*2+1]*NPTS + prS[rr*2+1])*DD + c4);
    A[rr][c4+0] = a.x + b.x; A[rr][c4+1] = a.y + b.y;
    A[rr][c4+2] = a.z + b.z; A[rr][c4+3] = a.w + b.w;
  }

  mlp_layer_f(A, B, Wt, M1, c1, 128, tid);
  mlp_layer_f(B, A, Wt, M2, c2, 256, tid);
  mlp_layer_f(A, B, Wt, M3, c3, 256, tid);

  __syncthreads();
  {
    int rg = tid >> 4, cg = tid & 15;
    int r0 = rg * 2, c16 = cg * 16;
    float p0 = 0.f, p1 = 0.f;
#pragma unroll
    for (int q = 0; q < 4; ++q) {
      float4 mv = *(const float4*)(M4 + c16 + q*4);
      p0 = fmaf(B[r0][c16+q*4+0], mv.x, p0); p0 = fmaf(B[r0][c16+q*4+1], mv.y, p0);
      p0 = fmaf(B[r0][c16+q*4+2], mv.z, p0); p0 = fmaf(B[r0][c16+q*4+3], mv.w, p0);
      p1 = fmaf(B[r0+1][c16+q*4+0], mv.x, p1); p1 = fmaf(B[r0+1][c16+q*4+1], mv.y, p1);
      p1 = fmaf(B[r0+1][c16+q*4+2], mv.z, p1); p1 = fmaf(B[r0+1][c16+q*4+3], mv.w, p1);
    }
#pragma unroll
    for (int m = 1; m < 16; m <<= 1) {
      p0 += __shfl_xor(p0, m);
      p1 += __shfl_xor(p1, m);
    }
    if (cg == 0) {
      float z0 = p0 + c4[0];
      float z1 = p1 + c4[0];
      out[base + r0]     = 1.f / (1.f + expf(-z0));
      out[base + r0 + 1] = 1.f / (1.f + expf(-z1));
    }
  }
}

// ---------- launcher ----------
extern "C" void kernel_launch(void* const* d_in, const int* in_sizes, int n_in,
                              void* d_out, int out_size, void* d_ws, size_t ws_size,
                              hipStream_t stream)
{
  const float* x    = (const float*)d_in[0];
  const float* lines= (const float*)d_in[1];
  const float* Wm1  = (const float*)d_in[2];
  const float* bm1  = (const float*)d_in[3];
  const float* Wm2  = (const float*)d_in[4];
  const float* bm2  = (const float*)d_in[5];
  const float* We1  = (const float*)d_in[6];
  const float* be1  = (const float*)d_in[7];
  const float* We2  = (const float*)d_in[8];
  const float* be2  = (const float*)d_in[9];
  const float* We3  = (const float*)d_in[10];
  const float* be3  = (const float*)d_in[11];
  const float* ln_g = (const float*)d_in[12];
  const float* ln_b = (const float*)d_in[13];
  const float* Wq   = (const float*)d_in[14];
  const float* Wk   = (const float*)d_in[15];
  const float* Wv   = (const float*)d_in[16];
  const float* A1   = (const float*)d_in[17];
  const float* a1   = (const float*)d_in[18];
  const float* A2   = (const float*)d_in[19];
  const float* a2   = (const float*)d_in[20];
  const float* alng = (const float*)d_in[21];
  const float* alnb = (const float*)d_in[22];
  const float* mem_k= (const float*)d_in[23];
  const float* mem_v= (const float*)d_in[24];
  const float* M1   = (const float*)d_in[25];
  const float* c1   = (const float*)d_in[26];
  const float* M2   = (const float*)d_in[27];
  const float* c2   = (const float*)d_in[28];
  const float* M3   = (const float*)d_in[29];
  const float* c3   = (const float*)d_in[30];
  const float* M4   = (const float*)d_in[31];
  const float* c4   = (const float*)d_in[32];
  float* out = (float*)d_out;

  char* wp = (char*)d_ws;
  auto alloc = [&](size_t bytes) -> void* {
    void* p = (void*)wp;
    wp += (bytes + 255) & ~(size_t)255;
    return p;
  };
  float* pf     = (float*)alloc((size_t)NPTS*64*4);
  float* pe     = (float*)alloc((size_t)NPTS*64*4);
  u16*   Khf    = (u16*)alloc((size_t)NE*128*4*512*2);   // bf16-hi MFMA A-fragments
  u16*   Klf    = (u16*)alloc((size_t)NE*128*4*512*2);   // bf16-lo
  u16*   A1h    = (u16*)alloc((size_t)NE*24*512*2);      // adapter L1 B-frags hi
  u16*   A1l    = (u16*)alloc((size_t)NE*24*512*2);      // lo
  u16*   A2h    = (u16*)alloc((size_t)NE*16*512*2);      // adapter L2 B-frags hi
  u16*   A2l    = (u16*)alloc((size_t)NE*16*512*2);      // lo
  float* Vhat   = (float*)alloc((size_t)NE*NM*DD*4);
  float* featsC = (float*)alloc((size_t)NE*NPTS*DD*4);
  float* QoutC  = (float*)alloc((size_t)NE*NPTS*DD*4);  // QC then reused as outC
  float* attnWb = (float*)alloc((size_t)NE*NPTS*NTK*4);
  float* slotW  = (float*)alloc((size_t)NE*NPTS*4);
  int*   attnIb = (int*)alloc((size_t)NE*NPTS*NTK*4);
  int*   plist  = (int*)alloc((size_t)NE*NPTS*4);
  int*   pairE  = (int*)alloc((size_t)NPTS*2*4);
  int*   pairS  = (int*)alloc((size_t)NPTS*2*4);
  int*   cnt    = (int*)alloc(64);

  hipMemsetAsync(cnt, 0, 64, stream);
  k_preproc<<<NPTS/256, 256, 0, stream>>>(x, lines, Wm1, bm1, Wm2, bm2,
                                          pf, pe, slotW, plist, pairE, pairS, cnt);
  k_kv<<<dim3(NM/32, NE, 2), 256, 0, stream>>>(mem_k, mem_v, Wk, Wv, Khf, Klf, Vhat);
  k_pack<<<NE, 256, 0, stream>>>(A1, A2, A1h, A1l, A2h, A2l);
  k_expert<<<dim3(NPTS/32, NE), 256, 0, stream>>>(pe, We1, be1, We2, be2, We3, be3,
                                                  ln_g, ln_b, Wq, plist, cnt, featsC, QoutC);
  k_scores<<<dim3(NPTS/16, NE), 256, 0, stream>>>(QoutC, Khf, Klf, cnt, attnWb, attnIb);
  k_adapter<<<dim3(NPTS/4, NE), 256, 0, stream>>>(Vhat, pf, A1h, A1l, A2h, A2l,
                                                  a1, a2, alng, alnb,
                                                  attnWb, attnIb, featsC, slotW, plist, cnt,
                                                  QoutC);
  k_final<<<NPTS/FR, 256, 0, stream>>>(QoutC, pairE, pairS, M1, c1, M2, c2, M3, c3, M4, c4, out);
}

// Round 9
// 1353.347 us; speedup vs baseline: 7.9852x; 1.1580x over previous
//
#include <hip/hip_runtime.h>
#include <hip/hip_bf16.h>
#include <math.h>

#define NPTS 16384
#define NE 4
#define NM 2048
#define DD 128    // D3
#define DP 64     // D1
#define NHE 256
#define NHM 256
#define NRES 64
#define NTK 16
#define NEG_INF -3.402823466e38f

typedef unsigned short u16;
typedef __attribute__((ext_vector_type(8))) short short8;
typedef __attribute__((ext_vector_type(4))) float f32x4;

// ---------- helpers ----------
__device__ __forceinline__ bool rank_gt(float av, int ai, float bv, int bi) {
  return (av > bv) || (av == bv && ai < bi);
}

__device__ __forceinline__ u16 f2bf(float x) {   // RNE float -> bf16 bits
  union { float f; unsigned u; } v; v.f = x;
  unsigned r = v.u + 0x7fffu + ((v.u >> 16) & 1u);
  return (u16)(r >> 16);
}
__device__ __forceinline__ float bf2f(u16 b) {
  union { float f; unsigned u; } v; v.u = ((unsigned)b) << 16;
  return v.f;
}

// ---------- kernel 1: per-point preproc ----------
__global__ __launch_bounds__(256) void k_preproc(
    const float* __restrict__ x, const float* __restrict__ lines,
    const float* __restrict__ Wm1, const float* __restrict__ bm1,
    const float* __restrict__ Wm2, const float* __restrict__ bm2,
    float* __restrict__ pf, float* __restrict__ pe,
    float* __restrict__ slotW, int* __restrict__ plist,
    int* __restrict__ pairE, int* __restrict__ pairS, int* __restrict__ cnt)
{
  int n = blockIdx.x * 256 + threadIdx.x;
  if (n >= NPTS) return;
  float c0 = x[n*5+0], c1 = x[n*5+1], c2 = x[n*5+2];

  float l0 = bm2[0], l1 = bm2[1], l2 = bm2[2], l3 = bm2[3];
#pragma unroll 4
  for (int j = 0; j < 64; ++j) {
    float h = fmaf(c0, Wm1[j], fmaf(c1, Wm1[64+j], fmaf(c2, Wm1[128+j], bm1[j])));
    h = fmaxf(h, 0.f);
    l0 = fmaf(h, Wm2[j*4+0], l0);
    l1 = fmaf(h, Wm2[j*4+1], l1);
    l2 = fmaf(h, Wm2[j*4+2], l2);
    l3 = fmaf(h, Wm2[j*4+3], l3);
  }
  float lg[4] = {l0, l1, l2, l3};
  float mx = fmaxf(fmaxf(l0, l1), fmaxf(l2, l3));
  float pr[4]; float ssum = 0.f;
#pragma unroll
  for (int k = 0; k < 4; ++k) { pr[k] = expf(lg[k] - mx); ssum += pr[k]; }
#pragma unroll
  for (int k = 0; k < 4; ++k) pr[k] /= ssum;
  int i0 = 0;
#pragma unroll
  for (int k = 1; k < 4; ++k) if (pr[k] > pr[i0]) i0 = k;
  int i1 = (i0 == 0) ? 1 : 0;
#pragma unroll
  for (int k = 0; k < 4; ++k) if (k != i0 && pr[k] > pr[i1]) i1 = k;
  float g0 = pr[i0], g1 = pr[i1], gs = g0 + g1;
  g0 /= gs; g1 /= gs;
  int s0 = atomicAdd(&cnt[i0], 1);
  int s1 = atomicAdd(&cnt[i1], 1);
  plist[i0*NPTS + s0] = n; slotW[i0*NPTS + s0] = g0;
  plist[i1*NPTS + s1] = n; slotW[i1*NPTS + s1] = g1;
  pairE[n*2+0] = i0; pairE[n*2+1] = i1;
  pairS[n*2+0] = s0; pairS[n*2+1] = s1;

  pe[(size_t)n*64 + 0] = c0;
  pe[(size_t)n*64 + 1] = c1;
  pe[(size_t)n*64 + 2] = c2;
  float cc[3] = {c0, c1, c2};
#pragma unroll
  for (int i = 0; i < 10; ++i) {
    float sc = 3.14159274101257324f * (float)(1 << i);
#pragma unroll
    for (int j = 0; j < 3; ++j) {
      float a = sc * cc[j];
      pe[(size_t)n*64 + 3 + (i*3+j)*2 + 0] = sinf(a);
      pe[(size_t)n*64 + 3 + (i*3+j)*2 + 1] = cosf(a);
    }
  }
  pe[(size_t)n*64 + 63] = 0.f;

  float pfv[64];
#pragma unroll
  for (int d = 0; d < 64; ++d) pfv[d] = 1.f;
  for (int i = 0; i < 2; ++i) {
    float p = x[n*5 + 3 + i] * 63.0f;
    float f = floorf(p);
    float wfr = p - f;
    int j0 = (int)f;
    int j1 = (int)fminf(f + 1.0f, 63.0f);
    const float* L = lines + (size_t)i * 64 * 64;
#pragma unroll
    for (int d = 0; d < 64; ++d) {
      float a = L[d*64 + j0];
      float b = L[d*64 + j1];
      pfv[d] *= a + wfr * (b - a);
    }
  }
#pragma unroll
  for (int d = 0; d < 64; ++d) pf[(size_t)n*64 + d] = pfv[d];
}

// ---------- kernel 2: K/V projection ----------
// K written as bf16-hi MFMA A-fragments only (R8: lo-term dropped — score error
// ~1.4e-3 vs rank-16 boundary gap ~0.035; swaps benign). V stays fp32 row-major.
__global__ __launch_bounds__(256) void k_kv(
    const float* __restrict__ mem_k, const float* __restrict__ mem_v,
    const float* __restrict__ Wk, const float* __restrict__ Wv,
    u16* __restrict__ Khf, float* __restrict__ Vhat)
{
  int e = blockIdx.y;
  int which = blockIdx.z;
  const float* src = which ? mem_v : mem_k;
  const float* W   = which ? Wv : Wk;
  int r0 = blockIdx.x * 32;
  __shared__ float sm[32][130];
  int tid = threadIdx.x;
  for (int idx = tid; idx < 32*32; idx += 256) {
    int r = idx >> 5, c4 = (idx & 31) * 4;
    float4 v = *(const float4*)(src + ((size_t)e*NM + r0 + r)*DD + c4);
    sm[r][c4+0] = v.x; sm[r][c4+1] = v.y; sm[r][c4+2] = v.z; sm[r][c4+3] = v.w;
  }
  __syncthreads();
  int r = tid >> 3, cb = (tid & 7) * 16;
  float acc[16];
#pragma unroll
  for (int i = 0; i < 16; ++i) acc[i] = 0.f;
  const float* We = W + (size_t)e*DD*DD;
#pragma unroll 4
  for (int k = 0; k < 128; ++k) {
    float s = sm[r][k];
    const float4* w4 = (const float4*)(We + (size_t)k*DD + cb);
#pragma unroll
    for (int q = 0; q < 4; ++q) {
      float4 wv = w4[q];
      acc[q*4+0] = fmaf(s, wv.x, acc[q*4+0]);
      acc[q*4+1] = fmaf(s, wv.y, acc[q*4+1]);
      acc[q*4+2] = fmaf(s, wv.z, acc[q*4+2]);
      acc[q*4+3] = fmaf(s, wv.w, acc[q*4+3]);
    }
  }
  if (which) {
    float* drow = Vhat + ((size_t)e*NM + r0 + r)*DD + cb;
#pragma unroll
    for (int i = 0; i < 16; ++i) drow[i] = acc[i];
  } else {
    int key = r0 + r;
    int T = key >> 4;
    int kr = key & 15;
#pragma unroll
    for (int b = 0; b < 2; ++b) {
      int k_off = cb + b*8;
      int kt = k_off >> 5;
      int lhi = (k_off >> 3) & 3;
      int lane_ = lhi*16 + kr;
      size_t dst = (((size_t)e*128 + T)*4 + kt)*512 + (size_t)lane_*8;
      unsigned ph[4];
#pragma unroll
      for (int p = 0; p < 4; ++p) {
        u16 h0 = f2bf(acc[b*8 + p*2 + 0]);
        u16 h1 = f2bf(acc[b*8 + p*2 + 1]);
        ph[p] = (unsigned)h0 | ((unsigned)h1 << 16);
      }
      *(uint4*)(Khf + dst) = make_uint4(ph[0], ph[1], ph[2], ph[3]);
    }
  }
}

// ---------- kernel 2b: pack ALL weight matrices into bf16 hi/lo B-fragments ----------
// Generic B-frag layout (HW-verified): lane = khalf*16 + col,
// 8 contiguous k: B[ks*32 + khalf*8 + j][ct*16 + col]; k >= Krows padded 0.
// Frag ids per expert: We1 0..31 (2ks x 16ct, K=63 padded to 64), We2 0..127,
// We3 0..63, Wq 0..31, A1 0..23, A2 0..15. grid (296, NE), block 64.
__global__ __launch_bounds__(64) void k_pack(
    const float* __restrict__ We1, const float* __restrict__ We2,
    const float* __restrict__ We3, const float* __restrict__ Wq,
    const float* __restrict__ A1, const float* __restrict__ A2,
    u16* __restrict__ We1h, u16* __restrict__ We1l,
    u16* __restrict__ We2h, u16* __restrict__ We2l,
    u16* __restrict__ We3h, u16* __restrict__ We3l,
    u16* __restrict__ Wqh,  u16* __restrict__ Wql,
    u16* __restrict__ A1h,  u16* __restrict__ A1l,
    u16* __restrict__ A2h,  u16* __restrict__ A2l)
{
  int e = blockIdx.y;
  int f = blockIdx.x;
  int lane = threadIdx.x;
  int col = lane & 15, khalf = lane >> 4;
  const float* src; u16 *dh, *dl;
  int Krows, N, ks, ct;
  if (f < 32) {
    int fl = f;        src = We1 + (size_t)e*63*256;  Krows = 63;  N = 256;
    ks = fl >> 4; ct = fl & 15;
    dh = We1h + ((size_t)e*32  + fl)*512; dl = We1l + ((size_t)e*32  + fl)*512;
  } else if (f < 160) {
    int fl = f - 32;   src = We2 + (size_t)e*256*256; Krows = 256; N = 256;
    ks = fl >> 4; ct = fl & 15;
    dh = We2h + ((size_t)e*128 + fl)*512; dl = We2l + ((size_t)e*128 + fl)*512;
  } else if (f < 224) {
    int fl = f - 160;  src = We3 + (size_t)e*256*128; Krows = 256; N = 128;
    ks = fl >> 3; ct = fl & 7;
    dh = We3h + ((size_t)e*64  + fl)*512; dl = We3l + ((size_t)e*64  + fl)*512;
  } else if (f < 256) {
    int fl = f - 224;  src = Wq  + (size_t)e*128*128; Krows = 128; N = 128;
    ks = fl >> 3; ct = fl & 7;
    dh = Wqh  + ((size_t)e*32  + fl)*512; dl = Wql  + ((size_t)e*32  + fl)*512;
  } else if (f < 280) {
    int fl = f - 256;  src = A1  + (size_t)e*192*64;  Krows = 192; N = 64;
    ks = fl >> 2; ct = fl & 3;
    dh = A1h  + ((size_t)e*24  + fl)*512; dl = A1l  + ((size_t)e*24  + fl)*512;
  } else {
    int fl = f - 280;  src = A2  + (size_t)e*64*128;  Krows = 64;  N = 128;
    ks = fl >> 3; ct = fl & 7;
    dh = A2h  + ((size_t)e*16  + fl)*512; dl = A2l  + ((size_t)e*16  + fl)*512;
  }
  unsigned ph[4], pl[4];
#pragma unroll
  for (int p = 0; p < 4; ++p) {
    int k0 = ks*32 + khalf*8 + 2*p;
    float x0 = (k0   < Krows) ? src[(size_t)k0*N     + ct*16 + col] : 0.f;
    float x1 = (k0+1 < Krows) ? src[(size_t)(k0+1)*N + ct*16 + col] : 0.f;
    u16 h0 = f2bf(x0), h1 = f2bf(x1);
    u16 l0 = f2bf(x0 - bf2f(h0)), l1 = f2bf(x1 - bf2f(h1));
    ph[p] = (unsigned)h0 | ((unsigned)h1 << 16);
    pl[p] = (unsigned)l0 | ((unsigned)l1 << 16);
  }
  *(uint4*)(dh + lane*8) = make_uint4(ph[0], ph[1], ph[2], ph[3]);
  *(uint4*)(dl + lane*8) = make_uint4(pl[0], pl[1], pl[2], pl[3]);
}

// ---------- kernel 3: MFMA expert SIREN MLP + LN + Q-proj ----------
// 32 slots/block, 4 waves; single 32 KB A-layout fp32 activation buffer.
// Per layer: read A-frags (lane-contiguous, conflict-free), 3-term hi/lo MFMA
// with global pre-packed B-frags, barrier, scatter C->A-layout write, barrier.
// R8 post-mortem: VALU version had 8-way Wt conflicts (7.9e7) + 96 staged
// rounds at 2 blocks/CU; this: 384 MFMA/wave, 8 barriers, 33.5 KB LDS.
__global__ __launch_bounds__(256) void k_expert(
    const float* __restrict__ pe,
    const u16* __restrict__ We1h, const u16* __restrict__ We1l,
    const u16* __restrict__ We2h, const u16* __restrict__ We2l,
    const u16* __restrict__ We3h, const u16* __restrict__ We3l,
    const u16* __restrict__ Wqh,  const u16* __restrict__ Wql,
    const float* __restrict__ be1, const float* __restrict__ be2,
    const float* __restrict__ be3,
    const float* __restrict__ ln_g, const float* __restrict__ ln_b,
    const int* __restrict__ plist, const int* __restrict__ cnt,
    float* __restrict__ featsC, float* __restrict__ QC)
{
  int e = blockIdx.y;
  int count = cnt[e];
  int base = blockIdx.x * 32;
  if (base >= count) return;
  __shared__ float actA[16*512];   // [(Mt*8+ks)][lane][8]  32 KB
  __shared__ float lnS[256];
  __shared__ int pts[32];
  int tid = threadIdx.x;
  int w = tid >> 6, lane = tid & 63;
  int rloc = lane & 15, khalf = lane >> 4;

  if (tid < 32) {
    int slot = base + tid;
    pts[tid] = (slot < count) ? plist[e*NPTS + slot] : 0;
  } else if (tid >= 64 && tid < 192) {
    int i = tid - 64;
    lnS[i] = ln_g[i];
    lnS[128 + i] = ln_b[i];
  }
  __syncthreads();
  // stage pe rows into A-layout: thread t -> (Mt=t>>7, ks=(t>>6)&1, lane)
  {
    int Mt = tid >> 7, ks = (tid >> 6) & 1;
    const float* src = pe + (size_t)pts[Mt*16 + rloc]*64 + ks*32 + khalf*8;
    float4 a = *(const float4*)src;
    float4 b = *(const float4*)(src + 4);
    float* d = &actA[(Mt*8 + ks)*512 + lane*8];
    *(float4*)d = a; *(float4*)(d + 4) = b;
  }
  __syncthreads();

#define CONV_FRAG(PTR, AH, AL) {                                        \
    const float* p_ = (PTR);                                            \
    float4 u0_ = *(const float4*)p_, u1_ = *(const float4*)(p_+4);      \
    float xv_[8] = {u0_.x,u0_.y,u0_.z,u0_.w,u1_.x,u1_.y,u1_.z,u1_.w};   \
    union { unsigned u[4]; short8 s; } H_, L_;                          \
    _Pragma("unroll")                                                   \
    for (int q_ = 0; q_ < 4; ++q_) {                                    \
      u16 h0_ = f2bf(xv_[2*q_]), h1_ = f2bf(xv_[2*q_+1]);               \
      u16 l0_ = f2bf(xv_[2*q_] - bf2f(h0_));                            \
      u16 l1_ = f2bf(xv_[2*q_+1] - bf2f(h1_));                          \
      H_.u[q_] = (unsigned)h0_ | ((unsigned)h1_ << 16);                 \
      L_.u[q_] = (unsigned)l0_ | ((unsigned)l1_ << 16);                 \
    }                                                                   \
    AH = H_.s; AL = L_.s; }

  // ---- L1: K=64 (2 ks), N=256, sin(30x) ----
  {
    f32x4 acc[2][4];
#pragma unroll
    for (int Mt = 0; Mt < 2; ++Mt)
#pragma unroll
      for (int c = 0; c < 4; ++c) acc[Mt][c] = (f32x4){0.f,0.f,0.f,0.f};
    for (int ks = 0; ks < 2; ++ks) {
      short8 ah[2], al[2];
#pragma unroll
      for (int Mt = 0; Mt < 2; ++Mt)
        CONV_FRAG(&actA[(Mt*8+ks)*512 + lane*8], ah[Mt], al[Mt]);
#pragma unroll
      for (int c = 0; c < 4; ++c) {
        size_t fo = ((size_t)e*32 + ks*16 + w*4 + c)*512 + (size_t)lane*8;
        short8 bh = *(const short8*)(We1h + fo);
        short8 bl = *(const short8*)(We1l + fo);
#pragma unroll
        for (int Mt = 0; Mt < 2; ++Mt) {
          acc[Mt][c] = __builtin_amdgcn_mfma_f32_16x16x32_bf16(ah[Mt], bh, acc[Mt][c], 0,0,0);
          acc[Mt][c] = __builtin_amdgcn_mfma_f32_16x16x32_bf16(ah[Mt], bl, acc[Mt][c], 0,0,0);
          acc[Mt][c] = __builtin_amdgcn_mfma_f32_16x16x32_bf16(al[Mt], bh, acc[Mt][c], 0,0,0);
        }
      }
    }
    __syncthreads();   // all reads of actA done
#pragma unroll
    for (int Mt = 0; Mt < 2; ++Mt)
#pragma unroll
      for (int c = 0; c < 4; ++c) {
        int n = (w*4+c)*16 + rloc;
        float b = be1[e*NHE + n];
        int ksp = n >> 5, lp = ((n>>3)&3)*16, jp = n & 7;
#pragma unroll
        for (int i = 0; i < 4; ++i)
          actA[(Mt*8+ksp)*512 + (lp + khalf*4 + i)*8 + jp] = sinf(30.f*(acc[Mt][c][i] + b));
      }
    __syncthreads();
  }

  // ---- L2: K=256 (8 ks), N=256, sin(30x) ----
  {
    f32x4 acc[2][4];
#pragma unroll
    for (int Mt = 0; Mt < 2; ++Mt)
#pragma unroll
      for (int c = 0; c < 4; ++c) acc[Mt][c] = (f32x4){0.f,0.f,0.f,0.f};
#pragma unroll 2
    for (int ks = 0; ks < 8; ++ks) {
      short8 ah[2], al[2];
#pragma unroll
      for (int Mt = 0; Mt < 2; ++Mt)
        CONV_FRAG(&actA[(Mt*8+ks)*512 + lane*8], ah[Mt], al[Mt]);
#pragma unroll
      for (int c = 0; c < 4; ++c) {
        size_t fo = ((size_t)e*128 + ks*16 + w*4 + c)*512 + (size_t)lane*8;
        short8 bh = *(const short8*)(We2h + fo);
        short8 bl = *(const short8*)(We2l + fo);
#pragma unroll
        for (int Mt = 0; Mt < 2; ++Mt) {
          acc[Mt][c] = __builtin_amdgcn_mfma_f32_16x16x32_bf16(ah[Mt], bh, acc[Mt][c], 0,0,0);
          acc[Mt][c] = __builtin_amdgcn_mfma_f32_16x16x32_bf16(ah[Mt], bl, acc[Mt][c], 0,0,0);
          acc[Mt][c] = __builtin_amdgcn_mfma_f32_16x16x32_bf16(al[Mt], bh, acc[Mt][c], 0,0,0);
        }
      }
    }
    __syncthreads();
#pragma unroll
    for (int Mt = 0; Mt < 2; ++Mt)
#pragma unroll
      for (int c = 0; c < 4; ++c) {
        int n = (w*4+c)*16 + rloc;
        float b = be2[e*NHE + n];
        int ksp = n >> 5, lp = ((n>>3)&3)*16, jp = n & 7;
#pragma unroll
        for (int i = 0; i < 4; ++i)
          actA[(Mt*8+ksp)*512 + (lp + khalf*4 + i)*8 + jp] = sinf(30.f*(acc[Mt][c][i] + b));
      }
    __syncthreads();
  }

  // ---- L3: K=256 (8 ks), N=128, linear -> feats ----
  {
    f32x4 acc[2][2];
#pragma unroll
    for (int Mt = 0; Mt < 2; ++Mt)
#pragma unroll
      for (int c = 0; c < 2; ++c) acc[Mt][c] = (f32x4){0.f,0.f,0.f,0.f};
#pragma unroll 2
    for (int ks = 0; ks < 8; ++ks) {
      short8 ah[2], al[2];
#pragma unroll
      for (int Mt = 0; Mt < 2; ++Mt)
        CONV_FRAG(&actA[(Mt*8+ks)*512 + lane*8], ah[Mt], al[Mt]);
#pragma unroll
      for (int c = 0; c < 2; ++c) {
        size_t fo = ((size_t)e*64 + ks*8 + w*2 + c)*512 + (size_t)lane*8;
        short8 bh = *(const short8*)(We3h + fo);
        short8 bl = *(const short8*)(We3l + fo);
#pragma unroll
        for (int Mt = 0; Mt < 2; ++Mt) {
          acc[Mt][c] = __builtin_amdgcn_mfma_f32_16x16x32_bf16(ah[Mt], bh, acc[Mt][c], 0,0,0);
          acc[Mt][c] = __builtin_amdgcn_mfma_f32_16x16x32_bf16(ah[Mt], bl, acc[Mt][c], 0,0,0);
          acc[Mt][c] = __builtin_amdgcn_mfma_f32_16x16x32_bf16(al[Mt], bh, acc[Mt][c], 0,0,0);
        }
      }
    }
    __syncthreads();
#pragma unroll
    for (int Mt = 0; Mt < 2; ++Mt)
#pragma unroll
      for (int c = 0; c < 2; ++c) {
        int n = (w*2+c)*16 + rloc;
        float b = be3[e*DD + n];
        int ksp = n >> 5, lp = ((n>>3)&3)*16, jp = n & 7;
#pragma unroll
        for (int i = 0; i < 4; ++i) {
          float f = acc[Mt][c][i] + b;
          actA[(Mt*8+ksp)*512 + (lp + khalf*4 + i)*8 + jp] = f;
          int slot = base + Mt*16 + khalf*4 + i;
          if (slot < count)
            featsC[((size_t)e*NPTS + slot)*DD + n] = f;
        }
      }
    __syncthreads();
  }

  // ---- LN (stats from A-layout via shfl over khalf) + Wq: K=128 (4 ks), N=128 ----
  {
    float mu[2], rsv[2];
#pragma unroll
    for (int Mt = 0; Mt < 2; ++Mt) {
      float sm = 0.f, sq = 0.f;
#pragma unroll
      for (int ks = 0; ks < 4; ++ks) {
        const float* p = &actA[(Mt*8+ks)*512 + lane*8];
        float4 u0 = *(const float4*)p, u1 = *(const float4*)(p+4);
        sm += u0.x+u0.y+u0.z+u0.w + u1.x+u1.y+u1.z+u1.w;
        sq += u0.x*u0.x+u0.y*u0.y+u0.z*u0.z+u0.w*u0.w
            + u1.x*u1.x+u1.y*u1.y+u1.z*u1.z+u1.w*u1.w;
      }
      sm += __shfl_xor(sm, 16); sq += __shfl_xor(sq, 16);
      sm += __shfl_xor(sm, 32); sq += __shfl_xor(sq, 32);
      mu[Mt] = sm * (1.f/128.f);
      rsv[Mt] = rsqrtf(sq * (1.f/128.f) - mu[Mt]*mu[Mt] + 1e-5f);
    }
    f32x4 acc[2][2];
#pragma unroll
    for (int Mt = 0; Mt < 2; ++Mt)
#pragma unroll
      for (int c = 0; c < 2; ++c) acc[Mt][c] = (f32x4){0.f,0.f,0.f,0.f};
    for (int ks = 0; ks < 4; ++ks) {
      short8 ah[2], al[2];
#pragma unroll
      for (int Mt = 0; Mt < 2; ++Mt) {
        const float* p = &actA[(Mt*8+ks)*512 + lane*8];
        float4 u0 = *(const float4*)p, u1 = *(const float4*)(p+4);
        float xv[8] = {u0.x,u0.y,u0.z,u0.w,u1.x,u1.y,u1.z,u1.w};
        union { unsigned u[4]; short8 s; } H, L;
#pragma unroll
        for (int j = 0; j < 8; ++j) {
          int k = ks*32 + khalf*8 + j;
          xv[j] = (xv[j] - mu[Mt]) * rsv[Mt] * lnS[k] + lnS[128 + k];
        }
#pragma unroll
        for (int q = 0; q < 4; ++q) {
          u16 h0 = f2bf(xv[2*q]), h1 = f2bf(xv[2*q+1]);
          u16 l0 = f2bf(xv[2*q] - bf2f(h0)), l1 = f2bf(xv[2*q+1] - bf2f(h1));
          H.u[q] = (unsigned)h0 | ((unsigned)h1 << 16);
          L.u[q] = (unsigned)l0 | ((unsigned)l1 << 16);
        }
        ah[Mt] = H.s; al[Mt] = L.s;
      }
#pragma unroll
      for (int c = 0; c < 2; ++c) {
        size_t fo = ((size_t)e*32 + ks*8 + w*2 + c)*512 + (size_t)lane*8;
        short8 bh = *(const short8*)(Wqh + fo);
        short8 bl = *(const short8*)(Wql + fo);
#pragma unroll
        for (int Mt = 0; Mt < 2; ++Mt) {
          acc[Mt][c] = __builtin_amdgcn_mfma_f32_16x16x32_bf16(ah[Mt], bh, acc[Mt][c], 0,0,0);
          acc[Mt][c] = __builtin_amdgcn_mfma_f32_16x16x32_bf16(ah[Mt], bl, acc[Mt][c], 0,0,0);
          acc[Mt][c] = __builtin_amdgcn_mfma_f32_16x16x32_bf16(al[Mt], bh, acc[Mt][c], 0,0,0);
        }
      }
    }
#pragma unroll
    for (int Mt = 0; Mt < 2; ++Mt)
#pragma unroll
      for (int c = 0; c < 2; ++c) {
        int n = (w*2+c)*16 + rloc;
#pragma unroll
        for (int i = 0; i < 4; ++i) {
          int slot = base + Mt*16 + khalf*4 + i;
          if (slot < count)
            QC[((size_t)e*NPTS + slot)*DD + n] = acc[Mt][c][i];
        }
      }
  }
#undef CONV_FRAG
}

// ---------- kernel 4: MFMA scores (Kh-only, 32 slots/block) + top-16 + softmax ----------
// 2-term: Kh·Qh + Kh·Ql (K-lo dropped, R8 analysis). 32 slots amortize K staging
// 2x; wave w = key-tile w x 2 slot-tiles (16 MFMA/chunk). Proven ballot top-16
// machinery duplicated over 2 list-register sets (8 slots/wave).
__global__ __launch_bounds__(256) void k_scores(
    const float* __restrict__ QC, const u16* __restrict__ Khf,
    const int* __restrict__ cnt,
    float* __restrict__ attnW, int* __restrict__ attnI)
{
  int e = blockIdx.y;
  int count = cnt[e];
  int sbase = blockIdx.x * 32;
  if (sbase >= count) return;
  __shared__ u16 KhS[16*512];    // 16 KB
  __shared__ u16 QhS[8*512];     // 8 KB
  __shared__ u16 QlS[8*512];     // 8 KB
  __shared__ float Ssc[64][33];  // 8.4 KB, odd pad: column reads 2-way (free)
  int tid = threadIdx.x;
  int w = tid >> 6, lane = tid & 63;

  // Q B-frags: 8 frag-sets (st*4 + kt); each wave builds 2
#pragma unroll
  for (int it = 0; it < 2; ++it) {
    int frag = it*4 + w;
    int st = frag >> 2, kt = frag & 3;
    int srow = lane & 15, khalf = lane >> 4;
    int slot = sbase + st*16 + srow;
    float q[8];
    if (slot < count) {
      const float* Qr = QC + ((size_t)e*NPTS + slot)*DD + kt*32 + khalf*8;
#pragma unroll
      for (int i = 0; i < 8; ++i) q[i] = Qr[i];
    } else {
#pragma unroll
      for (int i = 0; i < 8; ++i) q[i] = 0.f;
    }
    int dst = frag*512 + lane*8;
#pragma unroll
    for (int i = 0; i < 8; ++i) {
      u16 h = f2bf(q[i]);
      QhS[dst + i] = h;
      QlS[dst + i] = f2bf(q[i] - bf2f(h));
    }
  }

  float lv0 = NEG_INF, lv1 = NEG_INF;
  int   li0 = 0x7fffffff, li1 = 0x7fffffff;
  const u16* KhB = Khf + (size_t)e*128*4*512;

  for (int ch = 0; ch < NM/64; ++ch) {
    __syncthreads();
    {
      const uint4* srcH = (const uint4*)(KhB + (size_t)ch*8192);
      uint4* dH = (uint4*)KhS;
#pragma unroll
      for (int i = 0; i < 4; ++i) dH[tid + i*256] = srcH[tid + i*256];
    }
    __syncthreads();

#pragma unroll
    for (int st = 0; st < 2; ++st) {
      f32x4 acc = {0.f, 0.f, 0.f, 0.f};
#pragma unroll
      for (int kt = 0; kt < 4; ++kt) {
        short8 ah = *(const short8*)&KhS[(w*4+kt)*512 + lane*8];
        short8 bh = *(const short8*)&QhS[(st*4+kt)*512 + lane*8];
        short8 bl = *(const short8*)&QlS[(st*4+kt)*512 + lane*8];
        acc = __builtin_amdgcn_mfma_f32_16x16x32_bf16(ah, bh, acc, 0, 0, 0);
        acc = __builtin_amdgcn_mfma_f32_16x16x32_bf16(ah, bl, acc, 0, 0, 0);
      }
      int col = lane & 15, rbase = (lane >> 4) * 4;
#pragma unroll
      for (int i = 0; i < 4; ++i)
        Ssc[w*16 + rbase + i][st*16 + col] = acc[i];
    }
    __syncthreads();

    {
      int keyb = ch*64;
      auto ins = [&](float& lv, int& li, int sl0) {
#pragma unroll
        for (int j = 0; j < 4; ++j) {
          int slot = sbase + sl0 + j;
          if (slot >= count) continue;   // wave-uniform
          float v = Ssc[lane][sl0 + j];
          int key = keyb + lane;
          float Tv = __shfl(lv, j*16 + 15);
          int   Ti = __shfl(li, j*16 + 15);
          unsigned long long mb = __ballot(rank_gt(v, key, Tv, Ti));
          while (mb) {
            int b = __ffsll((unsigned long long)mb) - 1;
            mb &= mb - 1;
            float cv = __shfl(v, b);
            int   ck = keyb + b;
            Tv = __shfl(lv, j*16 + 15);
            Ti = __shfl(li, j*16 + 15);
            if (!rank_gt(cv, ck, Tv, Ti)) continue;
            float pv = __shfl_up(lv, 1);
            int   pi = __shfl_up(li, 1);
            int p = lane & 15;
            bool abv_me   = rank_gt(lv, li, cv, ck);
            bool abv_prev = (p == 0) || rank_gt(pv, pi, cv, ck);
            float nv = abv_me ? lv : (abv_prev ? cv : pv);
            int   ni = abv_me ? li : (abv_prev ? ck : pi);
            if ((lane >> 4) == j) { lv = nv; li = ni; }
          }
        }
      };
      ins(lv0, li0, w*8);
      ins(lv1, li1, w*8 + 4);
    }
  }

  const float inv_scale = 0.08838834764831845f;  // 1/sqrt(128)
  auto fin = [&](float lv, int li, int sl0) {
#pragma unroll
    for (int j = 0; j < 4; ++j) {
      int slot = sbase + sl0 + j;
      if (slot >= count) continue;
      float m = __shfl(lv, j*16 + 0);
      float ev = expf((lv - m) * inv_scale);
      float s = ev;
      s += __shfl_xor(s, 1); s += __shfl_xor(s, 2);
      s += __shfl_xor(s, 4); s += __shfl_xor(s, 8);
      if ((lane >> 4) == j) {
        size_t off = ((size_t)e*NPTS + slot)*NTK + (lane & 15);
        attnW[off] = ev / s;
        attnI[off] = li;
      }
    }
  };
  fin(lv0, li0, w*8);
  fin(lv1, li1, w*8 + 4);
}

// ---------- kernel 5: MFMA adapter MLP + LN + attention combine ----------
__global__ __launch_bounds__(256) void k_adapter(
    const float* __restrict__ Vhat, const float* __restrict__ pf,
    const u16* __restrict__ A1h, const u16* __restrict__ A1l,
    const u16* __restrict__ A2h, const u16* __restrict__ A2l,
    const float* __restrict__ a1, const float* __restrict__ a2,
    const float* __restrict__ alng, const float* __restrict__ alnb,
    const float* __restrict__ attnW, const int* __restrict__ attnI,
    const float* __restrict__ featsC, const float* __restrict__ slotW,
    const int* __restrict__ plist, const int* __restrict__ cnt,
    float* __restrict__ outC)
{
  int e = blockIdx.y;
  int count = cnt[e];
  int s0 = blockIdx.x * 4;
  if (s0 >= count) return;
  __shared__ float ainV[64][132];
  __shared__ float hid[64][68];
  __shared__ float pfS[4][68];
  __shared__ float attwS[4][16];
  __shared__ float alnS[128], albS[128];
  __shared__ int   rtiS[64];
  __shared__ float wslS[4];
  __shared__ int   ptlS[4];
  int tid = threadIdx.x;
  if (tid < 64) {
    int sl = tid >> 4, key = tid & 15;
    int slot = s0 + sl;
    if (slot < count) {
      size_t o = ((size_t)e*NPTS + slot)*NTK + key;
      rtiS[tid] = attnI[o];
      attwS[sl][key] = attnW[o];
    } else { rtiS[tid] = 0; attwS[sl][key] = 0.f; }
  } else if (tid < 68) {
    int sl = tid - 64;
    int slot = s0 + sl;
    wslS[sl] = (slot < count) ? slotW[e*NPTS + slot] : 0.f;
    ptlS[sl] = (slot < count) ? plist[e*NPTS + slot] : 0;
  } else if (tid >= 128 && tid < 192) {
    int c2 = (tid - 128) * 2;
    alnS[c2]   = alng[e*DD + c2];
    alnS[c2+1] = alng[e*DD + c2+1];
    albS[c2]   = alnb[e*DD + c2];
    albS[c2+1] = alnb[e*DD + c2+1];
  }
  __syncthreads();
  for (int idx = tid; idx < 64*32; idx += 256) {
    int r = idx >> 5, c4 = (idx & 31) * 4;
    *(float4*)&ainV[r][c4] = *(const float4*)(Vhat + ((size_t)e*NM + rtiS[r])*DD + c4);
  }
  if (tid < 64) {
    int sl = tid >> 4, c4 = (tid & 15) * 4;
    *(float4*)&pfS[sl][c4] = *(const float4*)(pf + (size_t)ptlS[sl]*64 + c4);
  }
  __syncthreads();

  int w = tid >> 6, lane = tid & 63;
  int rloc = lane & 15;
  int khalf = lane >> 4;

  f32x4 acc1[4];
#pragma unroll
  for (int ct = 0; ct < 4; ++ct) acc1[ct] = (f32x4){0.f, 0.f, 0.f, 0.f};
  for (int ks = 0; ks < 6; ++ks) {
    short8 ah, al;
    {
      const float* src = (ks < 4) ? &ainV[w*16 + rloc][ks*32 + khalf*8]
                                  : &pfS[w][(ks-4)*32 + khalf*8];
      float4 u0 = *(const float4*)(src);
      float4 u1 = *(const float4*)(src + 4);
      float xv[8] = {u0.x, u0.y, u0.z, u0.w, u1.x, u1.y, u1.z, u1.w};
      union { unsigned u[4]; short8 s; } H, L;
#pragma unroll
      for (int p = 0; p < 4; ++p) {
        u16 h0 = f2bf(xv[2*p]),  h1 = f2bf(xv[2*p+1]);
        u16 l0 = f2bf(xv[2*p] - bf2f(h0)), l1 = f2bf(xv[2*p+1] - bf2f(h1));
        H.u[p] = (unsigned)h0 | ((unsigned)h1 << 16);
        L.u[p] = (unsigned)l0 | ((unsigned)l1 << 16);
      }
      ah = H.s; al = L.s;
    }
    const u16* bh0 = A1h + ((size_t)e*24 + ks*4)*512 + (size_t)lane*8;
    const u16* bl0 = A1l + ((size_t)e*24 + ks*4)*512 + (size_t)lane*8;
#pragma unroll
    for (int ct = 0; ct < 4; ++ct) {
      short8 bh = *(const short8*)(bh0 + ct*512);
      short8 bl = *(const short8*)(bl0 + ct*512);
      acc1[ct] = __builtin_amdgcn_mfma_f32_16x16x32_bf16(ah, bh, acc1[ct], 0, 0, 0);
      acc1[ct] = __builtin_amdgcn_mfma_f32_16x16x32_bf16(ah, bl, acc1[ct], 0, 0, 0);
      acc1[ct] = __builtin_amdgcn_mfma_f32_16x16x32_bf16(al, bh, acc1[ct], 0, 0, 0);
    }
  }
#pragma unroll
  for (int ct = 0; ct < 4; ++ct) {
    float b = a1[e*64 + ct*16 + rloc];
#pragma unroll
    for (int i = 0; i < 4; ++i)
      hid[w*16 + khalf*4 + i][ct*16 + rloc] = fmaxf(acc1[ct][i] + b, 0.f);
  }

  f32x4 acc2[8];
#pragma unroll
  for (int ct = 0; ct < 8; ++ct) acc2[ct] = (f32x4){0.f, 0.f, 0.f, 0.f};
  for (int ks = 0; ks < 2; ++ks) {
    short8 ah, al;
    {
      const float* src = &hid[w*16 + rloc][ks*32 + khalf*8];
      float4 u0 = *(const float4*)(src);
      float4 u1 = *(const float4*)(src + 4);
      float xv[8] = {u0.x, u0.y, u0.z, u0.w, u1.x, u1.y, u1.z, u1.w};
      union { unsigned u[4]; short8 s; } H, L;
#pragma unroll
      for (int p = 0; p < 4; ++p) {
        u16 h0 = f2bf(xv[2*p]),  h1 = f2bf(xv[2*p+1]);
        u16 l0 = f2bf(xv[2*p] - bf2f(h0)), l1 = f2bf(xv[2*p+1] - bf2f(h1));
        H.u[p] = (unsigned)h0 | ((unsigned)h1 << 16);
        L.u[p] = (unsigned)l0 | ((unsigned)l1 << 16);
      }
      ah = H.s; al = L.s;
    }
    const u16* bh0 = A2h + ((size_t)e*16 + ks*8)*512 + (size_t)lane*8;
    const u16* bl0 = A2l + ((size_t)e*16 + ks*8)*512 + (size_t)lane*8;
#pragma unroll
    for (int ct = 0; ct < 8; ++ct) {
      short8 bh = *(const short8*)(bh0 + ct*512);
      short8 bl = *(const short8*)(bl0 + ct*512);
      acc2[ct] = __builtin_amdgcn_mfma_f32_16x16x32_bf16(ah, bh, acc2[ct], 0, 0, 0);
      acc2[ct] = __builtin_amdgcn_mfma_f32_16x16x32_bf16(ah, bl, acc2[ct], 0, 0, 0);
      acc2[ct] = __builtin_amdgcn_mfma_f32_16x16x32_bf16(al, bh, acc2[ct], 0, 0, 0);
    }
  }

  float ad[8][4];
#pragma unroll
  for (int ct = 0; ct < 8; ++ct) {
    float b = a2[e*DD + ct*16 + rloc];
#pragma unroll
    for (int i = 0; i < 4; ++i) ad[ct][i] = acc2[ct][i] + b;
  }
  float mu[4], rsv[4];
#pragma unroll
  for (int i = 0; i < 4; ++i) {
    float sm = 0.f, sq = 0.f;
#pragma unroll
    for (int ct = 0; ct < 8; ++ct) { sm += ad[ct][i]; sq += ad[ct][i]*ad[ct][i]; }
    sm += __shfl_xor(sm, 1); sq += __shfl_xor(sq, 1);
    sm += __shfl_xor(sm, 2); sq += __shfl_xor(sq, 2);
    sm += __shfl_xor(sm, 4); sq += __shfl_xor(sq, 4);
    sm += __shfl_xor(sm, 8); sq += __shfl_xor(sq, 8);
    mu[i] = sm * (1.f/128.f);
    float var = sq * (1.f/128.f) - mu[i]*mu[i];
    rsv[i] = rsqrtf(var + 1e-5f);
  }
  float aw[4];
#pragma unroll
  for (int i = 0; i < 4; ++i) aw[i] = attwS[w][khalf*4 + i];

  float outv[8];
#pragma unroll
  for (int ct = 0; ct < 8; ++ct) {
    int cg = ct*16 + rloc;
    float g = alnS[cg], bb = albS[cg];
    float s = 0.f;
#pragma unroll
    for (int i = 0; i < 4; ++i) {
      float vt = ainV[w*16 + khalf*4 + i][cg];
      s += aw[i] * (vt + (ad[ct][i] - mu[i]) * rsv[i] * g + bb);
    }
    outv[ct] = s;
  }
#pragma unroll
  for (int ct = 0; ct < 8; ++ct) {
    outv[ct] += __shfl_xor(outv[ct], 16);
    outv[ct] += __shfl_xor(outv[ct], 32);
  }
  int slot = s0 + w;
  if (khalf == 0 && slot < count) {
    size_t o = ((size_t)e*NPTS + slot)*DD;
    float wg = wslS[w];
#pragma unroll
    for (int ct = 0; ct < 8; ++ct) {
      int cg = ct*16 + rloc;
      outC[o + cg] = wg * (outv[ct] + featsC[o + cg]);
    }
  }
}

// ---------- kernel 6: gather pairs + final MLP + sigmoid ----------
#define FR 32
__device__ __forceinline__ void mlp_layer_f(
    const float (*X)[260], float (*Y)[260], float (*Wt)[260],
    const float* __restrict__ W, const float* __restrict__ bias,
    int K, int tid)
{
  int rg = tid >> 4;
  int cg = tid & 15;
  int r0 = rg * 2;
  int c16 = cg * 16;
  float acc0[16], acc1[16];
#pragma unroll
  for (int i = 0; i < 16; ++i) { acc0[i] = 0.f; acc1[i] = 0.f; }
  int nkc = K >> 3;
  for (int kc = 0; kc < nkc; ++kc) {
    __syncthreads();
    for (int idx = tid; idx < 512; idx += 256) {
      int rr = idx >> 6, c4 = (idx & 63) * 4;
      *(float4*)&Wt[rr][c4] = *(const float4*)(W + (size_t)(kc*8 + rr)*NHM + c4);
    }
    __syncthreads();
#pragma unroll
    for (int kk = 0; kk < 8; ++kk) {
      float a0 = X[r0][kc*8 + kk];
      float a1 = X[r0+1][kc*8 + kk];
#pragma unroll
      for (int q = 0; q < 4; ++q) {
        float4 wv = *(const float4*)&Wt[kk][c16 + q*4];
        acc0[q*4+0] = fmaf(a0, wv.x, acc0[q*4+0]);
        acc0[q*4+1] = fmaf(a0, wv.y, acc0[q*4+1]);
        acc0[q*4+2] = fmaf(a0, wv.z, acc0[q*4+2]);
        acc0[q*4+3] = fmaf(a0, wv.w, acc0[q*4+3]);
        acc1[q*4+0] = fmaf(a1, wv.x, acc1[q*4+0]);
        acc1[q*4+1] = fmaf(a1, wv.y, acc1[q*4+1]);
        acc1[q*4+2] = fmaf(a1, wv.z, acc1[q*4+2]);
        acc1[q*4+3] = fmaf(a1, wv.w, acc1[q*4+3]);
      }
    }
  }
  float4 b0 = *(const float4*)(bias + c16);
  float4 b1 = *(const float4*)(bias + c16 + 4);
  float4 b2 = *(const float4*)(bias + c16 + 8);
  float4 b3 = *(const float4*)(bias + c16 + 12);
  float bb[16] = {b0.x,b0.y,b0.z,b0.w, b1.x,b1.y,b1.z,b1.w,
                  b2.x,b2.y,b2.z,b2.w, b3.x,b3.y,b3.z,b3.w};
  __syncthreads();
#pragma unroll
  for (int i = 0; i < 16; ++i) {
    Y[r0][c16+i]   = fmaxf(acc0[i] + bb[i], 0.f);
    Y[r0+1][c16+i] = fmaxf(acc1[i] + bb[i], 0.f);
  }
}

__global__ __launch_bounds__(256) void k_final(
    const float* __restrict__ outC, const int* __restrict__ pairE, const int* __restrict__ pairS,
    const float* __restrict__ M1, const float* __restrict__ c1,
    const float* __restrict__ M2, const float* __restrict__ c2,
    const float* __restrict__ M3, const float* __restrict__ c3,
    const float* __restrict__ M4, const float* __restrict__ c4,
    float* __restrict__ out)
{
  int base = blockIdx.x * FR;
  __shared__ float A[FR][260];
  __shared__ float B[FR][260];
  __shared__ float Wt[8][260];
  __shared__ int prE[FR*2];
  __shared__ int prS[FR*2];
  int tid = threadIdx.x;
  if (tid < FR*2) {
    prE[tid] = pairE[(size_t)base*2 + tid];
    prS[tid] = pairS[(size_t)base*2 + tid];
  }
  __syncthreads();
  for (int idx = tid; idx < FR*32; idx += 256) {
    int rr = idx >> 5, c4 = (idx & 31) * 4;
    float4 a = *(const float4*)(outC + ((size_t)prE[rr*2+0]*NPTS + prS[rr*2+0])*DD + c4);
    float4 b = *(const float4*)(outC + ((size_t)prE[rr*2+1]*NPTS + prS[rr*2+1])*DD + c4);
    A[rr][c4+0] = a.x + b.x; A[rr][c4+1] = a.y + b.y;
    A[rr][c4+2] = a.z + b.z; A[rr][c4+3] = a.w + b.w;
  }

  mlp_layer_f(A, B, Wt, M1, c1, 128, tid);
  mlp_layer_f(B, A, Wt, M2, c2, 256, tid);
  mlp_layer_f(A, B, Wt, M3, c3, 256, tid);

  __syncthreads();
  {
    int rg = tid >> 4, cg = tid & 15;
    int r0 = rg * 2, c16 = cg * 16;
    float p0 = 0.f, p1 = 0.f;
#pragma unroll
    for (int q = 0; q < 4; ++q) {
      float4 mv = *(const float4*)(M4 + c16 + q*4);
      p0 = fmaf(B[r0][c16+q*4+0], mv.x, p0); p0 = fmaf(B[r0][c16+q*4+1], mv.y, p0);
      p0 = fmaf(B[r0][c16+q*4+2], mv.z, p0); p0 = fmaf(B[r0][c16+q*4+3], mv.w, p0);
      p1 = fmaf(B[r0+1][c16+q*4+0], mv.x, p1); p1 = fmaf(B[r0+1][c16+q*4+1], mv.y, p1);
      p1 = fmaf(B[r0+1][c16+q*4+2], mv.z, p1); p1 = fmaf(B[r0+1][c16+q*4+3], mv.w, p1);
    }
#pragma unroll
    for (int m = 1; m < 16; m <<= 1) {
      p0 += __shfl_xor(p0, m);
      p1 += __shfl_xor(p1, m);
    }
    if (cg == 0) {
      float z0 = p0 + c4[0];
      float z1 = p1 + c4[0];
      out[base + r0]     = 1.f / (1.f + expf(-z0));
      out[base + r0 + 1] = 1.f / (1.f + expf(-z1));
    }
  }
}

// ---------- launcher ----------
extern "C" void kernel_launch(void* const* d_in, const int* in_sizes, int n_in,
                              void* d_out, int out_size, void* d_ws, size_t ws_size,
                              hipStream_t stream)
{
  const float* x    = (const float*)d_in[0];
  const float* lines= (const float*)d_in[1];
  const float* Wm1  = (const float*)d_in[2];
  const float* bm1  = (const float*)d_in[3];
  const float* Wm2  = (const float*)d_in[4];
  const float* bm2  = (const float*)d_in[5];
  const float* We1  = (const float*)d_in[6];
  const float* be1  = (const float*)d_in[7];
  const float* We2  = (const float*)d_in[8];
  const float* be2  = (const float*)d_in[9];
  const float* We3  = (const float*)d_in[10];
  const float* be3  = (const float*)d_in[11];
  const float* ln_g = (const float*)d_in[12];
  const float* ln_b = (const float*)d_in[13];
  const float* Wq   = (const float*)d_in[14];
  const float* Wk   = (const float*)d_in[15];
  const float* Wv   = (const float*)d_in[16];
  const float* A1   = (const float*)d_in[17];
  const float* a1   = (const float*)d_in[18];
  const float* A2   = (const float*)d_in[19];
  const float* a2   = (const float*)d_in[20];
  const float* alng = (const float*)d_in[21];
  const float* alnb = (const float*)d_in[22];
  const float* mem_k= (const float*)d_in[23];
  const float* mem_v= (const float*)d_in[24];
  const float* M1   = (const float*)d_in[25];
  const float* c1   = (const float*)d_in[26];
  const float* M2   = (const float*)d_in[27];
  const float* c2   = (const float*)d_in[28];
  const float* M3   = (const float*)d_in[29];
  const float* c3   = (const float*)d_in[30];
  const float* M4   = (const float*)d_in[31];
  const float* c4   = (const float*)d_in[32];
  float* out = (float*)d_out;

  char* wp = (char*)d_ws;
  auto alloc = [&](size_t bytes) -> void* {
    void* p = (void*)wp;
    wp += (bytes + 255) & ~(size_t)255;
    return p;
  };
  float* pf     = (float*)alloc((size_t)NPTS*64*4);
  float* pe     = (float*)alloc((size_t)NPTS*64*4);
  u16*   Khf    = (u16*)alloc((size_t)NE*128*4*512*2);   // bf16-hi K A-fragments
  u16*   We1h   = (u16*)alloc((size_t)NE*32*512*2);
  u16*   We1l   = (u16*)alloc((size_t)NE*32*512*2);
  u16*   We2h   = (u16*)alloc((size_t)NE*128*512*2);
  u16*   We2l   = (u16*)alloc((size_t)NE*128*512*2);
  u16*   We3h   = (u16*)alloc((size_t)NE*64*512*2);
  u16*   We3l   = (u16*)alloc((size_t)NE*64*512*2);
  u16*   Wqh    = (u16*)alloc((size_t)NE*32*512*2);
  u16*   Wql    = (u16*)alloc((size_t)NE*32*512*2);
  u16*   A1h    = (u16*)alloc((size_t)NE*24*512*2);
  u16*   A1l    = (u16*)alloc((size_t)NE*24*512*2);
  u16*   A2h    = (u16*)alloc((size_t)NE*16*512*2);
  u16*   A2l    = (u16*)alloc((size_t)NE*16*512*2);
  float* Vhat   = (float*)alloc((size_t)NE*NM*DD*4);
  float* featsC = (float*)alloc((size_t)NE*NPTS*DD*4);
  float* QoutC  = (float*)alloc((size_t)NE*NPTS*DD*4);  // QC then reused as outC
  float* attnWb = (float*)alloc((size_t)NE*NPTS*NTK*4);
  float* slotW  = (float*)alloc((size_t)NE*NPTS*4);
  int*   attnIb = (int*)alloc((size_t)NE*NPTS*NTK*4);
  int*   plist  = (int*)alloc((size_t)NE*NPTS*4);
  int*   pairE  = (int*)alloc((size_t)NPTS*2*4);
  int*   pairS  = (int*)alloc((size_t)NPTS*2*4);
  int*   cnt    = (int*)alloc(64);

  hipMemsetAsync(cnt, 0, 64, stream);
  k_preproc<<<NPTS/256, 256, 0, stream>>>(x, lines, Wm1, bm1, Wm2, bm2,
                                          pf, pe, slotW, plist, pairE, pairS, cnt);
  k_kv<<<dim3(NM/32, NE, 2), 256, 0, stream>>>(mem_k, mem_v, Wk, Wv, Khf, Vhat);
  k_pack<<<dim3(296, NE), 64, 0, stream>>>(We1, We2, We3, Wq, A1, A2,
                                           We1h, We1l, We2h, We2l,
                                           We3h, We3l, Wqh, Wql,
                                           A1h, A1l, A2h, A2l);
  k_expert<<<dim3(NPTS/32, NE), 256, 0, stream>>>(pe, We1h, We1l, We2h, We2l,
                                                  We3h, We3l, Wqh, Wql,
                                                  be1, be2, be3, ln_g, ln_b,
                                                  plist, cnt, featsC, QoutC);
  k_scores<<<dim3(NPTS/32, NE), 256, 0, stream>>>(QoutC, Khf, cnt, attnWb, attnIb);
  k_adapter<<<dim3(NPTS/4, NE), 256, 0, stream>>>(Vhat, pf, A1h, A1l, A2h, A2l,
                                                  a1, a2, alng, alnb,
                                                  attnWb, attnIb, featsC, slotW, plist, cnt,
                                                  QoutC);
  k_final<<<NPTS/FR, 256, 0, stream>>>(QoutC, pairE, pairS, M1, c1, M2, c2, M3, c3, M4, c4, out);
}

// Round 10
// 1161.027 us; speedup vs baseline: 9.3079x; 1.1656x over previous
//
#include <hip/hip_runtime.h>
#include <hip/hip_bf16.h>
#include <math.h>

#define NPTS 16384
#define NE 4
#define NM 2048
#define DD 128    // D3
#define DP 64     // D1
#define NHE 256
#define NHM 256
#define NRES 64
#define NTK 16
#define NEG_INF -3.402823466e38f

typedef unsigned short u16;
typedef __attribute__((ext_vector_type(8))) short short8;
typedef __attribute__((ext_vector_type(4))) float f32x4;

// ---------- helpers ----------
__device__ __forceinline__ bool rank_gt(float av, int ai, float bv, int bi) {
  return (av > bv) || (av == bv && ai < bi);
}

__device__ __forceinline__ u16 f2bf(float x) {   // RNE float -> bf16 bits
  union { float f; unsigned u; } v; v.f = x;
  unsigned r = v.u + 0x7fffu + ((v.u >> 16) & 1u);
  return (u16)(r >> 16);
}
__device__ __forceinline__ float bf2f(u16 b) {
  union { float f; unsigned u; } v; v.u = ((unsigned)b) << 16;
  return v.f;
}

// ---------- kernel 1: per-point preproc ----------
__global__ __launch_bounds__(256) void k_preproc(
    const float* __restrict__ x, const float* __restrict__ lines,
    const float* __restrict__ Wm1, const float* __restrict__ bm1,
    const float* __restrict__ Wm2, const float* __restrict__ bm2,
    float* __restrict__ pf, float* __restrict__ pe,
    float* __restrict__ slotW, int* __restrict__ plist,
    int* __restrict__ pairE, int* __restrict__ pairS, int* __restrict__ cnt)
{
  int n = blockIdx.x * 256 + threadIdx.x;
  if (n >= NPTS) return;
  float c0 = x[n*5+0], c1 = x[n*5+1], c2 = x[n*5+2];

  float l0 = bm2[0], l1 = bm2[1], l2 = bm2[2], l3 = bm2[3];
#pragma unroll 4
  for (int j = 0; j < 64; ++j) {
    float h = fmaf(c0, Wm1[j], fmaf(c1, Wm1[64+j], fmaf(c2, Wm1[128+j], bm1[j])));
    h = fmaxf(h, 0.f);
    l0 = fmaf(h, Wm2[j*4+0], l0);
    l1 = fmaf(h, Wm2[j*4+1], l1);
    l2 = fmaf(h, Wm2[j*4+2], l2);
    l3 = fmaf(h, Wm2[j*4+3], l3);
  }
  float lg[4] = {l0, l1, l2, l3};
  float mx = fmaxf(fmaxf(l0, l1), fmaxf(l2, l3));
  float pr[4]; float ssum = 0.f;
#pragma unroll
  for (int k = 0; k < 4; ++k) { pr[k] = expf(lg[k] - mx); ssum += pr[k]; }
#pragma unroll
  for (int k = 0; k < 4; ++k) pr[k] /= ssum;
  int i0 = 0;
#pragma unroll
  for (int k = 1; k < 4; ++k) if (pr[k] > pr[i0]) i0 = k;
  int i1 = (i0 == 0) ? 1 : 0;
#pragma unroll
  for (int k = 0; k < 4; ++k) if (k != i0 && pr[k] > pr[i1]) i1 = k;
  float g0 = pr[i0], g1 = pr[i1], gs = g0 + g1;
  g0 /= gs; g1 /= gs;
  int s0 = atomicAdd(&cnt[i0], 1);
  int s1 = atomicAdd(&cnt[i1], 1);
  plist[i0*NPTS + s0] = n; slotW[i0*NPTS + s0] = g0;
  plist[i1*NPTS + s1] = n; slotW[i1*NPTS + s1] = g1;
  pairE[n*2+0] = i0; pairE[n*2+1] = i1;
  pairS[n*2+0] = s0; pairS[n*2+1] = s1;

  pe[(size_t)n*64 + 0] = c0;
  pe[(size_t)n*64 + 1] = c1;
  pe[(size_t)n*64 + 2] = c2;
  float cc[3] = {c0, c1, c2};
#pragma unroll
  for (int i = 0; i < 10; ++i) {
    float sc = 3.14159274101257324f * (float)(1 << i);
#pragma unroll
    for (int j = 0; j < 3; ++j) {
      float a = sc * cc[j];
      pe[(size_t)n*64 + 3 + (i*3+j)*2 + 0] = sinf(a);
      pe[(size_t)n*64 + 3 + (i*3+j)*2 + 1] = cosf(a);
    }
  }
  pe[(size_t)n*64 + 63] = 0.f;

  float pfv[64];
#pragma unroll
  for (int d = 0; d < 64; ++d) pfv[d] = 1.f;
  for (int i = 0; i < 2; ++i) {
    float p = x[n*5 + 3 + i] * 63.0f;
    float f = floorf(p);
    float wfr = p - f;
    int j0 = (int)f;
    int j1 = (int)fminf(f + 1.0f, 63.0f);
    const float* L = lines + (size_t)i * 64 * 64;
#pragma unroll
    for (int d = 0; d < 64; ++d) {
      float a = L[d*64 + j0];
      float b = L[d*64 + j1];
      pfv[d] *= a + wfr * (b - a);
    }
  }
#pragma unroll
  for (int d = 0; d < 64; ++d) pf[(size_t)n*64 + d] = pfv[d];
}

// ---------- kernel 2: K/V projection ----------
__global__ __launch_bounds__(256) void k_kv(
    const float* __restrict__ mem_k, const float* __restrict__ mem_v,
    const float* __restrict__ Wk, const float* __restrict__ Wv,
    u16* __restrict__ Khf, float* __restrict__ Vhat)
{
  int e = blockIdx.y;
  int which = blockIdx.z;
  const float* src = which ? mem_v : mem_k;
  const float* W   = which ? Wv : Wk;
  int r0 = blockIdx.x * 32;
  __shared__ float sm[32][130];
  int tid = threadIdx.x;
  for (int idx = tid; idx < 32*32; idx += 256) {
    int r = idx >> 5, c4 = (idx & 31) * 4;
    float4 v = *(const float4*)(src + ((size_t)e*NM + r0 + r)*DD + c4);
    sm[r][c4+0] = v.x; sm[r][c4+1] = v.y; sm[r][c4+2] = v.z; sm[r][c4+3] = v.w;
  }
  __syncthreads();
  int r = tid >> 3, cb = (tid & 7) * 16;
  float acc[16];
#pragma unroll
  for (int i = 0; i < 16; ++i) acc[i] = 0.f;
  const float* We = W + (size_t)e*DD*DD;
#pragma unroll 4
  for (int k = 0; k < 128; ++k) {
    float s = sm[r][k];
    const float4* w4 = (const float4*)(We + (size_t)k*DD + cb);
#pragma unroll
    for (int q = 0; q < 4; ++q) {
      float4 wv = w4[q];
      acc[q*4+0] = fmaf(s, wv.x, acc[q*4+0]);
      acc[q*4+1] = fmaf(s, wv.y, acc[q*4+1]);
      acc[q*4+2] = fmaf(s, wv.z, acc[q*4+2]);
      acc[q*4+3] = fmaf(s, wv.w, acc[q*4+3]);
    }
  }
  if (which) {
    float* drow = Vhat + ((size_t)e*NM + r0 + r)*DD + cb;
#pragma unroll
    for (int i = 0; i < 16; ++i) drow[i] = acc[i];
  } else {
    int key = r0 + r;
    int T = key >> 4;
    int kr = key & 15;
#pragma unroll
    for (int b = 0; b < 2; ++b) {
      int k_off = cb + b*8;
      int kt = k_off >> 5;
      int lhi = (k_off >> 3) & 3;
      int lane_ = lhi*16 + kr;
      size_t dst = (((size_t)e*128 + T)*4 + kt)*512 + (size_t)lane_*8;
      unsigned ph[4];
#pragma unroll
      for (int p = 0; p < 4; ++p) {
        u16 h0 = f2bf(acc[b*8 + p*2 + 0]);
        u16 h1 = f2bf(acc[b*8 + p*2 + 1]);
        ph[p] = (unsigned)h0 | ((unsigned)h1 << 16);
      }
      *(uint4*)(Khf + dst) = make_uint4(ph[0], ph[1], ph[2], ph[3]);
    }
  }
}

// ---------- kernel 2b: pack per-expert weights into bf16 hi/lo B-fragments ----------
__global__ __launch_bounds__(64) void k_pack(
    const float* __restrict__ We1, const float* __restrict__ We2,
    const float* __restrict__ We3, const float* __restrict__ Wq,
    const float* __restrict__ A1, const float* __restrict__ A2,
    u16* __restrict__ We1h, u16* __restrict__ We1l,
    u16* __restrict__ We2h, u16* __restrict__ We2l,
    u16* __restrict__ We3h, u16* __restrict__ We3l,
    u16* __restrict__ Wqh,  u16* __restrict__ Wql,
    u16* __restrict__ A1h,  u16* __restrict__ A1l,
    u16* __restrict__ A2h,  u16* __restrict__ A2l)
{
  int e = blockIdx.y;
  int f = blockIdx.x;
  int lane = threadIdx.x;
  int col = lane & 15, khalf = lane >> 4;
  const float* src; u16 *dh, *dl;
  int Krows, N, ks, ct;
  if (f < 32) {
    int fl = f;        src = We1 + (size_t)e*63*256;  Krows = 63;  N = 256;
    ks = fl >> 4; ct = fl & 15;
    dh = We1h + ((size_t)e*32  + fl)*512; dl = We1l + ((size_t)e*32  + fl)*512;
  } else if (f < 160) {
    int fl = f - 32;   src = We2 + (size_t)e*256*256; Krows = 256; N = 256;
    ks = fl >> 4; ct = fl & 15;
    dh = We2h + ((size_t)e*128 + fl)*512; dl = We2l + ((size_t)e*128 + fl)*512;
  } else if (f < 224) {
    int fl = f - 160;  src = We3 + (size_t)e*256*128; Krows = 256; N = 128;
    ks = fl >> 3; ct = fl & 7;
    dh = We3h + ((size_t)e*64  + fl)*512; dl = We3l + ((size_t)e*64  + fl)*512;
  } else if (f < 256) {
    int fl = f - 224;  src = Wq  + (size_t)e*128*128; Krows = 128; N = 128;
    ks = fl >> 3; ct = fl & 7;
    dh = Wqh  + ((size_t)e*32  + fl)*512; dl = Wql  + ((size_t)e*32  + fl)*512;
  } else if (f < 280) {
    int fl = f - 256;  src = A1  + (size_t)e*192*64;  Krows = 192; N = 64;
    ks = fl >> 2; ct = fl & 3;
    dh = A1h  + ((size_t)e*24  + fl)*512; dl = A1l  + ((size_t)e*24  + fl)*512;
  } else {
    int fl = f - 280;  src = A2  + (size_t)e*64*128;  Krows = 64;  N = 128;
    ks = fl >> 3; ct = fl & 7;
    dh = A2h  + ((size_t)e*16  + fl)*512; dl = A2l  + ((size_t)e*16  + fl)*512;
  }
  unsigned ph[4], pl[4];
#pragma unroll
  for (int p = 0; p < 4; ++p) {
    int k0 = ks*32 + khalf*8 + 2*p;
    float x0 = (k0   < Krows) ? src[(size_t)k0*N     + ct*16 + col] : 0.f;
    float x1 = (k0+1 < Krows) ? src[(size_t)(k0+1)*N + ct*16 + col] : 0.f;
    u16 h0 = f2bf(x0), h1 = f2bf(x1);
    u16 l0 = f2bf(x0 - bf2f(h0)), l1 = f2bf(x1 - bf2f(h1));
    ph[p] = (unsigned)h0 | ((unsigned)h1 << 16);
    pl[p] = (unsigned)l0 | ((unsigned)l1 << 16);
  }
  *(uint4*)(dh + lane*8) = make_uint4(ph[0], ph[1], ph[2], ph[3]);
  *(uint4*)(dl + lane*8) = make_uint4(pl[0], pl[1], pl[2], pl[3]);
}

// ---------- kernel 2c: pack final-MLP weights M1/M2/M3 (shared, N=256) ----------
// grid 320: M1 0..63 (K=128), M2 64..191 (K=256), M3 192..319 (K=256).
__global__ __launch_bounds__(64) void k_packM(
    const float* __restrict__ M1, const float* __restrict__ M2,
    const float* __restrict__ M3,
    u16* __restrict__ M1h, u16* __restrict__ M1l,
    u16* __restrict__ M2h, u16* __restrict__ M2l,
    u16* __restrict__ M3h, u16* __restrict__ M3l)
{
  int f = blockIdx.x;
  int lane = threadIdx.x;
  int col = lane & 15, khalf = lane >> 4;
  const float* src; u16 *dh, *dl;
  int ks, ct;
  if (f < 64)       { int fl=f;     src=M1; ks=fl>>4; ct=fl&15; dh=M1h+(size_t)fl*512; dl=M1l+(size_t)fl*512; }
  else if (f < 192) { int fl=f-64;  src=M2; ks=fl>>4; ct=fl&15; dh=M2h+(size_t)fl*512; dl=M2l+(size_t)fl*512; }
  else              { int fl=f-192; src=M3; ks=fl>>4; ct=fl&15; dh=M3h+(size_t)fl*512; dl=M3l+(size_t)fl*512; }
  unsigned ph[4], pl[4];
#pragma unroll
  for (int p = 0; p < 4; ++p) {
    int k0 = ks*32 + khalf*8 + 2*p;
    float x0 = src[(size_t)k0*NHM     + ct*16 + col];
    float x1 = src[(size_t)(k0+1)*NHM + ct*16 + col];
    u16 h0 = f2bf(x0), h1 = f2bf(x1);
    u16 l0 = f2bf(x0 - bf2f(h0)), l1 = f2bf(x1 - bf2f(h1));
    ph[p] = (unsigned)h0 | ((unsigned)h1 << 16);
    pl[p] = (unsigned)l0 | ((unsigned)l1 << 16);
  }
  *(uint4*)(dh + lane*8) = make_uint4(ph[0], ph[1], ph[2], ph[3]);
  *(uint4*)(dl + lane*8) = make_uint4(pl[0], pl[1], pl[2], pl[3]);
}

#define CONV_FRAG(PTR, AH, AL) {                                        \
    const float* p_ = (PTR);                                            \
    float4 u0_ = *(const float4*)p_, u1_ = *(const float4*)(p_+4);      \
    float xv_[8] = {u0_.x,u0_.y,u0_.z,u0_.w,u1_.x,u1_.y,u1_.z,u1_.w};   \
    union { unsigned u[4]; short8 s; } H_, L_;                          \
    _Pragma("unroll")                                                   \
    for (int q_ = 0; q_ < 4; ++q_) {                                    \
      u16 h0_ = f2bf(xv_[2*q_]), h1_ = f2bf(xv_[2*q_+1]);               \
      u16 l0_ = f2bf(xv_[2*q_] - bf2f(h0_));                            \
      u16 l1_ = f2bf(xv_[2*q_+1] - bf2f(h1_));                          \
      H_.u[q_] = (unsigned)h0_ | ((unsigned)h1_ << 16);                 \
      L_.u[q_] = (unsigned)l0_ | ((unsigned)l1_ << 16);                 \
    }                                                                   \
    AH = H_.s; AL = L_.s; }

// ---------- kernel 3: MFMA expert SIREN MLP + LN + Q-proj ----------
__global__ __launch_bounds__(256) void k_expert(
    const float* __restrict__ pe,
    const u16* __restrict__ We1h, const u16* __restrict__ We1l,
    const u16* __restrict__ We2h, const u16* __restrict__ We2l,
    const u16* __restrict__ We3h, const u16* __restrict__ We3l,
    const u16* __restrict__ Wqh,  const u16* __restrict__ Wql,
    const float* __restrict__ be1, const float* __restrict__ be2,
    const float* __restrict__ be3,
    const float* __restrict__ ln_g, const float* __restrict__ ln_b,
    const int* __restrict__ plist, const int* __restrict__ cnt,
    float* __restrict__ featsC, float* __restrict__ QC)
{
  int e = blockIdx.y;
  int count = cnt[e];
  int base = blockIdx.x * 32;
  if (base >= count) return;
  __shared__ float actA[16*512];   // 32 KB
  __shared__ float lnS[256];
  __shared__ int pts[32];
  int tid = threadIdx.x;
  int w = tid >> 6, lane = tid & 63;
  int rloc = lane & 15, khalf = lane >> 4;

  if (tid < 32) {
    int slot = base + tid;
    pts[tid] = (slot < count) ? plist[e*NPTS + slot] : 0;
  } else if (tid >= 64 && tid < 192) {
    int i = tid - 64;
    lnS[i] = ln_g[i];
    lnS[128 + i] = ln_b[i];
  }
  __syncthreads();
  {
    int Mt = tid >> 7, ks = (tid >> 6) & 1;
    const float* src = pe + (size_t)pts[Mt*16 + rloc]*64 + ks*32 + khalf*8;
    float4 a = *(const float4*)src;
    float4 b = *(const float4*)(src + 4);
    float* d = &actA[(Mt*8 + ks)*512 + lane*8];
    *(float4*)d = a; *(float4*)(d + 4) = b;
  }
  __syncthreads();

  // ---- L1: K=64 (2 ks), N=256, sin(30x) ----
  {
    f32x4 acc[2][4];
#pragma unroll
    for (int Mt = 0; Mt < 2; ++Mt)
#pragma unroll
      for (int c = 0; c < 4; ++c) acc[Mt][c] = (f32x4){0.f,0.f,0.f,0.f};
    for (int ks = 0; ks < 2; ++ks) {
      short8 ah[2], al[2];
#pragma unroll
      for (int Mt = 0; Mt < 2; ++Mt)
        CONV_FRAG(&actA[(Mt*8+ks)*512 + lane*8], ah[Mt], al[Mt]);
#pragma unroll
      for (int c = 0; c < 4; ++c) {
        size_t fo = ((size_t)e*32 + ks*16 + w*4 + c)*512 + (size_t)lane*8;
        short8 bh = *(const short8*)(We1h + fo);
        short8 bl = *(const short8*)(We1l + fo);
#pragma unroll
        for (int Mt = 0; Mt < 2; ++Mt) {
          acc[Mt][c] = __builtin_amdgcn_mfma_f32_16x16x32_bf16(ah[Mt], bh, acc[Mt][c], 0,0,0);
          acc[Mt][c] = __builtin_amdgcn_mfma_f32_16x16x32_bf16(ah[Mt], bl, acc[Mt][c], 0,0,0);
          acc[Mt][c] = __builtin_amdgcn_mfma_f32_16x16x32_bf16(al[Mt], bh, acc[Mt][c], 0,0,0);
        }
      }
    }
    __syncthreads();
#pragma unroll
    for (int Mt = 0; Mt < 2; ++Mt)
#pragma unroll
      for (int c = 0; c < 4; ++c) {
        int n = (w*4+c)*16 + rloc;
        float b = be1[e*NHE + n];
        int ksp = n >> 5, lp = ((n>>3)&3)*16, jp = n & 7;
#pragma unroll
        for (int i = 0; i < 4; ++i)
          actA[(Mt*8+ksp)*512 + (lp + khalf*4 + i)*8 + jp] = sinf(30.f*(acc[Mt][c][i] + b));
      }
    __syncthreads();
  }

  // ---- L2: K=256 (8 ks), N=256, sin(30x) ----
  {
    f32x4 acc[2][4];
#pragma unroll
    for (int Mt = 0; Mt < 2; ++Mt)
#pragma unroll
      for (int c = 0; c < 4; ++c) acc[Mt][c] = (f32x4){0.f,0.f,0.f,0.f};
#pragma unroll 2
    for (int ks = 0; ks < 8; ++ks) {
      short8 ah[2], al[2];
#pragma unroll
      for (int Mt = 0; Mt < 2; ++Mt)
        CONV_FRAG(&actA[(Mt*8+ks)*512 + lane*8], ah[Mt], al[Mt]);
#pragma unroll
      for (int c = 0; c < 4; ++c) {
        size_t fo = ((size_t)e*128 + ks*16 + w*4 + c)*512 + (size_t)lane*8;
        short8 bh = *(const short8*)(We2h + fo);
        short8 bl = *(const short8*)(We2l + fo);
#pragma unroll
        for (int Mt = 0; Mt < 2; ++Mt) {
          acc[Mt][c] = __builtin_amdgcn_mfma_f32_16x16x32_bf16(ah[Mt], bh, acc[Mt][c], 0,0,0);
          acc[Mt][c] = __builtin_amdgcn_mfma_f32_16x16x32_bf16(ah[Mt], bl, acc[Mt][c], 0,0,0);
          acc[Mt][c] = __builtin_amdgcn_mfma_f32_16x16x32_bf16(al[Mt], bh, acc[Mt][c], 0,0,0);
        }
      }
    }
    __syncthreads();
#pragma unroll
    for (int Mt = 0; Mt < 2; ++Mt)
#pragma unroll
      for (int c = 0; c < 4; ++c) {
        int n = (w*4+c)*16 + rloc;
        float b = be2[e*NHE + n];
        int ksp = n >> 5, lp = ((n>>3)&3)*16, jp = n & 7;
#pragma unroll
        for (int i = 0; i < 4; ++i)
          actA[(Mt*8+ksp)*512 + (lp + khalf*4 + i)*8 + jp] = sinf(30.f*(acc[Mt][c][i] + b));
      }
    __syncthreads();
  }

  // ---- L3: K=256 (8 ks), N=128, linear -> feats ----
  {
    f32x4 acc[2][2];
#pragma unroll
    for (int Mt = 0; Mt < 2; ++Mt)
#pragma unroll
      for (int c = 0; c < 2; ++c) acc[Mt][c] = (f32x4){0.f,0.f,0.f,0.f};
#pragma unroll 2
    for (int ks = 0; ks < 8; ++ks) {
      short8 ah[2], al[2];
#pragma unroll
      for (int Mt = 0; Mt < 2; ++Mt)
        CONV_FRAG(&actA[(Mt*8+ks)*512 + lane*8], ah[Mt], al[Mt]);
#pragma unroll
      for (int c = 0; c < 2; ++c) {
        size_t fo = ((size_t)e*64 + ks*8 + w*2 + c)*512 + (size_t)lane*8;
        short8 bh = *(const short8*)(We3h + fo);
        short8 bl = *(const short8*)(We3l + fo);
#pragma unroll
        for (int Mt = 0; Mt < 2; ++Mt) {
          acc[Mt][c] = __builtin_amdgcn_mfma_f32_16x16x32_bf16(ah[Mt], bh, acc[Mt][c], 0,0,0);
          acc[Mt][c] = __builtin_amdgcn_mfma_f32_16x16x32_bf16(ah[Mt], bl, acc[Mt][c], 0,0,0);
          acc[Mt][c] = __builtin_amdgcn_mfma_f32_16x16x32_bf16(al[Mt], bh, acc[Mt][c], 0,0,0);
        }
      }
    }
    __syncthreads();
#pragma unroll
    for (int Mt = 0; Mt < 2; ++Mt)
#pragma unroll
      for (int c = 0; c < 2; ++c) {
        int n = (w*2+c)*16 + rloc;
        float b = be3[e*DD + n];
        int ksp = n >> 5, lp = ((n>>3)&3)*16, jp = n & 7;
#pragma unroll
        for (int i = 0; i < 4; ++i) {
          float f = acc[Mt][c][i] + b;
          actA[(Mt*8+ksp)*512 + (lp + khalf*4 + i)*8 + jp] = f;
          int slot = base + Mt*16 + khalf*4 + i;
          if (slot < count)
            featsC[((size_t)e*NPTS + slot)*DD + n] = f;
        }
      }
    __syncthreads();
  }

  // ---- LN + Wq: K=128 (4 ks), N=128 ----
  {
    float mu[2], rsv[2];
#pragma unroll
    for (int Mt = 0; Mt < 2; ++Mt) {
      float sm = 0.f, sq = 0.f;
#pragma unroll
      for (int ks = 0; ks < 4; ++ks) {
        const float* p = &actA[(Mt*8+ks)*512 + lane*8];
        float4 u0 = *(const float4*)p, u1 = *(const float4*)(p+4);
        sm += u0.x+u0.y+u0.z+u0.w + u1.x+u1.y+u1.z+u1.w;
        sq += u0.x*u0.x+u0.y*u0.y+u0.z*u0.z+u0.w*u0.w
            + u1.x*u1.x+u1.y*u1.y+u1.z*u1.z+u1.w*u1.w;
      }
      sm += __shfl_xor(sm, 16); sq += __shfl_xor(sq, 16);
      sm += __shfl_xor(sm, 32); sq += __shfl_xor(sq, 32);
      mu[Mt] = sm * (1.f/128.f);
      rsv[Mt] = rsqrtf(sq * (1.f/128.f) - mu[Mt]*mu[Mt] + 1e-5f);
    }
    f32x4 acc[2][2];
#pragma unroll
    for (int Mt = 0; Mt < 2; ++Mt)
#pragma unroll
      for (int c = 0; c < 2; ++c) acc[Mt][c] = (f32x4){0.f,0.f,0.f,0.f};
    for (int ks = 0; ks < 4; ++ks) {
      short8 ah[2], al[2];
#pragma unroll
      for (int Mt = 0; Mt < 2; ++Mt) {
        const float* p = &actA[(Mt*8+ks)*512 + lane*8];
        float4 u0 = *(const float4*)p, u1 = *(const float4*)(p+4);
        float xv[8] = {u0.x,u0.y,u0.z,u0.w,u1.x,u1.y,u1.z,u1.w};
        union { unsigned u[4]; short8 s; } H, L;
#pragma unroll
        for (int j = 0; j < 8; ++j) {
          int k = ks*32 + khalf*8 + j;
          xv[j] = (xv[j] - mu[Mt]) * rsv[Mt] * lnS[k] + lnS[128 + k];
        }
#pragma unroll
        for (int q = 0; q < 4; ++q) {
          u16 h0 = f2bf(xv[2*q]), h1 = f2bf(xv[2*q+1]);
          u16 l0 = f2bf(xv[2*q] - bf2f(h0)), l1 = f2bf(xv[2*q+1] - bf2f(h1));
          H.u[q] = (unsigned)h0 | ((unsigned)h1 << 16);
          L.u[q] = (unsigned)l0 | ((unsigned)l1 << 16);
        }
        ah[Mt] = H.s; al[Mt] = L.s;
      }
#pragma unroll
      for (int c = 0; c < 2; ++c) {
        size_t fo = ((size_t)e*32 + ks*8 + w*2 + c)*512 + (size_t)lane*8;
        short8 bh = *(const short8*)(Wqh + fo);
        short8 bl = *(const short8*)(Wql + fo);
#pragma unroll
        for (int Mt = 0; Mt < 2; ++Mt) {
          acc[Mt][c] = __builtin_amdgcn_mfma_f32_16x16x32_bf16(ah[Mt], bh, acc[Mt][c], 0,0,0);
          acc[Mt][c] = __builtin_amdgcn_mfma_f32_16x16x32_bf16(ah[Mt], bl, acc[Mt][c], 0,0,0);
          acc[Mt][c] = __builtin_amdgcn_mfma_f32_16x16x32_bf16(al[Mt], bh, acc[Mt][c], 0,0,0);
        }
      }
    }
#pragma unroll
    for (int Mt = 0; Mt < 2; ++Mt)
#pragma unroll
      for (int c = 0; c < 2; ++c) {
        int n = (w*2+c)*16 + rloc;
#pragma unroll
        for (int i = 0; i < 4; ++i) {
          int slot = base + Mt*16 + khalf*4 + i;
          if (slot < count)
            QC[((size_t)e*NPTS + slot)*DD + n] = acc[Mt][c][i];
        }
      }
  }
}

// ---------- kernel 4: MFMA scores (pure bf16) + top-16 + softmax ----------
// R10: (a) Q-lo dropped too — single-term Kh·Qh (score err ~2.8e-3, boundary
// swaps benign; R8's K-lo drop left absmax bit-identical). LDS 32.4 KB ->
// 4 blocks/CU. (b) per-slot threshold CACHED in registers (Tc/Ic), updated
// only after accepted inserts — the common no-insert gate is now shfl-free
// (R9 post-mortem: insert machinery's dependent shfl chains dominate).
__global__ __launch_bounds__(256) void k_scores(
    const float* __restrict__ QC, const u16* __restrict__ Khf,
    const int* __restrict__ cnt,
    float* __restrict__ attnW, int* __restrict__ attnI)
{
  int e = blockIdx.y;
  int count = cnt[e];
  int sbase = blockIdx.x * 32;
  if (sbase >= count) return;
  __shared__ u16 KhS[16*512];    // 16 KB
  __shared__ u16 QhS[8*512];     // 8 KB
  __shared__ float Ssc[64][33];  // 8.4 KB
  int tid = threadIdx.x;
  int w = tid >> 6, lane = tid & 63;

#pragma unroll
  for (int it = 0; it < 2; ++it) {
    int frag = it*4 + w;
    int st = frag >> 2, kt = frag & 3;
    int srow = lane & 15, khalf = lane >> 4;
    int slot = sbase + st*16 + srow;
    float q[8];
    if (slot < count) {
      const float* Qr = QC + ((size_t)e*NPTS + slot)*DD + kt*32 + khalf*8;
#pragma unroll
      for (int i = 0; i < 8; ++i) q[i] = Qr[i];
    } else {
#pragma unroll
      for (int i = 0; i < 8; ++i) q[i] = 0.f;
    }
    int dst = frag*512 + lane*8;
#pragma unroll
    for (int i = 0; i < 8; ++i) QhS[dst + i] = f2bf(q[i]);
  }

  float lv0 = NEG_INF, lv1 = NEG_INF;
  int   li0 = 0x7fffffff, li1 = 0x7fffffff;
  float Tc0[4], Tc1[4];
  int   Ic0[4], Ic1[4];
#pragma unroll
  for (int j = 0; j < 4; ++j) {
    Tc0[j] = NEG_INF; Tc1[j] = NEG_INF;
    Ic0[j] = 0x7fffffff; Ic1[j] = 0x7fffffff;
  }
  const u16* KhB = Khf + (size_t)e*128*4*512;

#define INS_SET(LV, LI, TC, IC, SL0) {                                       \
    int keyb = ch*64;                                                        \
    _Pragma("unroll")                                                        \
    for (int j = 0; j < 4; ++j) {                                            \
      int slot = sbase + (SL0) + j;                                          \
      if (slot >= count) continue;                                           \
      float v = Ssc[lane][(SL0) + j];                                        \
      int key = keyb + lane;                                                 \
      unsigned long long mb = __ballot(rank_gt(v, key, TC[j], IC[j]));       \
      while (mb) {                                                           \
        int b = __ffsll((unsigned long long)mb) - 1;                         \
        mb &= mb - 1;                                                        \
        float cv = __shfl(v, b);                                             \
        int   ck = keyb + b;                                                 \
        if (!rank_gt(cv, ck, TC[j], IC[j])) continue;                        \
        float pv = __shfl_up(LV, 1);                                         \
        int   pi = __shfl_up(LI, 1);                                         \
        int p = lane & 15;                                                   \
        bool abv_me   = rank_gt(LV, LI, cv, ck);                             \
        bool abv_prev = (p == 0) || rank_gt(pv, pi, cv, ck);                 \
        float nv = abv_me ? LV : (abv_prev ? cv : pv);                       \
        int   ni = abv_me ? LI : (abv_prev ? ck : pi);                       \
        if ((lane >> 4) == j) { LV = nv; LI = ni; }                          \
        TC[j] = __shfl(LV, j*16 + 15);                                       \
        IC[j] = __shfl(LI, j*16 + 15);                                       \
      }                                                                      \
    } }

  for (int ch = 0; ch < NM/64; ++ch) {
    __syncthreads();
    {
      const uint4* srcH = (const uint4*)(KhB + (size_t)ch*8192);
      uint4* dH = (uint4*)KhS;
#pragma unroll
      for (int i = 0; i < 4; ++i) dH[tid + i*256] = srcH[tid + i*256];
    }
    __syncthreads();

#pragma unroll
    for (int st = 0; st < 2; ++st) {
      f32x4 acc = {0.f, 0.f, 0.f, 0.f};
#pragma unroll
      for (int kt = 0; kt < 4; ++kt) {
        short8 ah = *(const short8*)&KhS[(w*4+kt)*512 + lane*8];
        short8 bh = *(const short8*)&QhS[(st*4+kt)*512 + lane*8];
        acc = __builtin_amdgcn_mfma_f32_16x16x32_bf16(ah, bh, acc, 0, 0, 0);
      }
      int col = lane & 15, rbase = (lane >> 4) * 4;
#pragma unroll
      for (int i = 0; i < 4; ++i)
        Ssc[w*16 + rbase + i][st*16 + col] = acc[i];
    }
    __syncthreads();

    INS_SET(lv0, li0, Tc0, Ic0, w*8);
    INS_SET(lv1, li1, Tc1, Ic1, w*8 + 4);
  }
#undef INS_SET

  const float inv_scale = 0.08838834764831845f;  // 1/sqrt(128)
  auto fin = [&](float lv, int li, int sl0) {
#pragma unroll
    for (int j = 0; j < 4; ++j) {
      int slot = sbase + sl0 + j;
      if (slot >= count) continue;
      float m = __shfl(lv, j*16 + 0);
      float ev = expf((lv - m) * inv_scale);
      float s = ev;
      s += __shfl_xor(s, 1); s += __shfl_xor(s, 2);
      s += __shfl_xor(s, 4); s += __shfl_xor(s, 8);
      if ((lane >> 4) == j) {
        size_t off = ((size_t)e*NPTS + slot)*NTK + (lane & 15);
        attnW[off] = ev / s;
        attnI[off] = li;
      }
    }
  };
  fin(lv0, li0, w*8);
  fin(lv1, li1, w*8 + 4);
}

// ---------- kernel 5: MFMA adapter MLP + LN + attention combine ----------
__global__ __launch_bounds__(256) void k_adapter(
    const float* __restrict__ Vhat, const float* __restrict__ pf,
    const u16* __restrict__ A1h, const u16* __restrict__ A1l,
    const u16* __restrict__ A2h, const u16* __restrict__ A2l,
    const float* __restrict__ a1, const float* __restrict__ a2,
    const float* __restrict__ alng, const float* __restrict__ alnb,
    const float* __restrict__ attnW, const int* __restrict__ attnI,
    const float* __restrict__ featsC, const float* __restrict__ slotW,
    const int* __restrict__ plist, const int* __restrict__ cnt,
    float* __restrict__ outC)
{
  int e = blockIdx.y;
  int count = cnt[e];
  int s0 = blockIdx.x * 4;
  if (s0 >= count) return;
  __shared__ float ainV[64][132];
  __shared__ float hid[64][68];
  __shared__ float pfS[4][68];
  __shared__ float attwS[4][16];
  __shared__ float alnS[128], albS[128];
  __shared__ int   rtiS[64];
  __shared__ float wslS[4];
  __shared__ int   ptlS[4];
  int tid = threadIdx.x;
  if (tid < 64) {
    int sl = tid >> 4, key = tid & 15;
    int slot = s0 + sl;
    if (slot < count) {
      size_t o = ((size_t)e*NPTS + slot)*NTK + key;
      rtiS[tid] = attnI[o];
      attwS[sl][key] = attnW[o];
    } else { rtiS[tid] = 0; attwS[sl][key] = 0.f; }
  } else if (tid < 68) {
    int sl = tid - 64;
    int slot = s0 + sl;
    wslS[sl] = (slot < count) ? slotW[e*NPTS + slot] : 0.f;
    ptlS[sl] = (slot < count) ? plist[e*NPTS + slot] : 0;
  } else if (tid >= 128 && tid < 192) {
    int c2 = (tid - 128) * 2;
    alnS[c2]   = alng[e*DD + c2];
    alnS[c2+1] = alng[e*DD + c2+1];
    albS[c2]   = alnb[e*DD + c2];
    albS[c2+1] = alnb[e*DD + c2+1];
  }
  __syncthreads();
  for (int idx = tid; idx < 64*32; idx += 256) {
    int r = idx >> 5, c4 = (idx & 31) * 4;
    *(float4*)&ainV[r][c4] = *(const float4*)(Vhat + ((size_t)e*NM + rtiS[r])*DD + c4);
  }
  if (tid < 64) {
    int sl = tid >> 4, c4 = (tid & 15) * 4;
    *(float4*)&pfS[sl][c4] = *(const float4*)(pf + (size_t)ptlS[sl]*64 + c4);
  }
  __syncthreads();

  int w = tid >> 6, lane = tid & 63;
  int rloc = lane & 15;
  int khalf = lane >> 4;

  f32x4 acc1[4];
#pragma unroll
  for (int ct = 0; ct < 4; ++ct) acc1[ct] = (f32x4){0.f, 0.f, 0.f, 0.f};
  for (int ks = 0; ks < 6; ++ks) {
    short8 ah, al;
    {
      const float* src = (ks < 4) ? &ainV[w*16 + rloc][ks*32 + khalf*8]
                                  : &pfS[w][(ks-4)*32 + khalf*8];
      CONV_FRAG(src, ah, al);
    }
    const u16* bh0 = A1h + ((size_t)e*24 + ks*4)*512 + (size_t)lane*8;
    const u16* bl0 = A1l + ((size_t)e*24 + ks*4)*512 + (size_t)lane*8;
#pragma unroll
    for (int ct = 0; ct < 4; ++ct) {
      short8 bh = *(const short8*)(bh0 + ct*512);
      short8 bl = *(const short8*)(bl0 + ct*512);
      acc1[ct] = __builtin_amdgcn_mfma_f32_16x16x32_bf16(ah, bh, acc1[ct], 0, 0, 0);
      acc1[ct] = __builtin_amdgcn_mfma_f32_16x16x32_bf16(ah, bl, acc1[ct], 0, 0, 0);
      acc1[ct] = __builtin_amdgcn_mfma_f32_16x16x32_bf16(al, bh, acc1[ct], 0, 0, 0);
    }
  }
#pragma unroll
  for (int ct = 0; ct < 4; ++ct) {
    float b = a1[e*64 + ct*16 + rloc];
#pragma unroll
    for (int i = 0; i < 4; ++i)
      hid[w*16 + khalf*4 + i][ct*16 + rloc] = fmaxf(acc1[ct][i] + b, 0.f);
  }

  f32x4 acc2[8];
#pragma unroll
  for (int ct = 0; ct < 8; ++ct) acc2[ct] = (f32x4){0.f, 0.f, 0.f, 0.f};
  for (int ks = 0; ks < 2; ++ks) {
    short8 ah, al;
    CONV_FRAG(&hid[w*16 + rloc][ks*32 + khalf*8], ah, al);
    const u16* bh0 = A2h + ((size_t)e*16 + ks*8)*512 + (size_t)lane*8;
    const u16* bl0 = A2l + ((size_t)e*16 + ks*8)*512 + (size_t)lane*8;
#pragma unroll
    for (int ct = 0; ct < 8; ++ct) {
      short8 bh = *(const short8*)(bh0 + ct*512);
      short8 bl = *(const short8*)(bl0 + ct*512);
      acc2[ct] = __builtin_amdgcn_mfma_f32_16x16x32_bf16(ah, bh, acc2[ct], 0, 0, 0);
      acc2[ct] = __builtin_amdgcn_mfma_f32_16x16x32_bf16(ah, bl, acc2[ct], 0, 0, 0);
      acc2[ct] = __builtin_amdgcn_mfma_f32_16x16x32_bf16(al, bh, acc2[ct], 0, 0, 0);
    }
  }

  float ad[8][4];
#pragma unroll
  for (int ct = 0; ct < 8; ++ct) {
    float b = a2[e*DD + ct*16 + rloc];
#pragma unroll
    for (int i = 0; i < 4; ++i) ad[ct][i] = acc2[ct][i] + b;
  }
  float mu[4], rsv[4];
#pragma unroll
  for (int i = 0; i < 4; ++i) {
    float sm = 0.f, sq = 0.f;
#pragma unroll
    for (int ct = 0; ct < 8; ++ct) { sm += ad[ct][i]; sq += ad[ct][i]*ad[ct][i]; }
    sm += __shfl_xor(sm, 1); sq += __shfl_xor(sq, 1);
    sm += __shfl_xor(sm, 2); sq += __shfl_xor(sq, 2);
    sm += __shfl_xor(sm, 4); sq += __shfl_xor(sq, 4);
    sm += __shfl_xor(sm, 8); sq += __shfl_xor(sq, 8);
    mu[i] = sm * (1.f/128.f);
    float var = sq * (1.f/128.f) - mu[i]*mu[i];
    rsv[i] = rsqrtf(var + 1e-5f);
  }
  float aw[4];
#pragma unroll
  for (int i = 0; i < 4; ++i) aw[i] = attwS[w][khalf*4 + i];

  float outv[8];
#pragma unroll
  for (int ct = 0; ct < 8; ++ct) {
    int cg = ct*16 + rloc;
    float g = alnS[cg], bb = albS[cg];
    float s = 0.f;
#pragma unroll
    for (int i = 0; i < 4; ++i) {
      float vt = ainV[w*16 + khalf*4 + i][cg];
      s += aw[i] * (vt + (ad[ct][i] - mu[i]) * rsv[i] * g + bb);
    }
    outv[ct] = s;
  }
#pragma unroll
  for (int ct = 0; ct < 8; ++ct) {
    outv[ct] += __shfl_xor(outv[ct], 16);
    outv[ct] += __shfl_xor(outv[ct], 32);
  }
  int slot = s0 + w;
  if (khalf == 0 && slot < count) {
    size_t o = ((size_t)e*NPTS + slot)*DD;
    float wg = wslS[w];
#pragma unroll
    for (int ct = 0; ct < 8; ++ct) {
      int cg = ct*16 + rloc;
      outC[o + cg] = wg * (outv[ct] + featsC[o + cg]);
    }
  }
}

// ---------- kernel 6: MFMA final MLP + sigmoid ----------
// 32 rows/block in the k_expert-proven actA A-layout; M1/M2/M3 as pre-packed
// hi/lo B-frags from global (L2-resident). Barriers ~100 -> 8; LDS 34 KB ->
// 4 blocks/CU. Final dot: waves 0,1 handle row-tile Mt=w, reduce via shfl.
__global__ __launch_bounds__(256) void k_final(
    const float* __restrict__ outC, const int* __restrict__ pairE, const int* __restrict__ pairS,
    const u16* __restrict__ M1h, const u16* __restrict__ M1l,
    const u16* __restrict__ M2h, const u16* __restrict__ M2l,
    const u16* __restrict__ M3h, const u16* __restrict__ M3l,
    const float* __restrict__ c1, const float* __restrict__ c2,
    const float* __restrict__ c3,
    const float* __restrict__ M4, const float* __restrict__ c4,
    float* __restrict__ out)
{
  int base = blockIdx.x * 32;
  __shared__ float actA[16*512];   // 32 KB
  __shared__ float M4S[256];
  __shared__ int prE[64], prS[64];
  int tid = threadIdx.x;
  int w = tid >> 6, lane = tid & 63;
  int rloc = lane & 15, khalf = lane >> 4;

  if (tid < 64) {
    prE[tid] = pairE[(size_t)base*2 + tid];
    prS[tid] = pairS[(size_t)base*2 + tid];
  } else if (tid >= 64 && tid < 128) {
    int i = (tid - 64) * 4;
    *(float4*)&M4S[i] = *(const float4*)(M4 + i);
  }
  __syncthreads();
  // stage: sum the 2 outC rows per point directly into A-layout (K=128: ks 0..3)
#pragma unroll
  for (int it = 0; it < 2; ++it) {
    int combo = it*4 + w;             // 0..7 = (Mt, ks)
    int Mt = combo >> 2, ks = combo & 3;
    int row = Mt*16 + rloc;
    const float* sA = outC + ((size_t)prE[row*2+0]*NPTS + prS[row*2+0])*DD + ks*32 + khalf*8;
    const float* sB = outC + ((size_t)prE[row*2+1]*NPTS + prS[row*2+1])*DD + ks*32 + khalf*8;
    float4 a0 = *(const float4*)sA, a1 = *(const float4*)(sA+4);
    float4 b0 = *(const float4*)sB, b1 = *(const float4*)(sB+4);
    float* d = &actA[(Mt*8 + ks)*512 + lane*8];
    d[0]=a0.x+b0.x; d[1]=a0.y+b0.y; d[2]=a0.z+b0.z; d[3]=a0.w+b0.w;
    d[4]=a1.x+b1.x; d[5]=a1.y+b1.y; d[6]=a1.z+b1.z; d[7]=a1.w+b1.w;
  }
  __syncthreads();

  // ---- L1: K=128 (4 ks), N=256, relu ----
  {
    f32x4 acc[2][4];
#pragma unroll
    for (int Mt = 0; Mt < 2; ++Mt)
#pragma unroll
      for (int c = 0; c < 4; ++c) acc[Mt][c] = (f32x4){0.f,0.f,0.f,0.f};
    for (int ks = 0; ks < 4; ++ks) {
      short8 ah[2], al[2];
#pragma unroll
      for (int Mt = 0; Mt < 2; ++Mt)
        CONV_FRAG(&actA[(Mt*8+ks)*512 + lane*8], ah[Mt], al[Mt]);
#pragma unroll
      for (int c = 0; c < 4; ++c) {
        size_t fo = ((size_t)(ks*16 + w*4 + c))*512 + (size_t)lane*8;
        short8 bh = *(const short8*)(M1h + fo);
        short8 bl = *(const short8*)(M1l + fo);
#pragma unroll
        for (int Mt = 0; Mt < 2; ++Mt) {
          acc[Mt][c] = __builtin_amdgcn_mfma_f32_16x16x32_bf16(ah[Mt], bh, acc[Mt][c], 0,0,0);
          acc[Mt][c] = __builtin_amdgcn_mfma_f32_16x16x32_bf16(ah[Mt], bl, acc[Mt][c], 0,0,0);
          acc[Mt][c] = __builtin_amdgcn_mfma_f32_16x16x32_bf16(al[Mt], bh, acc[Mt][c], 0,0,0);
        }
      }
    }
    __syncthreads();
#pragma unroll
    for (int Mt = 0; Mt < 2; ++Mt)
#pragma unroll
      for (int c = 0; c < 4; ++c) {
        int n = (w*4+c)*16 + rloc;
        float b = c1[n];
        int ksp = n >> 5, lp = ((n>>3)&3)*16, jp = n & 7;
#pragma unroll
        for (int i = 0; i < 4; ++i)
          actA[(Mt*8+ksp)*512 + (lp + khalf*4 + i)*8 + jp] = fmaxf(acc[Mt][c][i] + b, 0.f);
      }
    __syncthreads();
  }

  // ---- L2, L3: K=256 (8 ks), N=256, relu ----
#pragma unroll 1
  for (int layer = 0; layer < 2; ++layer) {
    const u16* Wh = layer ? M3h : M2h;
    const u16* Wl = layer ? M3l : M2l;
    const float* bias = layer ? c3 : c2;
    f32x4 acc[2][4];
#pragma unroll
    for (int Mt = 0; Mt < 2; ++Mt)
#pragma unroll
      for (int c = 0; c < 4; ++c) acc[Mt][c] = (f32x4){0.f,0.f,0.f,0.f};
#pragma unroll 2
    for (int ks = 0; ks < 8; ++ks) {
      short8 ah[2], al[2];
#pragma unroll
      for (int Mt = 0; Mt < 2; ++Mt)
        CONV_FRAG(&actA[(Mt*8+ks)*512 + lane*8], ah[Mt], al[Mt]);
#pragma unroll
      for (int c = 0; c < 4; ++c) {
        size_t fo = ((size_t)(ks*16 + w*4 + c))*512 + (size_t)lane*8;
        short8 bh = *(const short8*)(Wh + fo);
        short8 bl = *(const short8*)(Wl + fo);
#pragma unroll
        for (int Mt = 0; Mt < 2; ++Mt) {
          acc[Mt][c] = __builtin_amdgcn_mfma_f32_16x16x32_bf16(ah[Mt], bh, acc[Mt][c], 0,0,0);
          acc[Mt][c] = __builtin_amdgcn_mfma_f32_16x16x32_bf16(ah[Mt], bl, acc[Mt][c], 0,0,0);
          acc[Mt][c] = __builtin_amdgcn_mfma_f32_16x16x32_bf16(al[Mt], bh, acc[Mt][c], 0,0,0);
        }
      }
    }
    __syncthreads();
#pragma unroll
    for (int Mt = 0; Mt < 2; ++Mt)
#pragma unroll
      for (int c = 0; c < 4; ++c) {
        int n = (w*4+c)*16 + rloc;
        float b = bias[n];
        int ksp = n >> 5, lp = ((n>>3)&3)*16, jp = n & 7;
#pragma unroll
        for (int i = 0; i < 4; ++i)
          actA[(Mt*8+ksp)*512 + (lp + khalf*4 + i)*8 + jp] = fmaxf(acc[Mt][c][i] + b, 0.f);
      }
    __syncthreads();
  }

  // ---- final: dot(row, M4) + c4 -> sigmoid; waves 0,1 handle Mt=w ----
  if (w < 2) {
    int Mt = w;
    float p = 0.f;
#pragma unroll
    for (int ks = 0; ks < 8; ++ks) {
      const float* pp = &actA[(Mt*8+ks)*512 + lane*8];
      const float* mm = &M4S[ks*32 + khalf*8];
#pragma unroll
      for (int j = 0; j < 8; ++j) p = fmaf(pp[j], mm[j], p);
    }
    p += __shfl_xor(p, 16);
    p += __shfl_xor(p, 32);
    if (khalf == 0) {
      float z = p + c4[0];
      out[base + Mt*16 + rloc] = 1.f / (1.f + expf(-z));
    }
  }
}

// ---------- launcher ----------
extern "C" void kernel_launch(void* const* d_in, const int* in_sizes, int n_in,
                              void* d_out, int out_size, void* d_ws, size_t ws_size,
                              hipStream_t stream)
{
  const float* x    = (const float*)d_in[0];
  const float* lines= (const float*)d_in[1];
  const float* Wm1  = (const float*)d_in[2];
  const float* bm1  = (const float*)d_in[3];
  const float* Wm2  = (const float*)d_in[4];
  const float* bm2  = (const float*)d_in[5];
  const float* We1  = (const float*)d_in[6];
  const float* be1  = (const float*)d_in[7];
  const float* We2  = (const float*)d_in[8];
  const float* be2  = (const float*)d_in[9];
  const float* We3  = (const float*)d_in[10];
  const float* be3  = (const float*)d_in[11];
  const float* ln_g = (const float*)d_in[12];
  const float* ln_b = (const float*)d_in[13];
  const float* Wq   = (const float*)d_in[14];
  const float* Wk   = (const float*)d_in[15];
  const float* Wv   = (const float*)d_in[16];
  const float* A1   = (const float*)d_in[17];
  const float* a1   = (const float*)d_in[18];
  const float* A2   = (const float*)d_in[19];
  const float* a2   = (const float*)d_in[20];
  const float* alng = (const float*)d_in[21];
  const float* alnb = (const float*)d_in[22];
  const float* mem_k= (const float*)d_in[23];
  const float* mem_v= (const float*)d_in[24];
  const float* M1   = (const float*)d_in[25];
  const float* c1   = (const float*)d_in[26];
  const float* M2   = (const float*)d_in[27];
  const float* c2   = (const float*)d_in[28];
  const float* M3   = (const float*)d_in[29];
  const float* c3   = (const float*)d_in[30];
  const float* M4   = (const float*)d_in[31];
  const float* c4   = (const float*)d_in[32];
  float* out = (float*)d_out;

  char* wp = (char*)d_ws;
  auto alloc = [&](size_t bytes) -> void* {
    void* p = (void*)wp;
    wp += (bytes + 255) & ~(size_t)255;
    return p;
  };
  float* pf     = (float*)alloc((size_t)NPTS*64*4);
  float* pe     = (float*)alloc((size_t)NPTS*64*4);
  u16*   Khf    = (u16*)alloc((size_t)NE*128*4*512*2);   // bf16-hi K A-fragments
  u16*   We1h   = (u16*)alloc((size_t)NE*32*512*2);
  u16*   We1l   = (u16*)alloc((size_t)NE*32*512*2);
  u16*   We2h   = (u16*)alloc((size_t)NE*128*512*2);
  u16*   We2l   = (u16*)alloc((size_t)NE*128*512*2);
  u16*   We3h   = (u16*)alloc((size_t)NE*64*512*2);
  u16*   We3l   = (u16*)alloc((size_t)NE*64*512*2);
  u16*   Wqh    = (u16*)alloc((size_t)NE*32*512*2);
  u16*   Wql    = (u16*)alloc((size_t)NE*32*512*2);
  u16*   A1h    = (u16*)alloc((size_t)NE*24*512*2);
  u16*   A1l    = (u16*)alloc((size_t)NE*24*512*2);
  u16*   A2h    = (u16*)alloc((size_t)NE*16*512*2);
  u16*   A2l    = (u16*)alloc((size_t)NE*16*512*2);
  u16*   M1h    = (u16*)alloc((size_t)64*512*2);
  u16*   M1l    = (u16*)alloc((size_t)64*512*2);
  u16*   M2h    = (u16*)alloc((size_t)128*512*2);
  u16*   M2l    = (u16*)alloc((size_t)128*512*2);
  u16*   M3h    = (u16*)alloc((size_t)128*512*2);
  u16*   M3l    = (u16*)alloc((size_t)128*512*2);
  float* Vhat   = (float*)alloc((size_t)NE*NM*DD*4);
  float* featsC = (float*)alloc((size_t)NE*NPTS*DD*4);
  float* QoutC  = (float*)alloc((size_t)NE*NPTS*DD*4);  // QC then reused as outC
  float* attnWb = (float*)alloc((size_t)NE*NPTS*NTK*4);
  float* slotW  = (float*)alloc((size_t)NE*NPTS*4);
  int*   attnIb = (int*)alloc((size_t)NE*NPTS*NTK*4);
  int*   plist  = (int*)alloc((size_t)NE*NPTS*4);
  int*   pairE  = (int*)alloc((size_t)NPTS*2*4);
  int*   pairS  = (int*)alloc((size_t)NPTS*2*4);
  int*   cnt    = (int*)alloc(64);

  hipMemsetAsync(cnt, 0, 64, stream);
  k_preproc<<<NPTS/256, 256, 0, stream>>>(x, lines, Wm1, bm1, Wm2, bm2,
                                          pf, pe, slotW, plist, pairE, pairS, cnt);
  k_kv<<<dim3(NM/32, NE, 2), 256, 0, stream>>>(mem_k, mem_v, Wk, Wv, Khf, Vhat);
  k_pack<<<dim3(296, NE), 64, 0, stream>>>(We1, We2, We3, Wq, A1, A2,
                                           We1h, We1l, We2h, We2l,
                                           We3h, We3l, Wqh, Wql,
                                           A1h, A1l, A2h, A2l);
  k_packM<<<320, 64, 0, stream>>>(M1, M2, M3, M1h, M1l, M2h, M2l, M3h, M3l);
  k_expert<<<dim3(NPTS/32, NE), 256, 0, stream>>>(pe, We1h, We1l, We2h, We2l,
                                                  We3h, We3l, Wqh, Wql,
                                                  be1, be2, be3, ln_g, ln_b,
                                                  plist, cnt, featsC, QoutC);
  k_scores<<<dim3(NPTS/32, NE), 256, 0, stream>>>(QoutC, Khf, cnt, attnWb, attnIb);
  k_adapter<<<dim3(NPTS/4, NE), 256, 0, stream>>>(Vhat, pf, A1h, A1l, A2h, A2l,
                                                  a1, a2, alng, alnb,
                                                  attnWb, attnIb, featsC, slotW, plist, cnt,
                                                  QoutC);
  k_final<<<NPTS/32, 256, 0, stream>>>(QoutC, pairE, pairS,
                                       M1h, M1l, M2h, M2l, M3h, M3l,
                                       c1, c2, c3, M4, c4, out);
}